// Round 4
// baseline (4625.891 us; speedup 1.0000x reference)
//
#include <hip/hip_runtime.h>
#include <hip/hip_bf16.h>

// Problem constants (fixed by setup_inputs)
constexpr int B_ = 8;
constexpr int C_ = 64;      // input channels = KC = VC = 64
constexpr int N_ = 65536;   // H*W = 256*256
constexpr int HW_ = 256;
constexpr float EPSF = 1e-6f;
constexpr int STATS = 4224; // 4096 matrix + 64 ksum + 64 vsum
constexpr int CHUNKS = 64;  // stats blocks per (branch,batch)

typedef __attribute__((ext_vector_type(8))) short bf16x8;
typedef __attribute__((ext_vector_type(4))) float f32x4;

// ================================================================
// Pass 1: per (branch,batch,chunk) compute partial Ksum/Vsum/matrix.
// (unchanged)
// ================================================================
__global__ __launch_bounds__(256, 2) void stats_kernel(
    const float* __restrict__ t1, const float* __restrict__ t2,
    const float* __restrict__ k1w, const float* __restrict__ k1b,
    const float* __restrict__ v1w, const float* __restrict__ v1b,
    const float* __restrict__ k2w, const float* __restrict__ k2b,
    const float* __restrict__ v2w, const float* __restrict__ v2b,
    float* __restrict__ partials)   // [2*B][CHUNKS][STATS]
{
  const int chunk = blockIdx.x;
  const int b = blockIdx.y;
  const int r = blockIdx.z;
  const float* x  = (r ? t2 : t1) + (size_t)b * C_ * N_;
  const float* kw = r ? k2w : k1w;
  const float* kb = r ? k2b : k1b;
  const float* vw = r ? v2w : v1w;
  const float* vb = r ? v2b : v1b;

  __shared__ float kwT[64 * 68];
  __shared__ float vwT[64 * 68];
  __shared__ float Kt[64 * 68];
  __shared__ float Vt[64 * 68];
  __shared__ float kb_s[64], vb_s[64];

  const int t = threadIdx.x;
  for (int idx = t; idx < 4096; idx += 256) {
    int m = idx >> 6, c = idx & 63;
    kwT[c * 68 + m] = kw[idx];
    vwT[c * 68 + m] = vw[idx];
  }
  if (t < 64) { kb_s[t] = kb[t]; vb_s[t] = vb[t]; }
  __syncthreads();

  const int mg = t & 3;       // channel group: channels mg*16 .. +16
  const int p  = t >> 2;      // pixel within tile (0..63)
  const int ty4 = (t >> 4) * 4;  // matrix-stage row base
  const int tx4 = (t & 15) * 4;  // matrix-stage col base

  float macc[16];
  float ksum[16], vsum[16];
#pragma unroll
  for (int i = 0; i < 16; ++i) { macc[i] = 0.f; ksum[i] = 0.f; vsum[i] = 0.f; }

  for (int tile = 0; tile < 16; ++tile) {
    const int n0 = chunk * 1024 + tile * 64;
    float kk[16], vv[16];
#pragma unroll
    for (int i = 0; i < 16; ++i) { kk[i] = kb_s[mg * 16 + i]; vv[i] = vb_s[mg * 16 + i]; }
    for (int c = 0; c < 64; ++c) {
      const float xv = x[(size_t)c * N_ + n0 + p];
#pragma unroll
      for (int i4 = 0; i4 < 4; ++i4) {
        const float4 wk = *(const float4*)&kwT[c * 68 + mg * 16 + i4 * 4];
        kk[i4 * 4 + 0] += wk.x * xv;
        kk[i4 * 4 + 1] += wk.y * xv;
        kk[i4 * 4 + 2] += wk.z * xv;
        kk[i4 * 4 + 3] += wk.w * xv;
        const float4 wvv = *(const float4*)&vwT[c * 68 + mg * 16 + i4 * 4];
        vv[i4 * 4 + 0] += wvv.x * xv;
        vv[i4 * 4 + 1] += wvv.y * xv;
        vv[i4 * 4 + 2] += wvv.z * xv;
        vv[i4 * 4 + 3] += wvv.w * xv;
      }
    }
    float ss = 0.f;
#pragma unroll
    for (int i = 0; i < 16; ++i) ss += kk[i] * kk[i];
    ss += __shfl_xor(ss, 1);
    ss += __shfl_xor(ss, 2);
    const float inv = rsqrtf(ss);
#pragma unroll
    for (int i = 0; i < 16; ++i) kk[i] *= inv;
#pragma unroll
    for (int i = 0; i < 16; ++i) { ksum[i] += kk[i]; vsum[i] += vv[i]; }

    __syncthreads();
#pragma unroll
    for (int i4 = 0; i4 < 4; ++i4) {
      *(float4*)&Kt[p * 68 + mg * 16 + i4 * 4] =
          make_float4(kk[i4 * 4 + 0], kk[i4 * 4 + 1], kk[i4 * 4 + 2], kk[i4 * 4 + 3]);
      *(float4*)&Vt[p * 68 + mg * 16 + i4 * 4] =
          make_float4(vv[i4 * 4 + 0], vv[i4 * 4 + 1], vv[i4 * 4 + 2], vv[i4 * 4 + 3]);
    }
    __syncthreads();
    for (int pp = 0; pp < 64; ++pp) {
      const float4 ka = *(const float4*)&Kt[pp * 68 + ty4];
      const float4 va = *(const float4*)&Vt[pp * 68 + tx4];
      macc[0]  += ka.x * va.x;  macc[1]  += ka.x * va.y;
      macc[2]  += ka.x * va.z;  macc[3]  += ka.x * va.w;
      macc[4]  += ka.y * va.x;  macc[5]  += ka.y * va.y;
      macc[6]  += ka.y * va.z;  macc[7]  += ka.y * va.w;
      macc[8]  += ka.z * va.x;  macc[9]  += ka.z * va.y;
      macc[10] += ka.z * va.z;  macc[11] += ka.z * va.w;
      macc[12] += ka.w * va.x;  macc[13] += ka.w * va.y;
      macc[14] += ka.w * va.z;  macc[15] += ka.w * va.w;
    }
  }

  float* pb = partials + ((size_t)(r * B_ + b) * CHUNKS + chunk) * STATS;
#pragma unroll
  for (int i = 0; i < 4; ++i)
#pragma unroll
    for (int j = 0; j < 4; ++j)
      pb[(ty4 + i) * 64 + tx4 + j] = macc[i * 4 + j];

  __syncthreads();
#pragma unroll
  for (int i4 = 0; i4 < 4; ++i4) {
    *(float4*)&Kt[p * 68 + mg * 16 + i4 * 4] =
        make_float4(ksum[i4 * 4 + 0], ksum[i4 * 4 + 1], ksum[i4 * 4 + 2], ksum[i4 * 4 + 3]);
    *(float4*)&Vt[p * 68 + mg * 16 + i4 * 4] =
        make_float4(vsum[i4 * 4 + 0], vsum[i4 * 4 + 1], vsum[i4 * 4 + 2], vsum[i4 * 4 + 3]);
  }
  __syncthreads();
  if (t < 64) {
    float s1 = 0.f, s2 = 0.f;
    for (int pp = 0; pp < 64; ++pp) { s1 += Kt[pp * 68 + t]; s2 += Vt[pp * 68 + t]; }
    pb[4096 + t] = s1;
    pb[4160 + t] = s2;
  }
}

// ================================================================
// Finalize: reduce partials, fold r_w in. (unchanged)
// ================================================================
__global__ void finalize_kernel(const float* __restrict__ partials,
                                const float* __restrict__ r1w,
                                const float* __restrict__ r2w,
                                float* __restrict__ derived)
{
  const int bb = blockIdx.x;           // r*8 + b
  const int r = bb >> 3;
  const float* rw = r ? r2w : r1w;
  __shared__ float mat[4096];
  __shared__ float ks[64], vs[64];
  const int t = threadIdx.x;
  const float* pb = partials + (size_t)bb * CHUNKS * STATS;
  for (int e = t; e < STATS; e += 256) {
    float s = 0.f;
    for (int j = 0; j < CHUNKS; ++j) s += pb[(size_t)j * STATS + e];
    if (e < 4096) mat[e] = s;
    else if (e < 4160) ks[e - 4096] = s;
    else vs[e - 4160] = s;
  }
  __syncthreads();
  float* der = derived + (size_t)bb * STATS;
  for (int e = t; e < 4096; e += 256) {
    const int o = e >> 6, m = e & 63;
    float s = 0.f;
    for (int c = 0; c < 64; ++c) s += rw[o * 64 + c] * mat[m * 64 + c];
    der[e] = s;
  }
  if (t < 64) {
    float s = 0.f;
    for (int c = 0; c < 64; ++c) s += rw[t * 64 + c] * vs[c];
    der[4096 + t] = s;
    der[4160 + t] = ks[t] + EPSF;
  }
}

// ================================================================
// Pass 2: per-pixel Q projection + attention output.
// NOW writes cat as chunked channel-last bf16 hi/lo planes:
//   catH[b][ch(8)][n][16ci], catL same; ch = r*4 + o/16.
// ================================================================
__global__ __launch_bounds__(256, 3) void attn_kernel(
    const float* __restrict__ t1, const float* __restrict__ t2,
    const float* __restrict__ q1w, const float* __restrict__ q1b,
    const float* __restrict__ q2w, const float* __restrict__ q2b,
    const float* __restrict__ r1b, const float* __restrict__ r2b,
    const float* __restrict__ derived,
    __hip_bfloat16* __restrict__ catH, __hip_bfloat16* __restrict__ catL)
{
  const int b = blockIdx.y;
  const int rbr = blockIdx.z;
  const float* x  = (rbr ? t2 : t1) + (size_t)b * C_ * N_;
  const float* qw = rbr ? q2w : q1w;
  const float* qb = rbr ? q2b : q1b;
  const float* rb = rbr ? r2b : r1b;
  const float* der = derived + (size_t)(rbr * B_ + b) * STATS;

  __shared__ float qwT[64 * 68];
  __shared__ float rm[4096];
  __shared__ float rvs[64], kse[64], rbs[64], qbs[64];

  const int t = threadIdx.x;
  for (int idx = t; idx < 4096; idx += 256) {
    int m = idx >> 6, c = idx & 63;
    qwT[c * 68 + m] = qw[idx];
    rm[idx] = der[idx];
  }
  if (t < 64) {
    rvs[t] = der[4096 + t];
    kse[t] = der[4160 + t];
    rbs[t] = rb[t];
    qbs[t] = qb[t];
  }
  __syncthreads();

  const int n = blockIdx.x * 256 + t;
  float q[64];
#pragma unroll
  for (int m = 0; m < 64; ++m) q[m] = qbs[m];
  for (int c = 0; c < 64; ++c) {
    const float xv = x[(size_t)c * N_ + n];
#pragma unroll
    for (int m4 = 0; m4 < 16; ++m4) {
      const float4 w = *(const float4*)&qwT[c * 68 + m4 * 4];
      q[m4 * 4 + 0] += w.x * xv;
      q[m4 * 4 + 1] += w.y * xv;
      q[m4 * 4 + 2] += w.z * xv;
      q[m4 * 4 + 3] += w.w * xv;
    }
  }
  float s0 = 0.f, s1 = 0.f, s2 = 0.f, s3 = 0.f;
#pragma unroll
  for (int m = 0; m < 64; m += 4) {
    s0 += q[m] * q[m];  s1 += q[m + 1] * q[m + 1];
    s2 += q[m + 2] * q[m + 2];  s3 += q[m + 3] * q[m + 3];
  }
  const float inv = rsqrtf((s0 + s1) + (s2 + s3));
  float d0 = 0.f, d1 = 0.f, d2 = 0.f, d3 = 0.f;
#pragma unroll
  for (int m = 0; m < 64; m += 4) {
    d0 += q[m] * kse[m];  d1 += q[m + 1] * kse[m + 1];
    d2 += q[m + 2] * kse[m + 2];  d3 += q[m + 3] * kse[m + 3];
  }
  const float rden = 1.0f / (65536.0f + inv * ((d0 + d1) + (d2 + d3)));
  const float f1 = rden * inv;

  unsigned hp[8], lp[8];
  for (int og = 0; og < 4; ++og) {
#pragma unroll
    for (int sl = 0; sl < 16; ++sl) {
      const int o = og * 16 + sl;
      float a0 = 0.f, a1 = 0.f, a2 = 0.f, a3 = 0.f;
      const float* rmo = &rm[o * 64];
#pragma unroll
      for (int m4 = 0; m4 < 16; ++m4) {
        const float4 w = *(const float4*)&rmo[m4 * 4];
        a0 += w.x * q[m4 * 4 + 0];
        a1 += w.y * q[m4 * 4 + 1];
        a2 += w.z * q[m4 * 4 + 2];
        a3 += w.w * q[m4 * 4 + 3];
      }
      const float av = f1 * ((a0 + a1) + (a2 + a3)) + rden * rvs[o] + rbs[o];
      __hip_bfloat16 h = __float2bfloat16(av);
      const float hf = __bfloat162float(h);
      __hip_bfloat16 lo = __float2bfloat16(av - hf);
      const unsigned hb = *(unsigned short*)&h;
      const unsigned lb = *(unsigned short*)&lo;
      if (sl & 1) { hp[sl >> 1] |= hb << 16; lp[sl >> 1] |= lb << 16; }
      else        { hp[sl >> 1]  = hb;       lp[sl >> 1]  = lb; }
    }
    const int ch = rbr * 4 + og;
    const size_t base = (((size_t)(b * 8 + ch)) * N_ + n) * 16;
    uint4* dh = (uint4*)(catH + base);
    dh[0] = make_uint4(hp[0], hp[1], hp[2], hp[3]);
    dh[1] = make_uint4(hp[4], hp[5], hp[6], hp[7]);
    uint4* dl = (uint4*)(catL + base);
    dl[0] = make_uint4(lp[0], lp[1], lp[2], lp[3]);
    dl[1] = make_uint4(lp[4], lp[5], lp[6], lp[7]);
  }
}

// ================================================================
// Prearrange conv weights into exact MFMA A-fragment order, split
// bf16 hi/lo.  WA[c(8)][s(5)][v(2)][ot(4)][lane(64)][j(8)] bf16.
// A-frag mapping (16x16x32): m = lane&15, k = (lane>>4)*8 + j;
// k of step s = (tap 2s + k/16, ci k%16); tap 9 = zero pad.
// ================================================================
__global__ void prep_wa_kernel(const float* __restrict__ cw,
                               __hip_bfloat16* __restrict__ WA) {
  const int e = blockIdx.x * 256 + threadIdx.x;   // 163840 total
  if (e >= 8 * 5 * 2 * 4 * 512) return;
  const int j    = e & 7;
  const int lane = (e >> 3) & 63;
  const int f    = e >> 9;
  const int ot   = f & 3;
  const int v    = (f >> 2) & 1;
  const int s    = (f >> 3) % 5;
  const int c    = (f >> 3) / 5;
  const int o    = ot * 16 + (lane & 15);
  const int g    = lane >> 4;
  const int tap  = 2 * s + (g >> 1);
  float val = 0.f;
  if (tap <= 8) {
    const int ci = c * 16 + (g & 1) * 8 + j;
    val = cw[(size_t)(o * 128 + ci) * 9 + tap];
  }
  __hip_bfloat16 h = __float2bfloat16(val);
  if (v) h = __float2bfloat16(val - __bfloat162float(h));
  WA[e] = h;
}

// ================================================================
// Pass 3: 3x3 conv via MFMA implicit GEMM, split-bf16 (hh + h*lo +
// lo*h; lo*lo dropped ~2^-18).  D[o][p] = sum_k W[o][k] X[k][p].
// Block 256 thr / 4 waves; tile 64o x (4 rows x 64 cols); wave = row.
// Per wave: 4 o-tiles x 4 p-tiles, acc 64 VGPR.  K-step = 2 taps x
// 16 ci (taps padded to 10).  X staged in LDS [6][68][pad 24] hi+lo
// (39 KB -> 3 blocks/CU); A-frags streamed from L2-resident WA.
// ================================================================
__global__ __launch_bounds__(256, 3) void conv_mfma_kernel(
    const __hip_bfloat16* __restrict__ catH,
    const __hip_bfloat16* __restrict__ catL,
    const __hip_bfloat16* __restrict__ WA,
    const float* __restrict__ cb,
    float* __restrict__ out)
{
  __shared__ __hip_bfloat16 XsH[6 * 68 * 24];
  __shared__ __hip_bfloat16 XsL[6 * 68 * 24];

  const int t  = threadIdx.x;
  const int w  = t >> 6;       // wave id = output row 0..3
  const int l  = t & 63;
  const int li = l & 15;
  const int g  = l >> 4;
  const int x0 = blockIdx.x * 64;
  const int y0 = blockIdx.y * 4;
  const int b  = blockIdx.z;

  f32x4 acc[4][4];
#pragma unroll
  for (int i = 0; i < 4; ++i)
#pragma unroll
    for (int k = 0; k < 4; ++k) acc[i][k] = (f32x4){0.f, 0.f, 0.f, 0.f};

  for (int c = 0; c < 8; ++c) {
    __syncthreads();
    // ---- stage X chunk: 6 rows x 66 cols x 16 ci, hi+lo ----
    for (int idx = t; idx < 396; idx += 256) {
      const int row = idx / 66;
      const int col = idx - row * 66;
      const int gy = y0 + row - 1;
      const int gx = x0 + col - 1;
      uint4 vh0 = {0,0,0,0}, vh1 = {0,0,0,0};
      uint4 vl0 = {0,0,0,0}, vl1 = {0,0,0,0};
      if ((unsigned)gy < 256u && (unsigned)gx < 256u) {
        const size_t base = (((size_t)(b * 8 + c)) * N_ + (gy * HW_ + gx)) * 16;
        const uint4* ph = (const uint4*)(catH + base);
        vh0 = ph[0]; vh1 = ph[1];
        const uint4* pl = (const uint4*)(catL + base);
        vl0 = pl[0]; vl1 = pl[1];
      }
      const int le = (row * 68 + col) * 24;
      *(uint4*)(&XsH[le]) = vh0; *(uint4*)(&XsH[le + 8]) = vh1;
      *(uint4*)(&XsL[le]) = vl0; *(uint4*)(&XsL[le + 8]) = vl1;
    }
    __syncthreads();

    const __hip_bfloat16* wa_c = WA + (size_t)c * 20480;
#pragma unroll
    for (int s = 0; s < 5; ++s) {
      const __hip_bfloat16* wa_s = wa_c + s * 4096 + l * 8;
      bf16x8 aH[4], aL[4];
#pragma unroll
      for (int ot = 0; ot < 4; ++ot) aH[ot] = *(const bf16x8*)(wa_s + ot * 512);
#pragma unroll
      for (int ot = 0; ot < 4; ++ot) aL[ot] = *(const bf16x8*)(wa_s + 2048 + ot * 512);

      int tap = 2 * s + (g >> 1);
      if (tap > 8) tap = 0;            // A is zero there; any valid addr
      const int ky = tap / 3;
      const int kx = tap - ky * 3;
      const int e0 = ((w + ky) * 68 + li + kx) * 24 + (g & 1) * 8;
      bf16x8 bH[4], bL[4];
#pragma unroll
      for (int pt = 0; pt < 4; ++pt) bH[pt] = *(const bf16x8*)(&XsH[e0 + pt * 384]);
#pragma unroll
      for (int pt = 0; pt < 4; ++pt) bL[pt] = *(const bf16x8*)(&XsL[e0 + pt * 384]);

#pragma unroll
      for (int ot = 0; ot < 4; ++ot)
#pragma unroll
        for (int pt = 0; pt < 4; ++pt) {
          acc[ot][pt] = __builtin_amdgcn_mfma_f32_16x16x32_bf16(
              aH[ot], bH[pt], acc[ot][pt], 0, 0, 0);
          acc[ot][pt] = __builtin_amdgcn_mfma_f32_16x16x32_bf16(
              aH[ot], bL[pt], acc[ot][pt], 0, 0, 0);
          acc[ot][pt] = __builtin_amdgcn_mfma_f32_16x16x32_bf16(
              aL[ot], bH[pt], acc[ot][pt], 0, 0, 0);
        }
    }
  }

  // ---- epilogue: D[m=o][n=p], m=(l>>4)*4+reg, n=l&15 ----
#pragma unroll
  for (int ot = 0; ot < 4; ++ot)
#pragma unroll
    for (int r = 0; r < 4; ++r) {
      const int o = ot * 16 + g * 4 + r;
      const float bv = cb[o];
      float* orow = out + ((size_t)b * 64 + o) * N_ + (size_t)(y0 + w) * HW_ + x0 + li;
#pragma unroll
      for (int pt = 0; pt < 4; ++pt)
        orow[pt * 16] = acc[ot][pt][r] + bv;
    }
}

// ================================================================
extern "C" void kernel_launch(void* const* d_in, const int* in_sizes, int n_in,
                              void* d_out, int out_size, void* d_ws, size_t ws_size,
                              hipStream_t stream) {
  const float* t1  = (const float*)d_in[0];
  const float* t2  = (const float*)d_in[1];
  const float* q1w = (const float*)d_in[2];
  const float* q1b = (const float*)d_in[3];
  const float* k1w = (const float*)d_in[4];
  const float* k1b = (const float*)d_in[5];
  const float* v1w = (const float*)d_in[6];
  const float* v1b = (const float*)d_in[7];
  const float* r1w = (const float*)d_in[8];
  const float* r1b = (const float*)d_in[9];
  const float* q2w = (const float*)d_in[10];
  const float* q2b = (const float*)d_in[11];
  const float* k2w = (const float*)d_in[12];
  const float* k2b = (const float*)d_in[13];
  const float* v2w = (const float*)d_in[14];
  const float* v2b = (const float*)d_in[15];
  const float* r2w = (const float*)d_in[16];
  const float* r2b = (const float*)d_in[17];
  const float* cw  = (const float*)d_in[18];
  const float* cbp = (const float*)d_in[19];
  float* out = (float*)d_out;

  // ws layout: [catH 128MB][catL 128MB][partials 17.3MB][derived]
  // WA (327 KB) aliases the partials region (dead after finalize;
  // prep_wa launched after finalize, before conv).
  char* ws = (char*)d_ws;
  const size_t catB  = (size_t)B_ * 8 * N_ * 16 * 2;     // 128 MB each
  const size_t partB = (size_t)16 * CHUNKS * STATS * sizeof(float);
  __hip_bfloat16* catHp = (__hip_bfloat16*)ws;
  __hip_bfloat16* catLp = (__hip_bfloat16*)(ws + catB);
  float* part = (float*)(ws + 2 * catB);
  float* der  = (float*)(ws + 2 * catB + partB);
  __hip_bfloat16* WA = (__hip_bfloat16*)part;            // alias

  stats_kernel<<<dim3(CHUNKS, B_, 2), 256, 0, stream>>>(
      t1, t2, k1w, k1b, v1w, v1b, k2w, k2b, v2w, v2b, part);
  finalize_kernel<<<dim3(16), 256, 0, stream>>>(part, r1w, r2w, der);
  prep_wa_kernel<<<dim3(640), 256, 0, stream>>>(cw, WA);
  attn_kernel<<<dim3(N_ / 256, B_, 2), 256, 0, stream>>>(
      t1, t2, q1w, q1b, q2w, q2b, r1b, r2b, der, catHp, catLp);
  conv_mfma_kernel<<<dim3(4, 64, B_), 256, 0, stream>>>(
      catHp, catLp, WA, cbp, out);
}

// Round 5
// 3590.809 us; speedup vs baseline: 1.2883x; 1.2883x over previous
//
#include <hip/hip_runtime.h>
#include <hip/hip_bf16.h>

// Problem constants (fixed by setup_inputs)
constexpr int B_ = 8;
constexpr int C_ = 64;      // input channels = KC = VC = 64
constexpr int N_ = 65536;   // H*W = 256*256
constexpr int HW_ = 256;
constexpr float EPSF = 1e-6f;
constexpr int STATS = 4224; // 4096 matrix + 64 ksum + 64 vsum
constexpr int CHUNKS = 64;  // stats blocks per (branch,batch)

typedef __attribute__((ext_vector_type(8))) short bf16x8;
typedef __attribute__((ext_vector_type(4))) float f32x4;

// ================================================================
// Pass 1: per (branch,batch,chunk) compute partial Ksum/Vsum/matrix.
// (unchanged)
// ================================================================
__global__ __launch_bounds__(256, 2) void stats_kernel(
    const float* __restrict__ t1, const float* __restrict__ t2,
    const float* __restrict__ k1w, const float* __restrict__ k1b,
    const float* __restrict__ v1w, const float* __restrict__ v1b,
    const float* __restrict__ k2w, const float* __restrict__ k2b,
    const float* __restrict__ v2w, const float* __restrict__ v2b,
    float* __restrict__ partials)   // [2*B][CHUNKS][STATS]
{
  const int chunk = blockIdx.x;
  const int b = blockIdx.y;
  const int r = blockIdx.z;
  const float* x  = (r ? t2 : t1) + (size_t)b * C_ * N_;
  const float* kw = r ? k2w : k1w;
  const float* kb = r ? k2b : k1b;
  const float* vw = r ? v2w : v1w;
  const float* vb = r ? v2b : v1b;

  __shared__ float kwT[64 * 68];
  __shared__ float vwT[64 * 68];
  __shared__ float Kt[64 * 68];
  __shared__ float Vt[64 * 68];
  __shared__ float kb_s[64], vb_s[64];

  const int t = threadIdx.x;
  for (int idx = t; idx < 4096; idx += 256) {
    int m = idx >> 6, c = idx & 63;
    kwT[c * 68 + m] = kw[idx];
    vwT[c * 68 + m] = vw[idx];
  }
  if (t < 64) { kb_s[t] = kb[t]; vb_s[t] = vb[t]; }
  __syncthreads();

  const int mg = t & 3;       // channel group: channels mg*16 .. +16
  const int p  = t >> 2;      // pixel within tile (0..63)
  const int ty4 = (t >> 4) * 4;  // matrix-stage row base
  const int tx4 = (t & 15) * 4;  // matrix-stage col base

  float macc[16];
  float ksum[16], vsum[16];
#pragma unroll
  for (int i = 0; i < 16; ++i) { macc[i] = 0.f; ksum[i] = 0.f; vsum[i] = 0.f; }

  for (int tile = 0; tile < 16; ++tile) {
    const int n0 = chunk * 1024 + tile * 64;
    float kk[16], vv[16];
#pragma unroll
    for (int i = 0; i < 16; ++i) { kk[i] = kb_s[mg * 16 + i]; vv[i] = vb_s[mg * 16 + i]; }
    for (int c = 0; c < 64; ++c) {
      const float xv = x[(size_t)c * N_ + n0 + p];
#pragma unroll
      for (int i4 = 0; i4 < 4; ++i4) {
        const float4 wk = *(const float4*)&kwT[c * 68 + mg * 16 + i4 * 4];
        kk[i4 * 4 + 0] += wk.x * xv;
        kk[i4 * 4 + 1] += wk.y * xv;
        kk[i4 * 4 + 2] += wk.z * xv;
        kk[i4 * 4 + 3] += wk.w * xv;
        const float4 wvv = *(const float4*)&vwT[c * 68 + mg * 16 + i4 * 4];
        vv[i4 * 4 + 0] += wvv.x * xv;
        vv[i4 * 4 + 1] += wvv.y * xv;
        vv[i4 * 4 + 2] += wvv.z * xv;
        vv[i4 * 4 + 3] += wvv.w * xv;
      }
    }
    float ss = 0.f;
#pragma unroll
    for (int i = 0; i < 16; ++i) ss += kk[i] * kk[i];
    ss += __shfl_xor(ss, 1);
    ss += __shfl_xor(ss, 2);
    const float inv = rsqrtf(ss);
#pragma unroll
    for (int i = 0; i < 16; ++i) kk[i] *= inv;
#pragma unroll
    for (int i = 0; i < 16; ++i) { ksum[i] += kk[i]; vsum[i] += vv[i]; }

    __syncthreads();
#pragma unroll
    for (int i4 = 0; i4 < 4; ++i4) {
      *(float4*)&Kt[p * 68 + mg * 16 + i4 * 4] =
          make_float4(kk[i4 * 4 + 0], kk[i4 * 4 + 1], kk[i4 * 4 + 2], kk[i4 * 4 + 3]);
      *(float4*)&Vt[p * 68 + mg * 16 + i4 * 4] =
          make_float4(vv[i4 * 4 + 0], vv[i4 * 4 + 1], vv[i4 * 4 + 2], vv[i4 * 4 + 3]);
    }
    __syncthreads();
    for (int pp = 0; pp < 64; ++pp) {
      const float4 ka = *(const float4*)&Kt[pp * 68 + ty4];
      const float4 va = *(const float4*)&Vt[pp * 68 + tx4];
      macc[0]  += ka.x * va.x;  macc[1]  += ka.x * va.y;
      macc[2]  += ka.x * va.z;  macc[3]  += ka.x * va.w;
      macc[4]  += ka.y * va.x;  macc[5]  += ka.y * va.y;
      macc[6]  += ka.y * va.z;  macc[7]  += ka.y * va.w;
      macc[8]  += ka.z * va.x;  macc[9]  += ka.z * va.y;
      macc[10] += ka.z * va.z;  macc[11] += ka.z * va.w;
      macc[12] += ka.w * va.x;  macc[13] += ka.w * va.y;
      macc[14] += ka.w * va.z;  macc[15] += ka.w * va.w;
    }
  }

  float* pb = partials + ((size_t)(r * B_ + b) * CHUNKS + chunk) * STATS;
#pragma unroll
  for (int i = 0; i < 4; ++i)
#pragma unroll
    for (int j = 0; j < 4; ++j)
      pb[(ty4 + i) * 64 + tx4 + j] = macc[i * 4 + j];

  __syncthreads();
#pragma unroll
  for (int i4 = 0; i4 < 4; ++i4) {
    *(float4*)&Kt[p * 68 + mg * 16 + i4 * 4] =
        make_float4(ksum[i4 * 4 + 0], ksum[i4 * 4 + 1], ksum[i4 * 4 + 2], ksum[i4 * 4 + 3]);
    *(float4*)&Vt[p * 68 + mg * 16 + i4 * 4] =
        make_float4(vsum[i4 * 4 + 0], vsum[i4 * 4 + 1], vsum[i4 * 4 + 2], vsum[i4 * 4 + 3]);
  }
  __syncthreads();
  if (t < 64) {
    float s1 = 0.f, s2 = 0.f;
    for (int pp = 0; pp < 64; ++pp) { s1 += Kt[pp * 68 + t]; s2 += Vt[pp * 68 + t]; }
    pb[4096 + t] = s1;
    pb[4160 + t] = s2;
  }
}

// ================================================================
// Finalize: reduce partials, fold r_w in. (unchanged)
// ================================================================
__global__ void finalize_kernel(const float* __restrict__ partials,
                                const float* __restrict__ r1w,
                                const float* __restrict__ r2w,
                                float* __restrict__ derived)
{
  const int bb = blockIdx.x;           // r*8 + b
  const int r = bb >> 3;
  const float* rw = r ? r2w : r1w;
  __shared__ float mat[4096];
  __shared__ float ks[64], vs[64];
  const int t = threadIdx.x;
  const float* pb = partials + (size_t)bb * CHUNKS * STATS;
  for (int e = t; e < STATS; e += 256) {
    float s = 0.f;
    for (int j = 0; j < CHUNKS; ++j) s += pb[(size_t)j * STATS + e];
    if (e < 4096) mat[e] = s;
    else if (e < 4160) ks[e - 4096] = s;
    else vs[e - 4160] = s;
  }
  __syncthreads();
  float* der = derived + (size_t)bb * STATS;
  for (int e = t; e < 4096; e += 256) {
    const int o = e >> 6, m = e & 63;
    float s = 0.f;
    for (int c = 0; c < 64; ++c) s += rw[o * 64 + c] * mat[m * 64 + c];
    der[e] = s;
  }
  if (t < 64) {
    float s = 0.f;
    for (int c = 0; c < 64; ++c) s += rw[t * 64 + c] * vs[c];
    der[4096 + t] = s;
    der[4160 + t] = ks[t] + EPSF;
  }
}

// ================================================================
// Pass 2: per-pixel Q projection + attention output.
// ROUND-5 FIX: round 4's hp[8]/lp[8] packing + address-taken bf16
// locals (on top of live q[64]) spilled to scratch -> 14.5 GB phantom
// HBM traffic (same signature as round-2 conv). Now: per og, write
// scalar bf16 hi/lo (pure bit-arithmetic conversion, no address-taken
// locals) into a 16 KB LDS staging buffer, barrier, then each thread
// re-reads its contiguous 32 B row and does coalesced uint4 stores.
// Live state stays ~q[64]+15 regs.
// cat layout (unchanged): catH/catL [b][ch(8)][n][16ci], ch=r*4+o/16.
// ================================================================
__global__ __launch_bounds__(256, 3) void attn_kernel(
    const float* __restrict__ t1, const float* __restrict__ t2,
    const float* __restrict__ q1w, const float* __restrict__ q1b,
    const float* __restrict__ q2w, const float* __restrict__ q2b,
    const float* __restrict__ r1b, const float* __restrict__ r2b,
    const float* __restrict__ derived,
    __hip_bfloat16* __restrict__ catH, __hip_bfloat16* __restrict__ catL)
{
  const int b = blockIdx.y;
  const int rbr = blockIdx.z;
  const float* x  = (rbr ? t2 : t1) + (size_t)b * C_ * N_;
  const float* qw = rbr ? q2w : q1w;
  const float* qb = rbr ? q2b : q1b;
  const float* rb = rbr ? r2b : r1b;
  const float* der = derived + (size_t)(rbr * B_ + b) * STATS;

  __shared__ float qwT[64 * 68];
  __shared__ float rm[4096];
  __shared__ float rvs[64], kse[64], rbs[64], qbs[64];
  __shared__ unsigned short stH[256 * 16];
  __shared__ unsigned short stL[256 * 16];

  const int t = threadIdx.x;
  for (int idx = t; idx < 4096; idx += 256) {
    int m = idx >> 6, c = idx & 63;
    qwT[c * 68 + m] = qw[idx];
    rm[idx] = der[idx];
  }
  if (t < 64) {
    rvs[t] = der[4096 + t];
    kse[t] = der[4160 + t];
    rbs[t] = rb[t];
    qbs[t] = qb[t];
  }
  __syncthreads();

  const int n = blockIdx.x * 256 + t;
  float q[64];
#pragma unroll
  for (int m = 0; m < 64; ++m) q[m] = qbs[m];
  for (int c = 0; c < 64; ++c) {
    const float xv = x[(size_t)c * N_ + n];
#pragma unroll
    for (int m4 = 0; m4 < 16; ++m4) {
      const float4 w = *(const float4*)&qwT[c * 68 + m4 * 4];
      q[m4 * 4 + 0] += w.x * xv;
      q[m4 * 4 + 1] += w.y * xv;
      q[m4 * 4 + 2] += w.z * xv;
      q[m4 * 4 + 3] += w.w * xv;
    }
  }
  float s0 = 0.f, s1 = 0.f, s2 = 0.f, s3 = 0.f;
#pragma unroll
  for (int m = 0; m < 64; m += 4) {
    s0 += q[m] * q[m];  s1 += q[m + 1] * q[m + 1];
    s2 += q[m + 2] * q[m + 2];  s3 += q[m + 3] * q[m + 3];
  }
  const float inv = rsqrtf((s0 + s1) + (s2 + s3));
  float d0 = 0.f, d1 = 0.f, d2 = 0.f, d3 = 0.f;
#pragma unroll
  for (int m = 0; m < 64; m += 4) {
    d0 += q[m] * kse[m];  d1 += q[m + 1] * kse[m + 1];
    d2 += q[m + 2] * kse[m + 2];  d3 += q[m + 3] * kse[m + 3];
  }
  const float rden = 1.0f / (65536.0f + inv * ((d0 + d1) + (d2 + d3)));
  const float f1 = rden * inv;

  for (int og = 0; og < 4; ++og) {
    __syncthreads();   // previous og's staging reads finished
#pragma unroll
    for (int sl = 0; sl < 16; ++sl) {
      const int o = og * 16 + sl;
      float a0 = 0.f, a1 = 0.f, a2 = 0.f, a3 = 0.f;
      const float* rmo = &rm[o * 64];
#pragma unroll
      for (int m4 = 0; m4 < 16; ++m4) {
        const float4 w = *(const float4*)&rmo[m4 * 4];
        a0 += w.x * q[m4 * 4 + 0];
        a1 += w.y * q[m4 * 4 + 1];
        a2 += w.z * q[m4 * 4 + 2];
        a3 += w.w * q[m4 * 4 + 3];
      }
      const float av = f1 * ((a0 + a1) + (a2 + a3)) + rden * rvs[o] + rbs[o];
      // bf16 hi/lo split, RNE, pure bit arithmetic (no address-taken locals)
      const unsigned u  = __float_as_uint(av);
      const unsigned short hb = (unsigned short)((u + 0x7fffu + ((u >> 16) & 1u)) >> 16);
      const float hf = __uint_as_float((unsigned)hb << 16);
      const unsigned ul = __float_as_uint(av - hf);
      const unsigned short lb = (unsigned short)((ul + 0x7fffu + ((ul >> 16) & 1u)) >> 16);
      stH[t * 16 + sl] = hb;
      stL[t * 16 + sl] = lb;
    }
    __syncthreads();
    const int ch = rbr * 4 + og;
    const size_t base = (((size_t)(b * 8 + ch)) * N_ + n) * 16;
    const uint4* sh = (const uint4*)&stH[t * 16];
    uint4* dh = (uint4*)(catH + base);
    dh[0] = sh[0]; dh[1] = sh[1];
    const uint4* sl4 = (const uint4*)&stL[t * 16];
    uint4* dl = (uint4*)(catL + base);
    dl[0] = sl4[0]; dl[1] = sl4[1];
  }
}

// ================================================================
// Prearrange conv weights into exact MFMA A-fragment order, split
// bf16 hi/lo.  WA[c(8)][s(5)][v(2)][ot(4)][lane(64)][j(8)] bf16.
// (unchanged)
// ================================================================
__global__ void prep_wa_kernel(const float* __restrict__ cw,
                               __hip_bfloat16* __restrict__ WA) {
  const int e = blockIdx.x * 256 + threadIdx.x;   // 163840 total
  if (e >= 8 * 5 * 2 * 4 * 512) return;
  const int j    = e & 7;
  const int lane = (e >> 3) & 63;
  const int f    = e >> 9;
  const int ot   = f & 3;
  const int v    = (f >> 2) & 1;
  const int s    = (f >> 3) % 5;
  const int c    = (f >> 3) / 5;
  const int o    = ot * 16 + (lane & 15);
  const int g    = lane >> 4;
  const int tap  = 2 * s + (g >> 1);
  float val = 0.f;
  if (tap <= 8) {
    const int ci = c * 16 + (g & 1) * 8 + j;
    val = cw[(size_t)(o * 128 + ci) * 9 + tap];
  }
  __hip_bfloat16 h = __float2bfloat16(val);
  if (v) h = __float2bfloat16(val - __bfloat162float(h));
  WA[e] = h;
}

// ================================================================
// Pass 3: 3x3 conv via MFMA implicit GEMM, split-bf16. (unchanged)
// ================================================================
__global__ __launch_bounds__(256, 3) void conv_mfma_kernel(
    const __hip_bfloat16* __restrict__ catH,
    const __hip_bfloat16* __restrict__ catL,
    const __hip_bfloat16* __restrict__ WA,
    const float* __restrict__ cb,
    float* __restrict__ out)
{
  __shared__ __hip_bfloat16 XsH[6 * 68 * 24];
  __shared__ __hip_bfloat16 XsL[6 * 68 * 24];

  const int t  = threadIdx.x;
  const int w  = t >> 6;       // wave id = output row 0..3
  const int l  = t & 63;
  const int li = l & 15;
  const int g  = l >> 4;
  const int x0 = blockIdx.x * 64;
  const int y0 = blockIdx.y * 4;
  const int b  = blockIdx.z;

  f32x4 acc[4][4];
#pragma unroll
  for (int i = 0; i < 4; ++i)
#pragma unroll
    for (int k = 0; k < 4; ++k) acc[i][k] = (f32x4){0.f, 0.f, 0.f, 0.f};

  for (int c = 0; c < 8; ++c) {
    __syncthreads();
    // ---- stage X chunk: 6 rows x 66 cols x 16 ci, hi+lo ----
    for (int idx = t; idx < 396; idx += 256) {
      const int row = idx / 66;
      const int col = idx - row * 66;
      const int gy = y0 + row - 1;
      const int gx = x0 + col - 1;
      uint4 vh0 = {0,0,0,0}, vh1 = {0,0,0,0};
      uint4 vl0 = {0,0,0,0}, vl1 = {0,0,0,0};
      if ((unsigned)gy < 256u && (unsigned)gx < 256u) {
        const size_t base = (((size_t)(b * 8 + c)) * N_ + (gy * HW_ + gx)) * 16;
        const uint4* ph = (const uint4*)(catH + base);
        vh0 = ph[0]; vh1 = ph[1];
        const uint4* pl = (const uint4*)(catL + base);
        vl0 = pl[0]; vl1 = pl[1];
      }
      const int le = (row * 68 + col) * 24;
      *(uint4*)(&XsH[le]) = vh0; *(uint4*)(&XsH[le + 8]) = vh1;
      *(uint4*)(&XsL[le]) = vl0; *(uint4*)(&XsL[le + 8]) = vl1;
    }
    __syncthreads();

    const __hip_bfloat16* wa_c = WA + (size_t)c * 20480;
#pragma unroll
    for (int s = 0; s < 5; ++s) {
      const __hip_bfloat16* wa_s = wa_c + s * 4096 + l * 8;
      bf16x8 aH[4], aL[4];
#pragma unroll
      for (int ot = 0; ot < 4; ++ot) aH[ot] = *(const bf16x8*)(wa_s + ot * 512);
#pragma unroll
      for (int ot = 0; ot < 4; ++ot) aL[ot] = *(const bf16x8*)(wa_s + 2048 + ot * 512);

      int tap = 2 * s + (g >> 1);
      if (tap > 8) tap = 0;            // A is zero there; any valid addr
      const int ky = tap / 3;
      const int kx = tap - ky * 3;
      const int e0 = ((w + ky) * 68 + li + kx) * 24 + (g & 1) * 8;
      bf16x8 bH[4], bL[4];
#pragma unroll
      for (int pt = 0; pt < 4; ++pt) bH[pt] = *(const bf16x8*)(&XsH[e0 + pt * 384]);
#pragma unroll
      for (int pt = 0; pt < 4; ++pt) bL[pt] = *(const bf16x8*)(&XsL[e0 + pt * 384]);

#pragma unroll
      for (int ot = 0; ot < 4; ++ot)
#pragma unroll
        for (int pt = 0; pt < 4; ++pt) {
          acc[ot][pt] = __builtin_amdgcn_mfma_f32_16x16x32_bf16(
              aH[ot], bH[pt], acc[ot][pt], 0, 0, 0);
          acc[ot][pt] = __builtin_amdgcn_mfma_f32_16x16x32_bf16(
              aH[ot], bL[pt], acc[ot][pt], 0, 0, 0);
          acc[ot][pt] = __builtin_amdgcn_mfma_f32_16x16x32_bf16(
              aL[ot], bH[pt], acc[ot][pt], 0, 0, 0);
        }
    }
  }

  // ---- epilogue: D[m=o][n=p], m=(l>>4)*4+reg, n=l&15 ----
#pragma unroll
  for (int ot = 0; ot < 4; ++ot)
#pragma unroll
    for (int r = 0; r < 4; ++r) {
      const int o = ot * 16 + g * 4 + r;
      const float bv = cb[o];
      float* orow = out + ((size_t)b * 64 + o) * N_ + (size_t)(y0 + w) * HW_ + x0 + li;
#pragma unroll
      for (int pt = 0; pt < 4; ++pt)
        orow[pt * 16] = acc[ot][pt][r] + bv;
    }
}

// ================================================================
extern "C" void kernel_launch(void* const* d_in, const int* in_sizes, int n_in,
                              void* d_out, int out_size, void* d_ws, size_t ws_size,
                              hipStream_t stream) {
  const float* t1  = (const float*)d_in[0];
  const float* t2  = (const float*)d_in[1];
  const float* q1w = (const float*)d_in[2];
  const float* q1b = (const float*)d_in[3];
  const float* k1w = (const float*)d_in[4];
  const float* k1b = (const float*)d_in[5];
  const float* v1w = (const float*)d_in[6];
  const float* v1b = (const float*)d_in[7];
  const float* r1w = (const float*)d_in[8];
  const float* r1b = (const float*)d_in[9];
  const float* q2w = (const float*)d_in[10];
  const float* q2b = (const float*)d_in[11];
  const float* k2w = (const float*)d_in[12];
  const float* k2b = (const float*)d_in[13];
  const float* v2w = (const float*)d_in[14];
  const float* v2b = (const float*)d_in[15];
  const float* r2w = (const float*)d_in[16];
  const float* r2b = (const float*)d_in[17];
  const float* cw  = (const float*)d_in[18];
  const float* cbp = (const float*)d_in[19];
  float* out = (float*)d_out;

  // ws layout: [catH 128MB][catL 128MB][partials 17.3MB][derived]
  // WA (327 KB) aliases the partials region (dead after finalize).
  char* ws = (char*)d_ws;
  const size_t catB  = (size_t)B_ * 8 * N_ * 16 * 2;     // 128 MB each
  const size_t partB = (size_t)16 * CHUNKS * STATS * sizeof(float);
  __hip_bfloat16* catHp = (__hip_bfloat16*)ws;
  __hip_bfloat16* catLp = (__hip_bfloat16*)(ws + catB);
  float* part = (float*)(ws + 2 * catB);
  float* der  = (float*)(ws + 2 * catB + partB);
  __hip_bfloat16* WA = (__hip_bfloat16*)part;            // alias

  stats_kernel<<<dim3(CHUNKS, B_, 2), 256, 0, stream>>>(
      t1, t2, k1w, k1b, v1w, v1b, k2w, k2b, v2w, v2b, part);
  finalize_kernel<<<dim3(16), 256, 0, stream>>>(part, r1w, r2w, der);
  prep_wa_kernel<<<dim3(640), 256, 0, stream>>>(cw, WA);
  attn_kernel<<<dim3(N_ / 256, B_, 2), 256, 0, stream>>>(
      t1, t2, q1w, q1b, q2w, q2b, r1b, r2b, der, catHp, catLp);
  conv_mfma_kernel<<<dim3(4, 64, B_), 256, 0, stream>>>(
      catHp, catLp, WA, cbp, out);
}

// Round 6
// 1548.201 us; speedup vs baseline: 2.9879x; 2.3193x over previous
//
#include <hip/hip_runtime.h>
#include <hip/hip_bf16.h>

// Problem constants (fixed by setup_inputs)
constexpr int B_ = 8;
constexpr int C_ = 64;      // input channels = KC = VC = 64
constexpr int N_ = 65536;   // H*W = 256*256
constexpr int HW_ = 256;
constexpr float EPSF = 1e-6f;
constexpr int STATS = 4224; // 4096 matrix + 64 ksum + 64 vsum
constexpr int CHUNKS = 64;  // stats blocks per (branch,batch)

typedef __attribute__((ext_vector_type(8))) short bf16x8;
typedef __attribute__((ext_vector_type(4))) float f32x4;

// ================================================================
// Pass 1: per (branch,batch,chunk) compute partial Ksum/Vsum/matrix.
// (unchanged)
// ================================================================
__global__ __launch_bounds__(256, 2) void stats_kernel(
    const float* __restrict__ t1, const float* __restrict__ t2,
    const float* __restrict__ k1w, const float* __restrict__ k1b,
    const float* __restrict__ v1w, const float* __restrict__ v1b,
    const float* __restrict__ k2w, const float* __restrict__ k2b,
    const float* __restrict__ v2w, const float* __restrict__ v2b,
    float* __restrict__ partials)   // [2*B][CHUNKS][STATS]
{
  const int chunk = blockIdx.x;
  const int b = blockIdx.y;
  const int r = blockIdx.z;
  const float* x  = (r ? t2 : t1) + (size_t)b * C_ * N_;
  const float* kw = r ? k2w : k1w;
  const float* kb = r ? k2b : k1b;
  const float* vw = r ? v2w : v1w;
  const float* vb = r ? v2b : v1b;

  __shared__ float kwT[64 * 68];
  __shared__ float vwT[64 * 68];
  __shared__ float Kt[64 * 68];
  __shared__ float Vt[64 * 68];
  __shared__ float kb_s[64], vb_s[64];

  const int t = threadIdx.x;
  for (int idx = t; idx < 4096; idx += 256) {
    int m = idx >> 6, c = idx & 63;
    kwT[c * 68 + m] = kw[idx];
    vwT[c * 68 + m] = vw[idx];
  }
  if (t < 64) { kb_s[t] = kb[t]; vb_s[t] = vb[t]; }
  __syncthreads();

  const int mg = t & 3;       // channel group: channels mg*16 .. +16
  const int p  = t >> 2;      // pixel within tile (0..63)
  const int ty4 = (t >> 4) * 4;  // matrix-stage row base
  const int tx4 = (t & 15) * 4;  // matrix-stage col base

  float macc[16];
  float ksum[16], vsum[16];
#pragma unroll
  for (int i = 0; i < 16; ++i) { macc[i] = 0.f; ksum[i] = 0.f; vsum[i] = 0.f; }

  for (int tile = 0; tile < 16; ++tile) {
    const int n0 = chunk * 1024 + tile * 64;
    float kk[16], vv[16];
#pragma unroll
    for (int i = 0; i < 16; ++i) { kk[i] = kb_s[mg * 16 + i]; vv[i] = vb_s[mg * 16 + i]; }
    for (int c = 0; c < 64; ++c) {
      const float xv = x[(size_t)c * N_ + n0 + p];
#pragma unroll
      for (int i4 = 0; i4 < 4; ++i4) {
        const float4 wk = *(const float4*)&kwT[c * 68 + mg * 16 + i4 * 4];
        kk[i4 * 4 + 0] += wk.x * xv;
        kk[i4 * 4 + 1] += wk.y * xv;
        kk[i4 * 4 + 2] += wk.z * xv;
        kk[i4 * 4 + 3] += wk.w * xv;
        const float4 wvv = *(const float4*)&vwT[c * 68 + mg * 16 + i4 * 4];
        vv[i4 * 4 + 0] += wvv.x * xv;
        vv[i4 * 4 + 1] += wvv.y * xv;
        vv[i4 * 4 + 2] += wvv.z * xv;
        vv[i4 * 4 + 3] += wvv.w * xv;
      }
    }
    float ss = 0.f;
#pragma unroll
    for (int i = 0; i < 16; ++i) ss += kk[i] * kk[i];
    ss += __shfl_xor(ss, 1);
    ss += __shfl_xor(ss, 2);
    const float inv = rsqrtf(ss);
#pragma unroll
    for (int i = 0; i < 16; ++i) kk[i] *= inv;
#pragma unroll
    for (int i = 0; i < 16; ++i) { ksum[i] += kk[i]; vsum[i] += vv[i]; }

    __syncthreads();
#pragma unroll
    for (int i4 = 0; i4 < 4; ++i4) {
      *(float4*)&Kt[p * 68 + mg * 16 + i4 * 4] =
          make_float4(kk[i4 * 4 + 0], kk[i4 * 4 + 1], kk[i4 * 4 + 2], kk[i4 * 4 + 3]);
      *(float4*)&Vt[p * 68 + mg * 16 + i4 * 4] =
          make_float4(vv[i4 * 4 + 0], vv[i4 * 4 + 1], vv[i4 * 4 + 2], vv[i4 * 4 + 3]);
    }
    __syncthreads();
    for (int pp = 0; pp < 64; ++pp) {
      const float4 ka = *(const float4*)&Kt[pp * 68 + ty4];
      const float4 va = *(const float4*)&Vt[pp * 68 + tx4];
      macc[0]  += ka.x * va.x;  macc[1]  += ka.x * va.y;
      macc[2]  += ka.x * va.z;  macc[3]  += ka.x * va.w;
      macc[4]  += ka.y * va.x;  macc[5]  += ka.y * va.y;
      macc[6]  += ka.y * va.z;  macc[7]  += ka.y * va.w;
      macc[8]  += ka.z * va.x;  macc[9]  += ka.z * va.y;
      macc[10] += ka.z * va.z;  macc[11] += ka.z * va.w;
      macc[12] += ka.w * va.x;  macc[13] += ka.w * va.y;
      macc[14] += ka.w * va.z;  macc[15] += ka.w * va.w;
    }
  }

  float* pb = partials + ((size_t)(r * B_ + b) * CHUNKS + chunk) * STATS;
#pragma unroll
  for (int i = 0; i < 4; ++i)
#pragma unroll
    for (int j = 0; j < 4; ++j)
      pb[(ty4 + i) * 64 + tx4 + j] = macc[i * 4 + j];

  __syncthreads();
#pragma unroll
  for (int i4 = 0; i4 < 4; ++i4) {
    *(float4*)&Kt[p * 68 + mg * 16 + i4 * 4] =
        make_float4(ksum[i4 * 4 + 0], ksum[i4 * 4 + 1], ksum[i4 * 4 + 2], ksum[i4 * 4 + 3]);
    *(float4*)&Vt[p * 68 + mg * 16 + i4 * 4] =
        make_float4(vsum[i4 * 4 + 0], vsum[i4 * 4 + 1], vsum[i4 * 4 + 2], vsum[i4 * 4 + 3]);
  }
  __syncthreads();
  if (t < 64) {
    float s1 = 0.f, s2 = 0.f;
    for (int pp = 0; pp < 64; ++pp) { s1 += Kt[pp * 68 + t]; s2 += Vt[pp * 68 + t]; }
    pb[4096 + t] = s1;
    pb[4160 + t] = s2;
  }
}

// ================================================================
// Finalize: reduce partials, fold r_w in. (unchanged)
// ================================================================
__global__ void finalize_kernel(const float* __restrict__ partials,
                                const float* __restrict__ r1w,
                                const float* __restrict__ r2w,
                                float* __restrict__ derived)
{
  const int bb = blockIdx.x;           // r*8 + b
  const int r = bb >> 3;
  const float* rw = r ? r2w : r1w;
  __shared__ float mat[4096];
  __shared__ float ks[64], vs[64];
  const int t = threadIdx.x;
  const float* pb = partials + (size_t)bb * CHUNKS * STATS;
  for (int e = t; e < STATS; e += 256) {
    float s = 0.f;
    for (int j = 0; j < CHUNKS; ++j) s += pb[(size_t)j * STATS + e];
    if (e < 4096) mat[e] = s;
    else if (e < 4160) ks[e - 4096] = s;
    else vs[e - 4160] = s;
  }
  __syncthreads();
  float* der = derived + (size_t)bb * STATS;
  for (int e = t; e < 4096; e += 256) {
    const int o = e >> 6, m = e & 63;
    float s = 0.f;
    for (int c = 0; c < 64; ++c) s += rw[o * 64 + c] * mat[m * 64 + c];
    der[e] = s;
  }
  if (t < 64) {
    float s = 0.f;
    for (int c = 0; c < 64; ++c) s += rw[t * 64 + c] * vs[c];
    der[4096 + t] = s;
    der[4160 + t] = ks[t] + EPSF;
  }
}

// ================================================================
// Pass 2: per-pixel Q projection + attention output.
// ROUND-6 FIX: round 4/5's fully-unrolled 16-deep output loop created
// ~64 concurrent dot-product temps on top of live q[64]; allocator
// spilled q to scratch (VGPR=84, 7 GB phantom FETCH = scratch fill).
// Now: runtime (unroll-disabled) o2 loop, 2 outputs/iter (~16 temps),
// __launch_bounds__(256,2) for 256-VGPR headroom. Staging is
// column-major u32 LDS stg[plane][o2*257+t]: conflict-free writes,
// lane-consecutive scalar read-back, coalesced uint4 global stores.
// cat layout (unchanged): catH/catL [b][ch(8)][n][16ci], ch=r*4+o/16.
// ================================================================
__global__ __launch_bounds__(256, 2) void attn_kernel(
    const float* __restrict__ t1, const float* __restrict__ t2,
    const float* __restrict__ q1w, const float* __restrict__ q1b,
    const float* __restrict__ q2w, const float* __restrict__ q2b,
    const float* __restrict__ r1b, const float* __restrict__ r2b,
    const float* __restrict__ derived,
    __hip_bfloat16* __restrict__ catH, __hip_bfloat16* __restrict__ catL)
{
  const int b = blockIdx.y;
  const int rbr = blockIdx.z;
  const float* x  = (rbr ? t2 : t1) + (size_t)b * C_ * N_;
  const float* qw = rbr ? q2w : q1w;
  const float* qb = rbr ? q2b : q1b;
  const float* rb = rbr ? r2b : r1b;
  const float* der = derived + (size_t)(rbr * B_ + b) * STATS;

  __shared__ float qwT[64 * 68];
  __shared__ float rm[4096];
  __shared__ float rvs[64], kse[64], rbs[64], qbs[64];
  __shared__ unsigned stg[2][8 * 257];   // [hi/lo][o2*257 + t], 16.4 KB

  const int t = threadIdx.x;
  for (int idx = t; idx < 4096; idx += 256) {
    int m = idx >> 6, c = idx & 63;
    qwT[c * 68 + m] = qw[idx];
    rm[idx] = der[idx];
  }
  if (t < 64) {
    rvs[t] = der[4096 + t];
    kse[t] = der[4160 + t];
    rbs[t] = rb[t];
    qbs[t] = qb[t];
  }
  __syncthreads();

  const int n = blockIdx.x * 256 + t;
  float q[64];
#pragma unroll
  for (int m = 0; m < 64; ++m) q[m] = qbs[m];
  for (int c = 0; c < 64; ++c) {
    const float xv = x[(size_t)c * N_ + n];
#pragma unroll
    for (int m4 = 0; m4 < 16; ++m4) {
      const float4 w = *(const float4*)&qwT[c * 68 + m4 * 4];
      q[m4 * 4 + 0] += w.x * xv;
      q[m4 * 4 + 1] += w.y * xv;
      q[m4 * 4 + 2] += w.z * xv;
      q[m4 * 4 + 3] += w.w * xv;
    }
  }
  float s0 = 0.f, s1 = 0.f, s2 = 0.f, s3 = 0.f;
#pragma unroll
  for (int m = 0; m < 64; m += 4) {
    s0 += q[m] * q[m];  s1 += q[m + 1] * q[m + 1];
    s2 += q[m + 2] * q[m + 2];  s3 += q[m + 3] * q[m + 3];
  }
  const float inv = rsqrtf((s0 + s1) + (s2 + s3));
  float d0 = 0.f, d1 = 0.f, d2 = 0.f, d3 = 0.f;
#pragma unroll
  for (int m = 0; m < 64; m += 4) {
    d0 += q[m] * kse[m];  d1 += q[m + 1] * kse[m + 1];
    d2 += q[m + 2] * kse[m + 2];  d3 += q[m + 3] * kse[m + 3];
  }
  const float rden = 1.0f / (65536.0f + inv * ((d0 + d1) + (d2 + d3)));
  const float f1 = rden * inv;

#pragma clang loop unroll(disable)
  for (int og = 0; og < 4; ++og) {
    __syncthreads();   // previous og's staging reads finished
#pragma clang loop unroll(disable)
    for (int o2 = 0; o2 < 8; ++o2) {
      const int o = og * 16 + 2 * o2;
      float a0 = 0.f, a1 = 0.f, a2 = 0.f, a3 = 0.f;
      float b0 = 0.f, b1 = 0.f, b2 = 0.f, b3 = 0.f;
      const float* r0 = &rm[o * 64];
      const float* r1 = &rm[(o + 1) * 64];
#pragma unroll
      for (int m4 = 0; m4 < 16; ++m4) {
        const float4 w0 = *(const float4*)&r0[m4 * 4];
        const float4 w1 = *(const float4*)&r1[m4 * 4];
        a0 += w0.x * q[m4 * 4 + 0];  a1 += w0.y * q[m4 * 4 + 1];
        a2 += w0.z * q[m4 * 4 + 2];  a3 += w0.w * q[m4 * 4 + 3];
        b0 += w1.x * q[m4 * 4 + 0];  b1 += w1.y * q[m4 * 4 + 1];
        b2 += w1.z * q[m4 * 4 + 2];  b3 += w1.w * q[m4 * 4 + 3];
      }
      const float av0 = f1 * ((a0 + a1) + (a2 + a3)) + rden * rvs[o] + rbs[o];
      const float av1 = f1 * ((b0 + b1) + (b2 + b3)) + rden * rvs[o + 1] + rbs[o + 1];
      // bf16 hi/lo split, RNE, pure bit arithmetic
      const unsigned u0 = __float_as_uint(av0);
      const unsigned h0 = (u0 + 0x7fffu + ((u0 >> 16) & 1u)) >> 16;
      const unsigned ul0 = __float_as_uint(av0 - __uint_as_float(h0 << 16));
      const unsigned l0 = (ul0 + 0x7fffu + ((ul0 >> 16) & 1u)) >> 16;
      const unsigned u1 = __float_as_uint(av1);
      const unsigned h1 = (u1 + 0x7fffu + ((u1 >> 16) & 1u)) >> 16;
      const unsigned ul1 = __float_as_uint(av1 - __uint_as_float(h1 << 16));
      const unsigned l1 = (ul1 + 0x7fffu + ((ul1 >> 16) & 1u)) >> 16;
      stg[0][o2 * 257 + t] = h0 | (h1 << 16);
      stg[1][o2 * 257 + t] = l0 | (l1 << 16);
    }
    __syncthreads();
    const int ch = rbr * 4 + og;
    const size_t base = (((size_t)(b * 8 + ch)) * N_ + n) * 16;
    uint4 v0, v1;
    v0.x = stg[0][0 * 257 + t]; v0.y = stg[0][1 * 257 + t];
    v0.z = stg[0][2 * 257 + t]; v0.w = stg[0][3 * 257 + t];
    v1.x = stg[0][4 * 257 + t]; v1.y = stg[0][5 * 257 + t];
    v1.z = stg[0][6 * 257 + t]; v1.w = stg[0][7 * 257 + t];
    uint4* dh = (uint4*)(catH + base);
    dh[0] = v0; dh[1] = v1;
    v0.x = stg[1][0 * 257 + t]; v0.y = stg[1][1 * 257 + t];
    v0.z = stg[1][2 * 257 + t]; v0.w = stg[1][3 * 257 + t];
    v1.x = stg[1][4 * 257 + t]; v1.y = stg[1][5 * 257 + t];
    v1.z = stg[1][6 * 257 + t]; v1.w = stg[1][7 * 257 + t];
    uint4* dl = (uint4*)(catL + base);
    dl[0] = v0; dl[1] = v1;
  }
}

// ================================================================
// Prearrange conv weights into exact MFMA A-fragment order, split
// bf16 hi/lo.  WA[c(8)][s(5)][v(2)][ot(4)][lane(64)][j(8)] bf16.
// (unchanged)
// ================================================================
__global__ void prep_wa_kernel(const float* __restrict__ cw,
                               __hip_bfloat16* __restrict__ WA) {
  const int e = blockIdx.x * 256 + threadIdx.x;   // 163840 total
  if (e >= 8 * 5 * 2 * 4 * 512) return;
  const int j    = e & 7;
  const int lane = (e >> 3) & 63;
  const int f    = e >> 9;
  const int ot   = f & 3;
  const int v    = (f >> 2) & 1;
  const int s    = (f >> 3) % 5;
  const int c    = (f >> 3) / 5;
  const int o    = ot * 16 + (lane & 15);
  const int g    = lane >> 4;
  const int tap  = 2 * s + (g >> 1);
  float val = 0.f;
  if (tap <= 8) {
    const int ci = c * 16 + (g & 1) * 8 + j;
    val = cw[(size_t)(o * 128 + ci) * 9 + tap];
  }
  __hip_bfloat16 h = __float2bfloat16(val);
  if (v) h = __float2bfloat16(val - __bfloat162float(h));
  WA[e] = h;
}

// ================================================================
// Pass 3: 3x3 conv via MFMA implicit GEMM, split-bf16. (unchanged)
// ================================================================
__global__ __launch_bounds__(256, 3) void conv_mfma_kernel(
    const __hip_bfloat16* __restrict__ catH,
    const __hip_bfloat16* __restrict__ catL,
    const __hip_bfloat16* __restrict__ WA,
    const float* __restrict__ cb,
    float* __restrict__ out)
{
  __shared__ __hip_bfloat16 XsH[6 * 68 * 24];
  __shared__ __hip_bfloat16 XsL[6 * 68 * 24];

  const int t  = threadIdx.x;
  const int w  = t >> 6;       // wave id = output row 0..3
  const int l  = t & 63;
  const int li = l & 15;
  const int g  = l >> 4;
  const int x0 = blockIdx.x * 64;
  const int y0 = blockIdx.y * 4;
  const int b  = blockIdx.z;

  f32x4 acc[4][4];
#pragma unroll
  for (int i = 0; i < 4; ++i)
#pragma unroll
    for (int k = 0; k < 4; ++k) acc[i][k] = (f32x4){0.f, 0.f, 0.f, 0.f};

  for (int c = 0; c < 8; ++c) {
    __syncthreads();
    // ---- stage X chunk: 6 rows x 66 cols x 16 ci, hi+lo ----
    for (int idx = t; idx < 396; idx += 256) {
      const int row = idx / 66;
      const int col = idx - row * 66;
      const int gy = y0 + row - 1;
      const int gx = x0 + col - 1;
      uint4 vh0 = {0,0,0,0}, vh1 = {0,0,0,0};
      uint4 vl0 = {0,0,0,0}, vl1 = {0,0,0,0};
      if ((unsigned)gy < 256u && (unsigned)gx < 256u) {
        const size_t base = (((size_t)(b * 8 + c)) * N_ + (gy * HW_ + gx)) * 16;
        const uint4* ph = (const uint4*)(catH + base);
        vh0 = ph[0]; vh1 = ph[1];
        const uint4* pl = (const uint4*)(catL + base);
        vl0 = pl[0]; vl1 = pl[1];
      }
      const int le = (row * 68 + col) * 24;
      *(uint4*)(&XsH[le]) = vh0; *(uint4*)(&XsH[le + 8]) = vh1;
      *(uint4*)(&XsL[le]) = vl0; *(uint4*)(&XsL[le + 8]) = vl1;
    }
    __syncthreads();

    const __hip_bfloat16* wa_c = WA + (size_t)c * 20480;
#pragma unroll
    for (int s = 0; s < 5; ++s) {
      const __hip_bfloat16* wa_s = wa_c + s * 4096 + l * 8;
      bf16x8 aH[4], aL[4];
#pragma unroll
      for (int ot = 0; ot < 4; ++ot) aH[ot] = *(const bf16x8*)(wa_s + ot * 512);
#pragma unroll
      for (int ot = 0; ot < 4; ++ot) aL[ot] = *(const bf16x8*)(wa_s + 2048 + ot * 512);

      int tap = 2 * s + (g >> 1);
      if (tap > 8) tap = 0;            // A is zero there; any valid addr
      const int ky = tap / 3;
      const int kx = tap - ky * 3;
      const int e0 = ((w + ky) * 68 + li + kx) * 24 + (g & 1) * 8;
      bf16x8 bH[4], bL[4];
#pragma unroll
      for (int pt = 0; pt < 4; ++pt) bH[pt] = *(const bf16x8*)(&XsH[e0 + pt * 384]);
#pragma unroll
      for (int pt = 0; pt < 4; ++pt) bL[pt] = *(const bf16x8*)(&XsL[e0 + pt * 384]);

#pragma unroll
      for (int ot = 0; ot < 4; ++ot)
#pragma unroll
        for (int pt = 0; pt < 4; ++pt) {
          acc[ot][pt] = __builtin_amdgcn_mfma_f32_16x16x32_bf16(
              aH[ot], bH[pt], acc[ot][pt], 0, 0, 0);
          acc[ot][pt] = __builtin_amdgcn_mfma_f32_16x16x32_bf16(
              aH[ot], bL[pt], acc[ot][pt], 0, 0, 0);
          acc[ot][pt] = __builtin_amdgcn_mfma_f32_16x16x32_bf16(
              aL[ot], bH[pt], acc[ot][pt], 0, 0, 0);
        }
    }
  }

  // ---- epilogue: D[m=o][n=p], m=(l>>4)*4+reg, n=l&15 ----
#pragma unroll
  for (int ot = 0; ot < 4; ++ot)
#pragma unroll
    for (int r = 0; r < 4; ++r) {
      const int o = ot * 16 + g * 4 + r;
      const float bv = cb[o];
      float* orow = out + ((size_t)b * 64 + o) * N_ + (size_t)(y0 + w) * HW_ + x0 + li;
#pragma unroll
      for (int pt = 0; pt < 4; ++pt)
        orow[pt * 16] = acc[ot][pt][r] + bv;
    }
}

// ================================================================
extern "C" void kernel_launch(void* const* d_in, const int* in_sizes, int n_in,
                              void* d_out, int out_size, void* d_ws, size_t ws_size,
                              hipStream_t stream) {
  const float* t1  = (const float*)d_in[0];
  const float* t2  = (const float*)d_in[1];
  const float* q1w = (const float*)d_in[2];
  const float* q1b = (const float*)d_in[3];
  const float* k1w = (const float*)d_in[4];
  const float* k1b = (const float*)d_in[5];
  const float* v1w = (const float*)d_in[6];
  const float* v1b = (const float*)d_in[7];
  const float* r1w = (const float*)d_in[8];
  const float* r1b = (const float*)d_in[9];
  const float* q2w = (const float*)d_in[10];
  const float* q2b = (const float*)d_in[11];
  const float* k2w = (const float*)d_in[12];
  const float* k2b = (const float*)d_in[13];
  const float* v2w = (const float*)d_in[14];
  const float* v2b = (const float*)d_in[15];
  const float* r2w = (const float*)d_in[16];
  const float* r2b = (const float*)d_in[17];
  const float* cw  = (const float*)d_in[18];
  const float* cbp = (const float*)d_in[19];
  float* out = (float*)d_out;

  // ws layout: [catH 128MB][catL 128MB][partials 17.3MB][derived]
  // WA (327 KB) aliases the partials region (dead after finalize).
  char* ws = (char*)d_ws;
  const size_t catB  = (size_t)B_ * 8 * N_ * 16 * 2;     // 128 MB each
  const size_t partB = (size_t)16 * CHUNKS * STATS * sizeof(float);
  __hip_bfloat16* catHp = (__hip_bfloat16*)ws;
  __hip_bfloat16* catLp = (__hip_bfloat16*)(ws + catB);
  float* part = (float*)(ws + 2 * catB);
  float* der  = (float*)(ws + 2 * catB + partB);
  __hip_bfloat16* WA = (__hip_bfloat16*)part;            // alias

  stats_kernel<<<dim3(CHUNKS, B_, 2), 256, 0, stream>>>(
      t1, t2, k1w, k1b, v1w, v1b, k2w, k2b, v2w, v2b, part);
  finalize_kernel<<<dim3(16), 256, 0, stream>>>(part, r1w, r2w, der);
  prep_wa_kernel<<<dim3(640), 256, 0, stream>>>(cw, WA);
  attn_kernel<<<dim3(N_ / 256, B_, 2), 256, 0, stream>>>(
      t1, t2, q1w, q1b, q2w, q2b, r1b, r2b, der, catHp, catLp);
  conv_mfma_kernel<<<dim3(4, 64, B_), 256, 0, stream>>>(
      catHp, catLp, WA, cbp, out);
}

// Round 7
// 1011.709 us; speedup vs baseline: 4.5724x; 1.5303x over previous
//
#include <hip/hip_runtime.h>
#include <hip/hip_bf16.h>

// Problem constants (fixed by setup_inputs)
constexpr int B_ = 8;
constexpr int C_ = 64;      // input channels = KC = VC = 64
constexpr int N_ = 65536;   // H*W = 256*256
constexpr int HW_ = 256;
constexpr float EPSF = 1e-6f;
constexpr int STATS = 4224; // 4096 matrix + 64 ksum + 64 vsum
constexpr int CHUNKS = 64;  // stats blocks per (branch,batch)

typedef __attribute__((ext_vector_type(8))) short bf16x8;
typedef __attribute__((ext_vector_type(4))) float f32x4;

// RNE fp32 -> bf16 bits, pure bit arithmetic (no address-taken locals)
__device__ __forceinline__ unsigned short f2bf(float f) {
  const unsigned u = __float_as_uint(f);
  return (unsigned short)((u + 0x7fffu + ((u >> 16) & 1u)) >> 16);
}

// ================================================================
// prep_proj: K/V projection weights -> MFMA A-fragment order, bf16.
// WK[r(2)][kv(2)][ot(4)][ks(2)][lane(64)][j(8)]  (16384 bf16, 32 KB)
// A-frag (16x16x32): m = ot*16 + (lane&15), ch = ks*32 + (lane>>4)*8 + j
// ================================================================
__global__ void prep_proj_kernel(const float* __restrict__ k1w,
                                 const float* __restrict__ v1w,
                                 const float* __restrict__ k2w,
                                 const float* __restrict__ v2w,
                                 unsigned short* __restrict__ WK) {
  const int e = blockIdx.x * 256 + threadIdx.x;   // 16384 total
  if (e >= 16384) return;
  const int j    = e & 7;
  const int lane = (e >> 3) & 63;
  const int ks   = (e >> 9) & 1;
  const int ot   = (e >> 10) & 3;
  const int kv   = (e >> 12) & 1;
  const int r    = (e >> 13) & 1;
  const int m    = ot * 16 + (lane & 15);
  const int ch   = ks * 32 + ((lane >> 4) & 3) * 8 + j;
  const float* w = r ? (kv ? v2w : k2w) : (kv ? v1w : k1w);
  WK[e] = f2bf(w[m * 64 + ch]);
}

// ================================================================
// Pass 1 (REWRITTEN, MFMA): per (branch,batch,chunk) partial
// Ksum/Vsum/matrix. Block 256 thr / 4 waves; 16 iters x 64 px.
// Per iter: stage x->Xs bf16 [px][72ch] (ch XOR-swizzled by px>>4 so
// frag reads stay contiguous); wave w projects px-tile w (K: bias,
// wave-parallel shfl norm; V: bias), writes Khat/V bf16 -> Ks/Vs
// [row][72px]; matrix mfma: wave w rows w*16..+15 x all 64 V-rows
// over k=64 px. ksum/vsum via ones-vector MFMA (row sums for free).
// Partials layout unchanged -> finalize untouched.
// ================================================================
__global__ __launch_bounds__(256, 2) void stats_mfma_kernel(
    const float* __restrict__ t1, const float* __restrict__ t2,
    const float* __restrict__ k1b, const float* __restrict__ v1b,
    const float* __restrict__ k2b, const float* __restrict__ v2b,
    const unsigned short* __restrict__ WK,
    float* __restrict__ partials)
{
  const int chunk = blockIdx.x;
  const int b = blockIdx.y;
  const int r = blockIdx.z;
  const float* x  = (r ? t2 : t1) + (size_t)b * C_ * N_;
  const float* kb = r ? k2b : k1b;
  const float* vb = r ? v2b : v1b;
  const unsigned short* WKr = WK + r * 8192;      // [kv][ot][ks][lane][j]

  __shared__ unsigned short Xs[64 * 72];
  __shared__ unsigned short Ks[64 * 72];
  __shared__ unsigned short Vs[64 * 72];

  const int t  = threadIdx.x;
  const int w  = t >> 6;        // wave id: px-tile + matrix row-tile
  const int l  = t & 63;
  const int li = l & 15;
  const int g  = l >> 4;

  // bias preload (row = ot*16 + g*4 + rg for this lane's C-rows)
  float kbv[4][4], vbv[4][4];
#pragma unroll
  for (int ot = 0; ot < 4; ++ot)
#pragma unroll
    for (int rg = 0; rg < 4; ++rg) {
      kbv[ot][rg] = kb[ot * 16 + g * 4 + rg];
      vbv[ot][rg] = vb[ot * 16 + g * 4 + rg];
    }

  bf16x8 ones;
#pragma unroll
  for (int j = 0; j < 8; ++j) ones[j] = (short)0x3F80;   // bf16 1.0

  f32x4 accM[4];                 // matrix tiles (mt=w, ct=0..3)
#pragma unroll
  for (int ct = 0; ct < 4; ++ct) accM[ct] = (f32x4){0.f, 0.f, 0.f, 0.f};
  f32x4 accSk = (f32x4){0.f, 0.f, 0.f, 0.f};   // ksum rows w*16..
  f32x4 accSv = (f32x4){0.f, 0.f, 0.f, 0.f};   // vsum rows w*16..

  for (int it = 0; it < 16; ++it) {
    const int px0 = chunk * 1024 + it * 64;
    __syncthreads();             // prev iter's Xs/Ks/Vs reads done

    // ---- stage X: 64 ch x 64 px fp32 -> bf16 Xs[px][ch^((px>>4)<<4)]
    {
      const int ch = t >> 2;
      const int ps = t & 3;
      const float* src = x + (size_t)ch * N_ + px0 + ps * 16;
      const float4 f0 = ((const float4*)src)[0];
      const float4 f1 = ((const float4*)src)[1];
      const float4 f2 = ((const float4*)src)[2];
      const float4 f3 = ((const float4*)src)[3];
      float v[16] = {f0.x, f0.y, f0.z, f0.w, f1.x, f1.y, f1.z, f1.w,
                     f2.x, f2.y, f2.z, f2.w, f3.x, f3.y, f3.z, f3.w};
      unsigned short* dst = &Xs[(ps * 16) * 72 + (ch ^ (ps << 4))];
#pragma unroll
      for (int i = 0; i < 16; ++i) dst[i * 72] = f2bf(v[i]);
    }
    __syncthreads();

    // ---- projection: B-frags from Xs (px = w*16+li, swizzle key w)
    bf16x8 bx0 = *(const bf16x8*)&Xs[(w * 16 + li) * 72 + ((g * 8) ^ (w << 4))];
    bf16x8 bx1 = *(const bf16x8*)&Xs[(w * 16 + li) * 72 + ((32 + g * 8) ^ (w << 4))];

    // K = kw*x + kb, then l2-normalize over the 64 rows per pixel
    f32x4 ka[4];
#pragma unroll
    for (int ot = 0; ot < 4; ++ot) {
      f32x4 a = (f32x4){0.f, 0.f, 0.f, 0.f};
      const bf16x8 w0 = *(const bf16x8*)(WKr + ((ot * 2 + 0) * 64 + l) * 8);
      const bf16x8 w1 = *(const bf16x8*)(WKr + ((ot * 2 + 1) * 64 + l) * 8);
      a = __builtin_amdgcn_mfma_f32_16x16x32_bf16(w0, bx0, a, 0, 0, 0);
      a = __builtin_amdgcn_mfma_f32_16x16x32_bf16(w1, bx1, a, 0, 0, 0);
      ka[ot] = a;
    }
    float ss = 0.f;
#pragma unroll
    for (int ot = 0; ot < 4; ++ot)
#pragma unroll
      for (int rg = 0; rg < 4; ++rg) {
        const float v2 = ka[ot][rg] + kbv[ot][rg];
        ka[ot][rg] = v2;
        ss += v2 * v2;
      }
    ss += __shfl_xor(ss, 16);
    ss += __shfl_xor(ss, 32);
    const float inv = rsqrtf(ss);
#pragma unroll
    for (int ot = 0; ot < 4; ++ot)
#pragma unroll
      for (int rg = 0; rg < 4; ++rg)
        Ks[(ot * 16 + g * 4 + rg) * 72 + w * 16 + li] = f2bf(ka[ot][rg] * inv);

    // V = vw*x + vb
#pragma unroll
    for (int ot = 0; ot < 4; ++ot) {
      f32x4 a = (f32x4){0.f, 0.f, 0.f, 0.f};
      const bf16x8 w0 = *(const bf16x8*)(WKr + 4096 + ((ot * 2 + 0) * 64 + l) * 8);
      const bf16x8 w1 = *(const bf16x8*)(WKr + 4096 + ((ot * 2 + 1) * 64 + l) * 8);
      a = __builtin_amdgcn_mfma_f32_16x16x32_bf16(w0, bx0, a, 0, 0, 0);
      a = __builtin_amdgcn_mfma_f32_16x16x32_bf16(w1, bx1, a, 0, 0, 0);
#pragma unroll
      for (int rg = 0; rg < 4; ++rg)
        Vs[(ot * 16 + g * 4 + rg) * 72 + w * 16 + li] = f2bf(a[rg] + vbv[ot][rg]);
    }
    __syncthreads();

    // ---- matrix: mat[m][c] += Khat[m,px] V[c,px], k-dim = 64 px
#pragma unroll
    for (int ks = 0; ks < 2; ++ks) {
      const int ko = ks * 32 + g * 8;
      const bf16x8 aK = *(const bf16x8*)&Ks[(w * 16 + li) * 72 + ko];
      const bf16x8 aV = *(const bf16x8*)&Vs[(w * 16 + li) * 72 + ko];
      accSk = __builtin_amdgcn_mfma_f32_16x16x32_bf16(aK, ones, accSk, 0, 0, 0);
      accSv = __builtin_amdgcn_mfma_f32_16x16x32_bf16(aV, ones, accSv, 0, 0, 0);
#pragma unroll
      for (int ct = 0; ct < 4; ++ct) {
        const bf16x8 bV = *(const bf16x8*)&Vs[(ct * 16 + li) * 72 + ko];
        accM[ct] = __builtin_amdgcn_mfma_f32_16x16x32_bf16(aK, bV, accM[ct], 0, 0, 0);
      }
    }
  }

  // ---- write partials (layout identical to original stats kernel)
  float* pb = partials + ((size_t)(r * B_ + b) * CHUNKS + chunk) * STATS;
#pragma unroll
  for (int ct = 0; ct < 4; ++ct)
#pragma unroll
    for (int rg = 0; rg < 4; ++rg)
      pb[(w * 16 + g * 4 + rg) * 64 + ct * 16 + li] = accM[ct][rg];
  if (li == 0) {
#pragma unroll
    for (int rg = 0; rg < 4; ++rg) {
      pb[4096 + w * 16 + g * 4 + rg] = accSk[rg];
      pb[4160 + w * 16 + g * 4 + rg] = accSv[rg];
    }
  }
}

// ================================================================
// Finalize: reduce partials, fold r_w in. (unchanged)
// ================================================================
__global__ void finalize_kernel(const float* __restrict__ partials,
                                const float* __restrict__ r1w,
                                const float* __restrict__ r2w,
                                float* __restrict__ derived)
{
  const int bb = blockIdx.x;           // r*8 + b
  const int r = bb >> 3;
  const float* rw = r ? r2w : r1w;
  __shared__ float mat[4096];
  __shared__ float ks[64], vs[64];
  const int t = threadIdx.x;
  const float* pb = partials + (size_t)bb * CHUNKS * STATS;
  for (int e = t; e < STATS; e += 256) {
    float s = 0.f;
    for (int j = 0; j < CHUNKS; ++j) s += pb[(size_t)j * STATS + e];
    if (e < 4096) mat[e] = s;
    else if (e < 4160) ks[e - 4096] = s;
    else vs[e - 4160] = s;
  }
  __syncthreads();
  float* der = derived + (size_t)bb * STATS;
  for (int e = t; e < 4096; e += 256) {
    const int o = e >> 6, m = e & 63;
    float s = 0.f;
    for (int c = 0; c < 64; ++c) s += rw[o * 64 + c] * mat[m * 64 + c];
    der[e] = s;
  }
  if (t < 64) {
    float s = 0.f;
    for (int c = 0; c < 64; ++c) s += rw[t * 64 + c] * vs[c];
    der[4096 + t] = s;
    der[4160 + t] = ks[t] + EPSF;
  }
}

// ================================================================
// Pass 2: per-pixel Q projection + attention output. (unchanged)
// ================================================================
__global__ __launch_bounds__(256, 2) void attn_kernel(
    const float* __restrict__ t1, const float* __restrict__ t2,
    const float* __restrict__ q1w, const float* __restrict__ q1b,
    const float* __restrict__ q2w, const float* __restrict__ q2b,
    const float* __restrict__ r1b, const float* __restrict__ r2b,
    const float* __restrict__ derived,
    __hip_bfloat16* __restrict__ catH, __hip_bfloat16* __restrict__ catL)
{
  const int b = blockIdx.y;
  const int rbr = blockIdx.z;
  const float* x  = (rbr ? t2 : t1) + (size_t)b * C_ * N_;
  const float* qw = rbr ? q2w : q1w;
  const float* qb = rbr ? q2b : q1b;
  const float* rb = rbr ? r2b : r1b;
  const float* der = derived + (size_t)(rbr * B_ + b) * STATS;

  __shared__ float qwT[64 * 68];
  __shared__ float rm[4096];
  __shared__ float rvs[64], kse[64], rbs[64], qbs[64];
  __shared__ unsigned stg[2][8 * 257];   // [hi/lo][o2*257 + t]

  const int t = threadIdx.x;
  for (int idx = t; idx < 4096; idx += 256) {
    int m = idx >> 6, c = idx & 63;
    qwT[c * 68 + m] = qw[idx];
    rm[idx] = der[idx];
  }
  if (t < 64) {
    rvs[t] = der[4096 + t];
    kse[t] = der[4160 + t];
    rbs[t] = rb[t];
    qbs[t] = qb[t];
  }
  __syncthreads();

  const int n = blockIdx.x * 256 + t;
  float q[64];
#pragma unroll
  for (int m = 0; m < 64; ++m) q[m] = qbs[m];
  for (int c = 0; c < 64; ++c) {
    const float xv = x[(size_t)c * N_ + n];
#pragma unroll
    for (int m4 = 0; m4 < 16; ++m4) {
      const float4 w = *(const float4*)&qwT[c * 68 + m4 * 4];
      q[m4 * 4 + 0] += w.x * xv;
      q[m4 * 4 + 1] += w.y * xv;
      q[m4 * 4 + 2] += w.z * xv;
      q[m4 * 4 + 3] += w.w * xv;
    }
  }
  float s0 = 0.f, s1 = 0.f, s2 = 0.f, s3 = 0.f;
#pragma unroll
  for (int m = 0; m < 64; m += 4) {
    s0 += q[m] * q[m];  s1 += q[m + 1] * q[m + 1];
    s2 += q[m + 2] * q[m + 2];  s3 += q[m + 3] * q[m + 3];
  }
  const float inv = rsqrtf((s0 + s1) + (s2 + s3));
  float d0 = 0.f, d1 = 0.f, d2 = 0.f, d3 = 0.f;
#pragma unroll
  for (int m = 0; m < 64; m += 4) {
    d0 += q[m] * kse[m];  d1 += q[m + 1] * kse[m + 1];
    d2 += q[m + 2] * kse[m + 2];  d3 += q[m + 3] * kse[m + 3];
  }
  const float rden = 1.0f / (65536.0f + inv * ((d0 + d1) + (d2 + d3)));
  const float f1 = rden * inv;

#pragma clang loop unroll(disable)
  for (int og = 0; og < 4; ++og) {
    __syncthreads();   // previous og's staging reads finished
#pragma clang loop unroll(disable)
    for (int o2 = 0; o2 < 8; ++o2) {
      const int o = og * 16 + 2 * o2;
      float a0 = 0.f, a1 = 0.f, a2 = 0.f, a3 = 0.f;
      float b0 = 0.f, b1 = 0.f, b2 = 0.f, b3 = 0.f;
      const float* r0 = &rm[o * 64];
      const float* r1 = &rm[(o + 1) * 64];
#pragma unroll
      for (int m4 = 0; m4 < 16; ++m4) {
        const float4 w0 = *(const float4*)&r0[m4 * 4];
        const float4 w1 = *(const float4*)&r1[m4 * 4];
        a0 += w0.x * q[m4 * 4 + 0];  a1 += w0.y * q[m4 * 4 + 1];
        a2 += w0.z * q[m4 * 4 + 2];  a3 += w0.w * q[m4 * 4 + 3];
        b0 += w1.x * q[m4 * 4 + 0];  b1 += w1.y * q[m4 * 4 + 1];
        b2 += w1.z * q[m4 * 4 + 2];  b3 += w1.w * q[m4 * 4 + 3];
      }
      const float av0 = f1 * ((a0 + a1) + (a2 + a3)) + rden * rvs[o] + rbs[o];
      const float av1 = f1 * ((b0 + b1) + (b2 + b3)) + rden * rvs[o + 1] + rbs[o + 1];
      const unsigned u0 = __float_as_uint(av0);
      const unsigned h0 = (u0 + 0x7fffu + ((u0 >> 16) & 1u)) >> 16;
      const unsigned ul0 = __float_as_uint(av0 - __uint_as_float(h0 << 16));
      const unsigned l0 = (ul0 + 0x7fffu + ((ul0 >> 16) & 1u)) >> 16;
      const unsigned u1 = __float_as_uint(av1);
      const unsigned h1 = (u1 + 0x7fffu + ((u1 >> 16) & 1u)) >> 16;
      const unsigned ul1 = __float_as_uint(av1 - __uint_as_float(h1 << 16));
      const unsigned l1 = (ul1 + 0x7fffu + ((ul1 >> 16) & 1u)) >> 16;
      stg[0][o2 * 257 + t] = h0 | (h1 << 16);
      stg[1][o2 * 257 + t] = l0 | (l1 << 16);
    }
    __syncthreads();
    const int ch = rbr * 4 + og;
    const size_t base = (((size_t)(b * 8 + ch)) * N_ + n) * 16;
    uint4 v0, v1;
    v0.x = stg[0][0 * 257 + t]; v0.y = stg[0][1 * 257 + t];
    v0.z = stg[0][2 * 257 + t]; v0.w = stg[0][3 * 257 + t];
    v1.x = stg[0][4 * 257 + t]; v1.y = stg[0][5 * 257 + t];
    v1.z = stg[0][6 * 257 + t]; v1.w = stg[0][7 * 257 + t];
    uint4* dh = (uint4*)(catH + base);
    dh[0] = v0; dh[1] = v1;
    v0.x = stg[1][0 * 257 + t]; v0.y = stg[1][1 * 257 + t];
    v0.z = stg[1][2 * 257 + t]; v0.w = stg[1][3 * 257 + t];
    v1.x = stg[1][4 * 257 + t]; v1.y = stg[1][5 * 257 + t];
    v1.z = stg[1][6 * 257 + t]; v1.w = stg[1][7 * 257 + t];
    uint4* dl = (uint4*)(catL + base);
    dl[0] = v0; dl[1] = v1;
  }
}

// ================================================================
// Prearrange conv weights into MFMA A-fragment order, split bf16
// hi/lo. WA[c(8)][s(5)][v(2)][ot(4)][lane(64)][j(8)]. (unchanged)
// ================================================================
__global__ void prep_wa_kernel(const float* __restrict__ cw,
                               __hip_bfloat16* __restrict__ WA) {
  const int e = blockIdx.x * 256 + threadIdx.x;   // 163840 total
  if (e >= 8 * 5 * 2 * 4 * 512) return;
  const int j    = e & 7;
  const int lane = (e >> 3) & 63;
  const int f    = e >> 9;
  const int ot   = f & 3;
  const int v    = (f >> 2) & 1;
  const int s    = (f >> 3) % 5;
  const int c    = (f >> 3) / 5;
  const int o    = ot * 16 + (lane & 15);
  const int g    = lane >> 4;
  const int tap  = 2 * s + (g >> 1);
  float val = 0.f;
  if (tap <= 8) {
    const int ci = c * 16 + (g & 1) * 8 + j;
    val = cw[(size_t)(o * 128 + ci) * 9 + tap];
  }
  __hip_bfloat16 h = __float2bfloat16(val);
  if (v) h = __float2bfloat16(val - __bfloat162float(h));
  WA[e] = h;
}

// ================================================================
// Pass 3: 3x3 conv via MFMA implicit GEMM, split-bf16. (unchanged)
// ================================================================
__global__ __launch_bounds__(256, 3) void conv_mfma_kernel(
    const __hip_bfloat16* __restrict__ catH,
    const __hip_bfloat16* __restrict__ catL,
    const __hip_bfloat16* __restrict__ WA,
    const float* __restrict__ cb,
    float* __restrict__ out)
{
  __shared__ __hip_bfloat16 XsH[6 * 68 * 24];
  __shared__ __hip_bfloat16 XsL[6 * 68 * 24];

  const int t  = threadIdx.x;
  const int w  = t >> 6;       // wave id = output row 0..3
  const int l  = t & 63;
  const int li = l & 15;
  const int g  = l >> 4;
  const int x0 = blockIdx.x * 64;
  const int y0 = blockIdx.y * 4;
  const int b  = blockIdx.z;

  f32x4 acc[4][4];
#pragma unroll
  for (int i = 0; i < 4; ++i)
#pragma unroll
    for (int k = 0; k < 4; ++k) acc[i][k] = (f32x4){0.f, 0.f, 0.f, 0.f};

  for (int c = 0; c < 8; ++c) {
    __syncthreads();
    for (int idx = t; idx < 396; idx += 256) {
      const int row = idx / 66;
      const int col = idx - row * 66;
      const int gy = y0 + row - 1;
      const int gx = x0 + col - 1;
      uint4 vh0 = {0,0,0,0}, vh1 = {0,0,0,0};
      uint4 vl0 = {0,0,0,0}, vl1 = {0,0,0,0};
      if ((unsigned)gy < 256u && (unsigned)gx < 256u) {
        const size_t base = (((size_t)(b * 8 + c)) * N_ + (gy * HW_ + gx)) * 16;
        const uint4* ph = (const uint4*)(catH + base);
        vh0 = ph[0]; vh1 = ph[1];
        const uint4* pl = (const uint4*)(catL + base);
        vl0 = pl[0]; vl1 = pl[1];
      }
      const int le = (row * 68 + col) * 24;
      *(uint4*)(&XsH[le]) = vh0; *(uint4*)(&XsH[le + 8]) = vh1;
      *(uint4*)(&XsL[le]) = vl0; *(uint4*)(&XsL[le + 8]) = vl1;
    }
    __syncthreads();

    const __hip_bfloat16* wa_c = WA + (size_t)c * 20480;
#pragma unroll
    for (int s = 0; s < 5; ++s) {
      const __hip_bfloat16* wa_s = wa_c + s * 4096 + l * 8;
      bf16x8 aH[4], aL[4];
#pragma unroll
      for (int ot = 0; ot < 4; ++ot) aH[ot] = *(const bf16x8*)(wa_s + ot * 512);
#pragma unroll
      for (int ot = 0; ot < 4; ++ot) aL[ot] = *(const bf16x8*)(wa_s + 2048 + ot * 512);

      int tap = 2 * s + (g >> 1);
      if (tap > 8) tap = 0;
      const int ky = tap / 3;
      const int kx = tap - ky * 3;
      const int e0 = ((w + ky) * 68 + li + kx) * 24 + (g & 1) * 8;
      bf16x8 bH[4], bL[4];
#pragma unroll
      for (int pt = 0; pt < 4; ++pt) bH[pt] = *(const bf16x8*)(&XsH[e0 + pt * 384]);
#pragma unroll
      for (int pt = 0; pt < 4; ++pt) bL[pt] = *(const bf16x8*)(&XsL[e0 + pt * 384]);

#pragma unroll
      for (int ot = 0; ot < 4; ++ot)
#pragma unroll
        for (int pt = 0; pt < 4; ++pt) {
          acc[ot][pt] = __builtin_amdgcn_mfma_f32_16x16x32_bf16(
              aH[ot], bH[pt], acc[ot][pt], 0, 0, 0);
          acc[ot][pt] = __builtin_amdgcn_mfma_f32_16x16x32_bf16(
              aH[ot], bL[pt], acc[ot][pt], 0, 0, 0);
          acc[ot][pt] = __builtin_amdgcn_mfma_f32_16x16x32_bf16(
              aL[ot], bH[pt], acc[ot][pt], 0, 0, 0);
        }
    }
  }

#pragma unroll
  for (int ot = 0; ot < 4; ++ot)
#pragma unroll
    for (int r = 0; r < 4; ++r) {
      const int o = ot * 16 + g * 4 + r;
      const float bv = cb[o];
      float* orow = out + ((size_t)b * 64 + o) * N_ + (size_t)(y0 + w) * HW_ + x0 + li;
#pragma unroll
      for (int pt = 0; pt < 4; ++pt)
        orow[pt * 16] = acc[ot][pt][r] + bv;
    }
}

// ================================================================
extern "C" void kernel_launch(void* const* d_in, const int* in_sizes, int n_in,
                              void* d_out, int out_size, void* d_ws, size_t ws_size,
                              hipStream_t stream) {
  const float* t1  = (const float*)d_in[0];
  const float* t2  = (const float*)d_in[1];
  const float* q1w = (const float*)d_in[2];
  const float* q1b = (const float*)d_in[3];
  const float* k1w = (const float*)d_in[4];
  const float* k1b = (const float*)d_in[5];
  const float* v1w = (const float*)d_in[6];
  const float* v1b = (const float*)d_in[7];
  const float* r1w = (const float*)d_in[8];
  const float* r1b = (const float*)d_in[9];
  const float* q2w = (const float*)d_in[10];
  const float* q2b = (const float*)d_in[11];
  const float* k2w = (const float*)d_in[12];
  const float* k2b = (const float*)d_in[13];
  const float* v2w = (const float*)d_in[14];
  const float* v2b = (const float*)d_in[15];
  const float* r2w = (const float*)d_in[16];
  const float* r2b = (const float*)d_in[17];
  const float* cw  = (const float*)d_in[18];
  const float* cbp = (const float*)d_in[19];
  float* out = (float*)d_out;

  // ws layout: [catH 128MB][catL 128MB][partials 17.3MB][derived]
  // WA (327 KB) aliases partials (dead after finalize). WK (32 KB)
  // aliases the catH region (dead until attn runs, after stats).
  char* ws = (char*)d_ws;
  const size_t catB  = (size_t)B_ * 8 * N_ * 16 * 2;     // 128 MB each
  const size_t partB = (size_t)16 * CHUNKS * STATS * sizeof(float);
  __hip_bfloat16* catHp = (__hip_bfloat16*)ws;
  __hip_bfloat16* catLp = (__hip_bfloat16*)(ws + catB);
  float* part = (float*)(ws + 2 * catB);
  float* der  = (float*)(ws + 2 * catB + partB);
  __hip_bfloat16* WA = (__hip_bfloat16*)part;            // alias
  unsigned short* WKp = (unsigned short*)ws;             // alias (catH)

  prep_proj_kernel<<<dim3(64), 256, 0, stream>>>(k1w, v1w, k2w, v2w, WKp);
  stats_mfma_kernel<<<dim3(CHUNKS, B_, 2), 256, 0, stream>>>(
      t1, t2, k1b, v1b, k2b, v2b, WKp, part);
  finalize_kernel<<<dim3(16), 256, 0, stream>>>(part, r1w, r2w, der);
  prep_wa_kernel<<<dim3(640), 256, 0, stream>>>(cw, WA);
  attn_kernel<<<dim3(N_ / 256, B_, 2), 256, 0, stream>>>(
      t1, t2, q1w, q1b, q2w, q2b, r1b, r2b, der, catHp, catLp);
  conv_mfma_kernel<<<dim3(4, 64, B_), 256, 0, stream>>>(
      catHp, catLp, WA, cbp, out);
}

// Round 8
// 660.203 us; speedup vs baseline: 7.0068x; 1.5324x over previous
//
#include <hip/hip_runtime.h>
#include <hip/hip_bf16.h>

// Problem constants (fixed by setup_inputs)
constexpr int B_ = 8;
constexpr int C_ = 64;      // input channels = KC = VC = 64
constexpr int N_ = 65536;   // H*W = 256*256
constexpr int HW_ = 256;
constexpr float EPSF = 1e-6f;
constexpr int STATS = 4224; // 4096 matrix + 64 ksum + 64 vsum
constexpr int CHUNKS = 64;  // stats blocks per (branch,batch)

typedef __attribute__((ext_vector_type(8))) short bf16x8;
typedef __attribute__((ext_vector_type(4))) float f32x4;

// RNE fp32 -> bf16 bits, pure bit arithmetic (no address-taken locals)
__device__ __forceinline__ unsigned short f2bf(float f) {
  const unsigned u = __float_as_uint(f);
  return (unsigned short)((u + 0x7fffu + ((u >> 16) & 1u)) >> 16);
}

// ================================================================
// prep_proj: K/V projection weights -> MFMA A-fragment order, bf16.
// WK[r(2)][kv(2)][ot(4)][ks(2)][lane(64)][j(8)]  (unchanged)
// ================================================================
__global__ void prep_proj_kernel(const float* __restrict__ k1w,
                                 const float* __restrict__ v1w,
                                 const float* __restrict__ k2w,
                                 const float* __restrict__ v2w,
                                 unsigned short* __restrict__ WK) {
  const int e = blockIdx.x * 256 + threadIdx.x;   // 16384 total
  if (e >= 16384) return;
  const int j    = e & 7;
  const int lane = (e >> 3) & 63;
  const int ks   = (e >> 9) & 1;
  const int ot   = (e >> 10) & 3;
  const int kv   = (e >> 12) & 1;
  const int r    = (e >> 13) & 1;
  const int m    = ot * 16 + (lane & 15);
  const int ch   = ks * 32 + ((lane >> 4) & 3) * 8 + j;
  const float* w = r ? (kv ? v2w : k2w) : (kv ? v1w : k1w);
  WK[e] = f2bf(w[m * 64 + ch]);
}

// ================================================================
// qw_prep: Q projection weights -> A-frag order, bf16 HI/LO planes.
// QWA[r(2)][v(2)][ot(4)][ks(2)][lane(64)][j(8)]  (16384, 32 KB)
// ================================================================
__global__ void qw_prep_kernel(const float* __restrict__ q1w,
                               const float* __restrict__ q2w,
                               unsigned short* __restrict__ QWA) {
  const int e = blockIdx.x * 256 + threadIdx.x;
  if (e >= 16384) return;
  const int j    = e & 7;
  const int lane = (e >> 3) & 63;
  const int ks   = (e >> 9) & 1;
  const int ot   = (e >> 10) & 3;
  const int v    = (e >> 12) & 1;
  const int r    = (e >> 13) & 1;
  const int m    = ot * 16 + (lane & 15);
  const int ch   = ks * 32 + ((lane >> 4) & 3) * 8 + j;
  const float val = (r ? q2w : q1w)[m * 64 + ch];
  unsigned short h = f2bf(val);
  if (v) h = f2bf(val - __uint_as_float((unsigned)h << 16));
  QWA[e] = h;
}

// ================================================================
// rm_prep: rm (= derived[bb][o*64+m]) -> A-frag order bf16 HI/LO.
// RMA[bb(16)][v(2)][ot(4)][ks(2)][lane(64)][j(8)]  (131072, 256 KB)
// ================================================================
__global__ void rm_prep_kernel(const float* __restrict__ derived,
                               unsigned short* __restrict__ RMA) {
  const int e = blockIdx.x * 256 + threadIdx.x;   // 131072 total
  if (e >= 131072) return;
  const int j    = e & 7;
  const int lane = (e >> 3) & 63;
  const int ks   = (e >> 9) & 1;
  const int ot   = (e >> 10) & 3;
  const int v    = (e >> 12) & 1;
  const int bb   = e >> 13;
  const int o    = ot * 16 + (lane & 15);
  const int m    = ks * 32 + ((lane >> 4) & 3) * 8 + j;
  const float val = derived[(size_t)bb * STATS + o * 64 + m];
  unsigned short h = f2bf(val);
  if (v) h = f2bf(val - __uint_as_float((unsigned)h << 16));
  RMA[e] = h;
}

// ================================================================
// Pass 1 (MFMA stats, unchanged from round 7)
// ================================================================
__global__ __launch_bounds__(256, 2) void stats_mfma_kernel(
    const float* __restrict__ t1, const float* __restrict__ t2,
    const float* __restrict__ k1b, const float* __restrict__ v1b,
    const float* __restrict__ k2b, const float* __restrict__ v2b,
    const unsigned short* __restrict__ WK,
    float* __restrict__ partials)
{
  const int chunk = blockIdx.x;
  const int b = blockIdx.y;
  const int r = blockIdx.z;
  const float* x  = (r ? t2 : t1) + (size_t)b * C_ * N_;
  const float* kb = r ? k2b : k1b;
  const float* vb = r ? v2b : v1b;
  const unsigned short* WKr = WK + r * 8192;

  __shared__ unsigned short Xs[64 * 72];
  __shared__ unsigned short Ks[64 * 72];
  __shared__ unsigned short Vs[64 * 72];

  const int t  = threadIdx.x;
  const int w  = t >> 6;
  const int l  = t & 63;
  const int li = l & 15;
  const int g  = l >> 4;

  float kbv[4][4], vbv[4][4];
#pragma unroll
  for (int ot = 0; ot < 4; ++ot)
#pragma unroll
    for (int rg = 0; rg < 4; ++rg) {
      kbv[ot][rg] = kb[ot * 16 + g * 4 + rg];
      vbv[ot][rg] = vb[ot * 16 + g * 4 + rg];
    }

  bf16x8 ones;
#pragma unroll
  for (int j = 0; j < 8; ++j) ones[j] = (short)0x3F80;

  f32x4 accM[4];
#pragma unroll
  for (int ct = 0; ct < 4; ++ct) accM[ct] = (f32x4){0.f, 0.f, 0.f, 0.f};
  f32x4 accSk = (f32x4){0.f, 0.f, 0.f, 0.f};
  f32x4 accSv = (f32x4){0.f, 0.f, 0.f, 0.f};

  for (int it = 0; it < 16; ++it) {
    const int px0 = chunk * 1024 + it * 64;
    __syncthreads();
    {
      const int ch = t >> 2;
      const int ps = t & 3;
      const float* src = x + (size_t)ch * N_ + px0 + ps * 16;
      const float4 f0 = ((const float4*)src)[0];
      const float4 f1 = ((const float4*)src)[1];
      const float4 f2 = ((const float4*)src)[2];
      const float4 f3 = ((const float4*)src)[3];
      float v[16] = {f0.x, f0.y, f0.z, f0.w, f1.x, f1.y, f1.z, f1.w,
                     f2.x, f2.y, f2.z, f2.w, f3.x, f3.y, f3.z, f3.w};
      unsigned short* dst = &Xs[(ps * 16) * 72 + (ch ^ (ps << 4))];
#pragma unroll
      for (int i = 0; i < 16; ++i) dst[i * 72] = f2bf(v[i]);
    }
    __syncthreads();

    bf16x8 bx0 = *(const bf16x8*)&Xs[(w * 16 + li) * 72 + ((g * 8) ^ (w << 4))];
    bf16x8 bx1 = *(const bf16x8*)&Xs[(w * 16 + li) * 72 + ((32 + g * 8) ^ (w << 4))];

    f32x4 ka[4];
#pragma unroll
    for (int ot = 0; ot < 4; ++ot) {
      f32x4 a = (f32x4){0.f, 0.f, 0.f, 0.f};
      const bf16x8 w0 = *(const bf16x8*)(WKr + ((ot * 2 + 0) * 64 + l) * 8);
      const bf16x8 w1 = *(const bf16x8*)(WKr + ((ot * 2 + 1) * 64 + l) * 8);
      a = __builtin_amdgcn_mfma_f32_16x16x32_bf16(w0, bx0, a, 0, 0, 0);
      a = __builtin_amdgcn_mfma_f32_16x16x32_bf16(w1, bx1, a, 0, 0, 0);
      ka[ot] = a;
    }
    float ss = 0.f;
#pragma unroll
    for (int ot = 0; ot < 4; ++ot)
#pragma unroll
      for (int rg = 0; rg < 4; ++rg) {
        const float v2 = ka[ot][rg] + kbv[ot][rg];
        ka[ot][rg] = v2;
        ss += v2 * v2;
      }
    ss += __shfl_xor(ss, 16);
    ss += __shfl_xor(ss, 32);
    const float inv = rsqrtf(ss);
#pragma unroll
    for (int ot = 0; ot < 4; ++ot)
#pragma unroll
      for (int rg = 0; rg < 4; ++rg)
        Ks[(ot * 16 + g * 4 + rg) * 72 + w * 16 + li] = f2bf(ka[ot][rg] * inv);

#pragma unroll
    for (int ot = 0; ot < 4; ++ot) {
      f32x4 a = (f32x4){0.f, 0.f, 0.f, 0.f};
      const bf16x8 w0 = *(const bf16x8*)(WKr + 4096 + ((ot * 2 + 0) * 64 + l) * 8);
      const bf16x8 w1 = *(const bf16x8*)(WKr + 4096 + ((ot * 2 + 1) * 64 + l) * 8);
      a = __builtin_amdgcn_mfma_f32_16x16x32_bf16(w0, bx0, a, 0, 0, 0);
      a = __builtin_amdgcn_mfma_f32_16x16x32_bf16(w1, bx1, a, 0, 0, 0);
#pragma unroll
      for (int rg = 0; rg < 4; ++rg)
        Vs[(ot * 16 + g * 4 + rg) * 72 + w * 16 + li] = f2bf(a[rg] + vbv[ot][rg]);
    }
    __syncthreads();

#pragma unroll
    for (int ks = 0; ks < 2; ++ks) {
      const int ko = ks * 32 + g * 8;
      const bf16x8 aK = *(const bf16x8*)&Ks[(w * 16 + li) * 72 + ko];
      const bf16x8 aV = *(const bf16x8*)&Vs[(w * 16 + li) * 72 + ko];
      accSk = __builtin_amdgcn_mfma_f32_16x16x32_bf16(aK, ones, accSk, 0, 0, 0);
      accSv = __builtin_amdgcn_mfma_f32_16x16x32_bf16(aV, ones, accSv, 0, 0, 0);
#pragma unroll
      for (int ct = 0; ct < 4; ++ct) {
        const bf16x8 bV = *(const bf16x8*)&Vs[(ct * 16 + li) * 72 + ko];
        accM[ct] = __builtin_amdgcn_mfma_f32_16x16x32_bf16(aK, bV, accM[ct], 0, 0, 0);
      }
    }
  }

  float* pb = partials + ((size_t)(r * B_ + b) * CHUNKS + chunk) * STATS;
#pragma unroll
  for (int ct = 0; ct < 4; ++ct)
#pragma unroll
    for (int rg = 0; rg < 4; ++rg)
      pb[(w * 16 + g * 4 + rg) * 64 + ct * 16 + li] = accM[ct][rg];
  if (li == 0) {
#pragma unroll
    for (int rg = 0; rg < 4; ++rg) {
      pb[4096 + w * 16 + g * 4 + rg] = accSk[rg];
      pb[4160 + w * 16 + g * 4 + rg] = accSv[rg];
    }
  }
}

// ================================================================
// Finalize: reduce partials, fold r_w in. (unchanged)
// ================================================================
__global__ void finalize_kernel(const float* __restrict__ partials,
                                const float* __restrict__ r1w,
                                const float* __restrict__ r2w,
                                float* __restrict__ derived)
{
  const int bb = blockIdx.x;
  const int r = bb >> 3;
  const float* rw = r ? r2w : r1w;
  __shared__ float mat[4096];
  __shared__ float ks[64], vs[64];
  const int t = threadIdx.x;
  const float* pb = partials + (size_t)bb * CHUNKS * STATS;
  for (int e = t; e < STATS; e += 256) {
    float s = 0.f;
    for (int j = 0; j < CHUNKS; ++j) s += pb[(size_t)j * STATS + e];
    if (e < 4096) mat[e] = s;
    else if (e < 4160) ks[e - 4096] = s;
    else vs[e - 4160] = s;
  }
  __syncthreads();
  float* der = derived + (size_t)bb * STATS;
  for (int e = t; e < 4096; e += 256) {
    const int o = e >> 6, m = e & 63;
    float s = 0.f;
    for (int c = 0; c < 64; ++c) s += rw[o * 64 + c] * mat[m * 64 + c];
    der[e] = s;
  }
  if (t < 64) {
    float s = 0.f;
    for (int c = 0; c < 64; ++c) s += rw[t * 64 + c] * vs[c];
    der[4096 + t] = s;
    der[4160 + t] = ks[t] + EPSF;
  }
}

// ================================================================
// Pass 2 (REWRITTEN, MFMA): per-pixel Q proj + attention output.
// Same 64-px-tile structure as stats. Per wave-iter (16 px):
//  proj: q = qw*x + qb via 3-pass hi/lo MFMA (24 mfma)
//  norm/denom: shfl_xor(16,32) reduces -> inv, rden, f1 per px
//  q -> bf16 hi/lo -> wave-private LDS rows (no barrier)
//  out:  av = rm*q via 3-pass hi/lo MFMA (24 mfma) from RMA (L2)
//  epilogue: f1*av + rden*rvs + rb -> bf16 hi/lo -> coalesced uint2
// cat layout (unchanged): catH/catL [b][ch(8)][n][16ci].
// ================================================================
__global__ __launch_bounds__(256, 2) void attn_mfma_kernel(
    const float* __restrict__ t1, const float* __restrict__ t2,
    const float* __restrict__ q1b, const float* __restrict__ q2b,
    const float* __restrict__ r1b, const float* __restrict__ r2b,
    const float* __restrict__ derived,
    const unsigned short* __restrict__ QWA,
    const unsigned short* __restrict__ RMA,
    __hip_bfloat16* __restrict__ catH, __hip_bfloat16* __restrict__ catL)
{
  const int chunk = blockIdx.x;
  const int b = blockIdx.y;
  const int rbr = blockIdx.z;
  const float* x  = (rbr ? t2 : t1) + (size_t)b * C_ * N_;
  const float* qb = rbr ? q2b : q1b;
  const float* rb = rbr ? r2b : r1b;
  const int bb = rbr * B_ + b;
  const float* der = derived + (size_t)bb * STATS;
  const unsigned short* qwa = QWA + rbr * 8192;   // [v][ot][ks][lane][j]
  const unsigned short* rma = RMA + (size_t)bb * 8192;

  __shared__ unsigned short XsH[64 * 72];
  __shared__ unsigned short XsL[64 * 72];
  __shared__ unsigned short QsH[64 * 72];
  __shared__ unsigned short QsL[64 * 72];

  const int t  = threadIdx.x;
  const int w  = t >> 6;
  const int l  = t & 63;
  const int li = l & 15;
  const int g  = l >> 4;

  // per-lane row params (rows m = ot*16 + g*4 + rg)
  float qbv[16], ksev[16], rvsv[16], rbv[16];
#pragma unroll
  for (int ot = 0; ot < 4; ++ot)
#pragma unroll
    for (int rg = 0; rg < 4; ++rg) {
      const int row = ot * 16 + g * 4 + rg;
      qbv[ot * 4 + rg]  = qb[row];
      ksev[ot * 4 + rg] = der[4160 + row];
      rvsv[ot * 4 + rg] = der[4096 + row];
      rbv[ot * 4 + rg]  = rb[row];
    }

#pragma clang loop unroll(disable)
  for (int it = 0; it < 16; ++it) {
    const int px0 = chunk * 1024 + it * 64;
    __syncthreads();
    // ---- stage x -> bf16 hi/lo, swizzled [px][72] (stats pattern)
    {
      const int ch = t >> 2;
      const int ps = t & 3;
      const float* src = x + (size_t)ch * N_ + px0 + ps * 16;
      const float4 f0 = ((const float4*)src)[0];
      const float4 f1v = ((const float4*)src)[1];
      const float4 f2v = ((const float4*)src)[2];
      const float4 f3v = ((const float4*)src)[3];
      float v[16] = {f0.x, f0.y, f0.z, f0.w, f1v.x, f1v.y, f1v.z, f1v.w,
                     f2v.x, f2v.y, f2v.z, f2v.w, f3v.x, f3v.y, f3v.z, f3v.w};
      const int col = ch ^ (ps << 4);
      unsigned short* dH = &XsH[(ps * 16) * 72 + col];
      unsigned short* dL = &XsL[(ps * 16) * 72 + col];
#pragma unroll
      for (int i = 0; i < 16; ++i) {
        const unsigned short h = f2bf(v[i]);
        dH[i * 72] = h;
        dL[i * 72] = f2bf(v[i] - __uint_as_float((unsigned)h << 16));
      }
    }
    __syncthreads();

    // ---- proj B-frags
    const int rowb = (w * 16 + li) * 72;
    const bf16x8 bxh0 = *(const bf16x8*)&XsH[rowb + ((g * 8) ^ (w << 4))];
    const bf16x8 bxh1 = *(const bf16x8*)&XsH[rowb + ((32 + g * 8) ^ (w << 4))];
    const bf16x8 bxl0 = *(const bf16x8*)&XsL[rowb + ((g * 8) ^ (w << 4))];
    const bf16x8 bxl1 = *(const bf16x8*)&XsL[rowb + ((32 + g * 8) ^ (w << 4))];

    // ---- Q projection, 3-pass hi/lo
    float q[16];
#pragma unroll
    for (int ot = 0; ot < 4; ++ot) {
      f32x4 a = (f32x4){0.f, 0.f, 0.f, 0.f};
      const bf16x8 wh0 = *(const bf16x8*)(qwa + ((0 * 4 + ot) * 2 + 0) * 512 + l * 8);
      const bf16x8 wh1 = *(const bf16x8*)(qwa + ((0 * 4 + ot) * 2 + 1) * 512 + l * 8);
      const bf16x8 wl0 = *(const bf16x8*)(qwa + ((1 * 4 + ot) * 2 + 0) * 512 + l * 8);
      const bf16x8 wl1 = *(const bf16x8*)(qwa + ((1 * 4 + ot) * 2 + 1) * 512 + l * 8);
      a = __builtin_amdgcn_mfma_f32_16x16x32_bf16(wh0, bxh0, a, 0, 0, 0);
      a = __builtin_amdgcn_mfma_f32_16x16x32_bf16(wh1, bxh1, a, 0, 0, 0);
      a = __builtin_amdgcn_mfma_f32_16x16x32_bf16(wh0, bxl0, a, 0, 0, 0);
      a = __builtin_amdgcn_mfma_f32_16x16x32_bf16(wh1, bxl1, a, 0, 0, 0);
      a = __builtin_amdgcn_mfma_f32_16x16x32_bf16(wl0, bxh0, a, 0, 0, 0);
      a = __builtin_amdgcn_mfma_f32_16x16x32_bf16(wl1, bxh1, a, 0, 0, 0);
#pragma unroll
      for (int rg = 0; rg < 4; ++rg) q[ot * 4 + rg] = a[rg] + qbv[ot * 4 + rg];
    }

    // ---- per-pixel norm + denom (4 g-groups share px li)
    float ss = 0.f, d = 0.f;
#pragma unroll
    for (int i = 0; i < 16; ++i) { ss += q[i] * q[i]; d += q[i] * ksev[i]; }
    ss += __shfl_xor(ss, 16);  ss += __shfl_xor(ss, 32);
    d  += __shfl_xor(d, 16);   d  += __shfl_xor(d, 32);
    const float inv = rsqrtf(ss);
    const float rden = 1.0f / (65536.0f + inv * d);
    const float f1 = rden * inv;

    // ---- q -> bf16 hi/lo -> wave-private LDS rows (no barrier)
#pragma unroll
    for (int ot = 0; ot < 4; ++ot) {
      unsigned h0, h1, h2, h3, l0, l1, l2, l3;
      {
        const float v0 = q[ot * 4 + 0], v1 = q[ot * 4 + 1];
        const float v2 = q[ot * 4 + 2], v3 = q[ot * 4 + 3];
        h0 = f2bf(v0); l0 = f2bf(v0 - __uint_as_float(h0 << 16));
        h1 = f2bf(v1); l1 = f2bf(v1 - __uint_as_float(h1 << 16));
        h2 = f2bf(v2); l2 = f2bf(v2 - __uint_as_float(h2 << 16));
        h3 = f2bf(v3); l3 = f2bf(v3 - __uint_as_float(h3 << 16));
      }
      const int off = (w * 16 + li) * 72 + ot * 16 + g * 4;
      *(uint2*)&QsH[off] = make_uint2(h0 | (h1 << 16), h2 | (h3 << 16));
      *(uint2*)&QsL[off] = make_uint2(l0 | (l1 << 16), l2 | (l3 << 16));
    }

    // ---- out-GEMM B-frags (own rows, k = m)
    const bf16x8 bqh0 = *(const bf16x8*)&QsH[rowb + g * 8];
    const bf16x8 bqh1 = *(const bf16x8*)&QsH[rowb + 32 + g * 8];
    const bf16x8 bql0 = *(const bf16x8*)&QsL[rowb + g * 8];
    const bf16x8 bql1 = *(const bf16x8*)&QsL[rowb + 32 + g * 8];

    // ---- out GEMM + epilogue + store, per ot
#pragma unroll
    for (int ot = 0; ot < 4; ++ot) {
      f32x4 a = (f32x4){0.f, 0.f, 0.f, 0.f};
      const bf16x8 rh0 = *(const bf16x8*)(rma + ((0 * 4 + ot) * 2 + 0) * 512 + l * 8);
      const bf16x8 rh1 = *(const bf16x8*)(rma + ((0 * 4 + ot) * 2 + 1) * 512 + l * 8);
      const bf16x8 rl0 = *(const bf16x8*)(rma + ((1 * 4 + ot) * 2 + 0) * 512 + l * 8);
      const bf16x8 rl1 = *(const bf16x8*)(rma + ((1 * 4 + ot) * 2 + 1) * 512 + l * 8);
      a = __builtin_amdgcn_mfma_f32_16x16x32_bf16(rh0, bqh0, a, 0, 0, 0);
      a = __builtin_amdgcn_mfma_f32_16x16x32_bf16(rh1, bqh1, a, 0, 0, 0);
      a = __builtin_amdgcn_mfma_f32_16x16x32_bf16(rh0, bql0, a, 0, 0, 0);
      a = __builtin_amdgcn_mfma_f32_16x16x32_bf16(rh1, bql1, a, 0, 0, 0);
      a = __builtin_amdgcn_mfma_f32_16x16x32_bf16(rl0, bqh0, a, 0, 0, 0);
      a = __builtin_amdgcn_mfma_f32_16x16x32_bf16(rl1, bqh1, a, 0, 0, 0);

      unsigned h0, h1, h2, h3, l0, l1, l2, l3;
      {
        const float a0 = f1 * a[0] + rden * rvsv[ot * 4 + 0] + rbv[ot * 4 + 0];
        const float a1 = f1 * a[1] + rden * rvsv[ot * 4 + 1] + rbv[ot * 4 + 1];
        const float a2 = f1 * a[2] + rden * rvsv[ot * 4 + 2] + rbv[ot * 4 + 2];
        const float a3 = f1 * a[3] + rden * rvsv[ot * 4 + 3] + rbv[ot * 4 + 3];
        h0 = f2bf(a0); l0 = f2bf(a0 - __uint_as_float(h0 << 16));
        h1 = f2bf(a1); l1 = f2bf(a1 - __uint_as_float(h1 << 16));
        h2 = f2bf(a2); l2 = f2bf(a2 - __uint_as_float(h2 << 16));
        h3 = f2bf(a3); l3 = f2bf(a3 - __uint_as_float(h3 << 16));
      }
      const size_t base =
          (((size_t)(b * 8 + rbr * 4 + ot)) * N_ + (px0 + w * 16 + li)) * 16 + g * 4;
      *(uint2*)(catH + base) = make_uint2(h0 | (h1 << 16), h2 | (h3 << 16));
      *(uint2*)(catL + base) = make_uint2(l0 | (l1 << 16), l2 | (l3 << 16));
    }
  }
}

// ================================================================
// prep_wa: conv weights -> A-frag order, split bf16 hi/lo. (unchanged)
// ================================================================
__global__ void prep_wa_kernel(const float* __restrict__ cw,
                               __hip_bfloat16* __restrict__ WA) {
  const int e = blockIdx.x * 256 + threadIdx.x;
  if (e >= 8 * 5 * 2 * 4 * 512) return;
  const int j    = e & 7;
  const int lane = (e >> 3) & 63;
  const int f    = e >> 9;
  const int ot   = f & 3;
  const int v    = (f >> 2) & 1;
  const int s    = (f >> 3) % 5;
  const int c    = (f >> 3) / 5;
  const int o    = ot * 16 + (lane & 15);
  const int g    = lane >> 4;
  const int tap  = 2 * s + (g >> 1);
  float val = 0.f;
  if (tap <= 8) {
    const int ci = c * 16 + (g & 1) * 8 + j;
    val = cw[(size_t)(o * 128 + ci) * 9 + tap];
  }
  __hip_bfloat16 h = __float2bfloat16(val);
  if (v) h = __float2bfloat16(val - __bfloat162float(h));
  WA[e] = h;
}

// ================================================================
// Pass 3: 3x3 conv via MFMA implicit GEMM, split-bf16. (unchanged)
// ================================================================
__global__ __launch_bounds__(256, 3) void conv_mfma_kernel(
    const __hip_bfloat16* __restrict__ catH,
    const __hip_bfloat16* __restrict__ catL,
    const __hip_bfloat16* __restrict__ WA,
    const float* __restrict__ cb,
    float* __restrict__ out)
{
  __shared__ __hip_bfloat16 XsH[6 * 68 * 24];
  __shared__ __hip_bfloat16 XsL[6 * 68 * 24];

  const int t  = threadIdx.x;
  const int w  = t >> 6;
  const int l  = t & 63;
  const int li = l & 15;
  const int g  = l >> 4;
  const int x0 = blockIdx.x * 64;
  const int y0 = blockIdx.y * 4;
  const int b  = blockIdx.z;

  f32x4 acc[4][4];
#pragma unroll
  for (int i = 0; i < 4; ++i)
#pragma unroll
    for (int k = 0; k < 4; ++k) acc[i][k] = (f32x4){0.f, 0.f, 0.f, 0.f};

  for (int c = 0; c < 8; ++c) {
    __syncthreads();
    for (int idx = t; idx < 396; idx += 256) {
      const int row = idx / 66;
      const int col = idx - row * 66;
      const int gy = y0 + row - 1;
      const int gx = x0 + col - 1;
      uint4 vh0 = {0,0,0,0}, vh1 = {0,0,0,0};
      uint4 vl0 = {0,0,0,0}, vl1 = {0,0,0,0};
      if ((unsigned)gy < 256u && (unsigned)gx < 256u) {
        const size_t base = (((size_t)(b * 8 + c)) * N_ + (gy * HW_ + gx)) * 16;
        const uint4* ph = (const uint4*)(catH + base);
        vh0 = ph[0]; vh1 = ph[1];
        const uint4* pl = (const uint4*)(catL + base);
        vl0 = pl[0]; vl1 = pl[1];
      }
      const int le = (row * 68 + col) * 24;
      *(uint4*)(&XsH[le]) = vh0; *(uint4*)(&XsH[le + 8]) = vh1;
      *(uint4*)(&XsL[le]) = vl0; *(uint4*)(&XsL[le + 8]) = vl1;
    }
    __syncthreads();

    const __hip_bfloat16* wa_c = WA + (size_t)c * 20480;
#pragma unroll
    for (int s = 0; s < 5; ++s) {
      const __hip_bfloat16* wa_s = wa_c + s * 4096 + l * 8;
      bf16x8 aH[4], aL[4];
#pragma unroll
      for (int ot = 0; ot < 4; ++ot) aH[ot] = *(const bf16x8*)(wa_s + ot * 512);
#pragma unroll
      for (int ot = 0; ot < 4; ++ot) aL[ot] = *(const bf16x8*)(wa_s + 2048 + ot * 512);

      int tap = 2 * s + (g >> 1);
      if (tap > 8) tap = 0;
      const int ky = tap / 3;
      const int kx = tap - ky * 3;
      const int e0 = ((w + ky) * 68 + li + kx) * 24 + (g & 1) * 8;
      bf16x8 bH[4], bL[4];
#pragma unroll
      for (int pt = 0; pt < 4; ++pt) bH[pt] = *(const bf16x8*)(&XsH[e0 + pt * 384]);
#pragma unroll
      for (int pt = 0; pt < 4; ++pt) bL[pt] = *(const bf16x8*)(&XsL[e0 + pt * 384]);

#pragma unroll
      for (int ot = 0; ot < 4; ++ot)
#pragma unroll
        for (int pt = 0; pt < 4; ++pt) {
          acc[ot][pt] = __builtin_amdgcn_mfma_f32_16x16x32_bf16(
              aH[ot], bH[pt], acc[ot][pt], 0, 0, 0);
          acc[ot][pt] = __builtin_amdgcn_mfma_f32_16x16x32_bf16(
              aH[ot], bL[pt], acc[ot][pt], 0, 0, 0);
          acc[ot][pt] = __builtin_amdgcn_mfma_f32_16x16x32_bf16(
              aL[ot], bH[pt], acc[ot][pt], 0, 0, 0);
        }
    }
  }

#pragma unroll
  for (int ot = 0; ot < 4; ++ot)
#pragma unroll
    for (int r = 0; r < 4; ++r) {
      const int o = ot * 16 + g * 4 + r;
      const float bv = cb[o];
      float* orow = out + ((size_t)b * 64 + o) * N_ + (size_t)(y0 + w) * HW_ + x0 + li;
#pragma unroll
      for (int pt = 0; pt < 4; ++pt)
        orow[pt * 16] = acc[ot][pt][r] + bv;
    }
}

// ================================================================
extern "C" void kernel_launch(void* const* d_in, const int* in_sizes, int n_in,
                              void* d_out, int out_size, void* d_ws, size_t ws_size,
                              hipStream_t stream) {
  const float* t1  = (const float*)d_in[0];
  const float* t2  = (const float*)d_in[1];
  const float* q1w = (const float*)d_in[2];
  const float* q1b = (const float*)d_in[3];
  const float* k1w = (const float*)d_in[4];
  const float* k1b = (const float*)d_in[5];
  const float* v1w = (const float*)d_in[6];
  const float* v1b = (const float*)d_in[7];
  const float* r1w = (const float*)d_in[8];
  const float* r1b = (const float*)d_in[9];
  const float* q2w = (const float*)d_in[10];
  const float* q2b = (const float*)d_in[11];
  const float* k2w = (const float*)d_in[12];
  const float* k2b = (const float*)d_in[13];
  const float* v2w = (const float*)d_in[14];
  const float* v2b = (const float*)d_in[15];
  const float* r2w = (const float*)d_in[16];
  const float* r2b = (const float*)d_in[17];
  const float* cw  = (const float*)d_in[18];
  const float* cbp = (const float*)d_in[19];
  float* out = (float*)d_out;

  // ws: [catH 128MB][catL 128MB][partials 16.5MB][derived 264KB]
  // Aliases inside the dead-after-finalize partials region:
  //   WA at +0 (320KB), RMA at +1MB (256KB), QWA at +2MB (32KB).
  // WK (stats weights) aliases catH (dead until attn runs).
  char* ws = (char*)d_ws;
  const size_t catB  = (size_t)B_ * 8 * N_ * 16 * 2;     // 128 MB each
  const size_t partB = (size_t)16 * CHUNKS * STATS * sizeof(float);
  __hip_bfloat16* catHp = (__hip_bfloat16*)ws;
  __hip_bfloat16* catLp = (__hip_bfloat16*)(ws + catB);
  float* part = (float*)(ws + 2 * catB);
  float* der  = (float*)(ws + 2 * catB + partB);
  __hip_bfloat16* WA   = (__hip_bfloat16*)part;                       // alias
  unsigned short* RMAp = (unsigned short*)(ws + 2 * catB + (1u << 20)); // alias
  unsigned short* QWAp = (unsigned short*)(ws + 2 * catB + (2u << 20)); // alias
  unsigned short* WKp  = (unsigned short*)ws;                         // alias (catH)

  prep_proj_kernel<<<dim3(64), 256, 0, stream>>>(k1w, v1w, k2w, v2w, WKp);
  stats_mfma_kernel<<<dim3(CHUNKS, B_, 2), 256, 0, stream>>>(
      t1, t2, k1b, v1b, k2b, v2b, WKp, part);
  finalize_kernel<<<dim3(16), 256, 0, stream>>>(part, r1w, r2w, der);
  qw_prep_kernel<<<dim3(64), 256, 0, stream>>>(q1w, q2w, QWAp);
  rm_prep_kernel<<<dim3(512), 256, 0, stream>>>(der, RMAp);
  prep_wa_kernel<<<dim3(640), 256, 0, stream>>>(cw, WA);
  attn_mfma_kernel<<<dim3(CHUNKS, B_, 2), 256, 0, stream>>>(
      t1, t2, q1b, q2b, r1b, r2b, der, QWAp, RMAp, catHp, catLp);
  conv_mfma_kernel<<<dim3(4, 64, B_), 256, 0, stream>>>(
      catHp, catLp, WA, cbp, out);
}

// Round 9
// 643.111 us; speedup vs baseline: 7.1930x; 1.0266x over previous
//
#include <hip/hip_runtime.h>
#include <hip/hip_bf16.h>

// Problem constants (fixed by setup_inputs)
constexpr int B_ = 8;
constexpr int C_ = 64;      // input channels = KC = VC = 64
constexpr int N_ = 65536;   // H*W = 256*256
constexpr int HW_ = 256;
constexpr float EPSF = 1e-6f;
constexpr int STATS = 4224; // 4096 matrix + 64 ksum + 64 vsum
constexpr int CHUNKS = 64;  // stats blocks per (branch,batch)

typedef __attribute__((ext_vector_type(8))) short bf16x8;
typedef __attribute__((ext_vector_type(4))) float f32x4;

// RNE fp32 -> bf16 bits, pure bit arithmetic (no address-taken locals)
__device__ __forceinline__ unsigned short f2bf(float f) {
  const unsigned u = __float_as_uint(f);
  return (unsigned short)((u + 0x7fffu + ((u >> 16) & 1u)) >> 16);
}

// ================================================================
// prep_proj: K/V projection weights -> MFMA A-fragment order, bf16.
// WK[r(2)][kv(2)][ot(4)][ks(2)][lane(64)][j(8)]  (unchanged)
// ================================================================
__global__ void prep_proj_kernel(const float* __restrict__ k1w,
                                 const float* __restrict__ v1w,
                                 const float* __restrict__ k2w,
                                 const float* __restrict__ v2w,
                                 unsigned short* __restrict__ WK) {
  const int e = blockIdx.x * 256 + threadIdx.x;   // 16384 total
  if (e >= 16384) return;
  const int j    = e & 7;
  const int lane = (e >> 3) & 63;
  const int ks   = (e >> 9) & 1;
  const int ot   = (e >> 10) & 3;
  const int kv   = (e >> 12) & 1;
  const int r    = (e >> 13) & 1;
  const int m    = ot * 16 + (lane & 15);
  const int ch   = ks * 32 + ((lane >> 4) & 3) * 8 + j;
  const float* w = r ? (kv ? v2w : k2w) : (kv ? v1w : k1w);
  WK[e] = f2bf(w[m * 64 + ch]);
}

// ================================================================
// qw_prep: Q projection weights -> A-frag order, bf16 HI/LO planes.
// ================================================================
__global__ void qw_prep_kernel(const float* __restrict__ q1w,
                               const float* __restrict__ q2w,
                               unsigned short* __restrict__ QWA) {
  const int e = blockIdx.x * 256 + threadIdx.x;
  if (e >= 16384) return;
  const int j    = e & 7;
  const int lane = (e >> 3) & 63;
  const int ks   = (e >> 9) & 1;
  const int ot   = (e >> 10) & 3;
  const int v    = (e >> 12) & 1;
  const int r    = (e >> 13) & 1;
  const int m    = ot * 16 + (lane & 15);
  const int ch   = ks * 32 + ((lane >> 4) & 3) * 8 + j;
  const float val = (r ? q2w : q1w)[m * 64 + ch];
  unsigned short h = f2bf(val);
  if (v) h = f2bf(val - __uint_as_float((unsigned)h << 16));
  QWA[e] = h;
}

// ================================================================
// rm_prep: rm (= derived[bb][o*64+m]) -> A-frag order bf16 HI/LO.
// ================================================================
__global__ void rm_prep_kernel(const float* __restrict__ derived,
                               unsigned short* __restrict__ RMA) {
  const int e = blockIdx.x * 256 + threadIdx.x;   // 131072 total
  if (e >= 131072) return;
  const int j    = e & 7;
  const int lane = (e >> 3) & 63;
  const int ks   = (e >> 9) & 1;
  const int ot   = (e >> 10) & 3;
  const int v    = (e >> 12) & 1;
  const int bb   = e >> 13;
  const int o    = ot * 16 + (lane & 15);
  const int m    = ks * 32 + ((lane >> 4) & 3) * 8 + j;
  const float val = derived[(size_t)bb * STATS + o * 64 + m];
  unsigned short h = f2bf(val);
  if (v) h = f2bf(val - __uint_as_float((unsigned)h << 16));
  RMA[e] = h;
}

// ================================================================
// Pass 1 (MFMA stats, unchanged)
// ================================================================
__global__ __launch_bounds__(256, 2) void stats_mfma_kernel(
    const float* __restrict__ t1, const float* __restrict__ t2,
    const float* __restrict__ k1b, const float* __restrict__ v1b,
    const float* __restrict__ k2b, const float* __restrict__ v2b,
    const unsigned short* __restrict__ WK,
    float* __restrict__ partials)
{
  const int chunk = blockIdx.x;
  const int b = blockIdx.y;
  const int r = blockIdx.z;
  const float* x  = (r ? t2 : t1) + (size_t)b * C_ * N_;
  const float* kb = r ? k2b : k1b;
  const float* vb = r ? v2b : v1b;
  const unsigned short* WKr = WK + r * 8192;

  __shared__ unsigned short Xs[64 * 72];
  __shared__ unsigned short Ks[64 * 72];
  __shared__ unsigned short Vs[64 * 72];

  const int t  = threadIdx.x;
  const int w  = t >> 6;
  const int l  = t & 63;
  const int li = l & 15;
  const int g  = l >> 4;

  float kbv[4][4], vbv[4][4];
#pragma unroll
  for (int ot = 0; ot < 4; ++ot)
#pragma unroll
    for (int rg = 0; rg < 4; ++rg) {
      kbv[ot][rg] = kb[ot * 16 + g * 4 + rg];
      vbv[ot][rg] = vb[ot * 16 + g * 4 + rg];
    }

  bf16x8 ones;
#pragma unroll
  for (int j = 0; j < 8; ++j) ones[j] = (short)0x3F80;

  f32x4 accM[4];
#pragma unroll
  for (int ct = 0; ct < 4; ++ct) accM[ct] = (f32x4){0.f, 0.f, 0.f, 0.f};
  f32x4 accSk = (f32x4){0.f, 0.f, 0.f, 0.f};
  f32x4 accSv = (f32x4){0.f, 0.f, 0.f, 0.f};

  for (int it = 0; it < 16; ++it) {
    const int px0 = chunk * 1024 + it * 64;
    __syncthreads();
    {
      const int ch = t >> 2;
      const int ps = t & 3;
      const float* src = x + (size_t)ch * N_ + px0 + ps * 16;
      const float4 f0 = ((const float4*)src)[0];
      const float4 f1 = ((const float4*)src)[1];
      const float4 f2 = ((const float4*)src)[2];
      const float4 f3 = ((const float4*)src)[3];
      float v[16] = {f0.x, f0.y, f0.z, f0.w, f1.x, f1.y, f1.z, f1.w,
                     f2.x, f2.y, f2.z, f2.w, f3.x, f3.y, f3.z, f3.w};
      unsigned short* dst = &Xs[(ps * 16) * 72 + (ch ^ (ps << 4))];
#pragma unroll
      for (int i = 0; i < 16; ++i) dst[i * 72] = f2bf(v[i]);
    }
    __syncthreads();

    bf16x8 bx0 = *(const bf16x8*)&Xs[(w * 16 + li) * 72 + ((g * 8) ^ (w << 4))];
    bf16x8 bx1 = *(const bf16x8*)&Xs[(w * 16 + li) * 72 + ((32 + g * 8) ^ (w << 4))];

    f32x4 ka[4];
#pragma unroll
    for (int ot = 0; ot < 4; ++ot) {
      f32x4 a = (f32x4){0.f, 0.f, 0.f, 0.f};
      const bf16x8 w0 = *(const bf16x8*)(WKr + ((ot * 2 + 0) * 64 + l) * 8);
      const bf16x8 w1 = *(const bf16x8*)(WKr + ((ot * 2 + 1) * 64 + l) * 8);
      a = __builtin_amdgcn_mfma_f32_16x16x32_bf16(w0, bx0, a, 0, 0, 0);
      a = __builtin_amdgcn_mfma_f32_16x16x32_bf16(w1, bx1, a, 0, 0, 0);
      ka[ot] = a;
    }
    float ss = 0.f;
#pragma unroll
    for (int ot = 0; ot < 4; ++ot)
#pragma unroll
      for (int rg = 0; rg < 4; ++rg) {
        const float v2 = ka[ot][rg] + kbv[ot][rg];
        ka[ot][rg] = v2;
        ss += v2 * v2;
      }
    ss += __shfl_xor(ss, 16);
    ss += __shfl_xor(ss, 32);
    const float inv = rsqrtf(ss);
#pragma unroll
    for (int ot = 0; ot < 4; ++ot)
#pragma unroll
      for (int rg = 0; rg < 4; ++rg)
        Ks[(ot * 16 + g * 4 + rg) * 72 + w * 16 + li] = f2bf(ka[ot][rg] * inv);

#pragma unroll
    for (int ot = 0; ot < 4; ++ot) {
      f32x4 a = (f32x4){0.f, 0.f, 0.f, 0.f};
      const bf16x8 w0 = *(const bf16x8*)(WKr + 4096 + ((ot * 2 + 0) * 64 + l) * 8);
      const bf16x8 w1 = *(const bf16x8*)(WKr + 4096 + ((ot * 2 + 1) * 64 + l) * 8);
      a = __builtin_amdgcn_mfma_f32_16x16x32_bf16(w0, bx0, a, 0, 0, 0);
      a = __builtin_amdgcn_mfma_f32_16x16x32_bf16(w1, bx1, a, 0, 0, 0);
#pragma unroll
      for (int rg = 0; rg < 4; ++rg)
        Vs[(ot * 16 + g * 4 + rg) * 72 + w * 16 + li] = f2bf(a[rg] + vbv[ot][rg]);
    }
    __syncthreads();

#pragma unroll
    for (int ks = 0; ks < 2; ++ks) {
      const int ko = ks * 32 + g * 8;
      const bf16x8 aK = *(const bf16x8*)&Ks[(w * 16 + li) * 72 + ko];
      const bf16x8 aV = *(const bf16x8*)&Vs[(w * 16 + li) * 72 + ko];
      accSk = __builtin_amdgcn_mfma_f32_16x16x32_bf16(aK, ones, accSk, 0, 0, 0);
      accSv = __builtin_amdgcn_mfma_f32_16x16x32_bf16(aV, ones, accSv, 0, 0, 0);
#pragma unroll
      for (int ct = 0; ct < 4; ++ct) {
        const bf16x8 bV = *(const bf16x8*)&Vs[(ct * 16 + li) * 72 + ko];
        accM[ct] = __builtin_amdgcn_mfma_f32_16x16x32_bf16(aK, bV, accM[ct], 0, 0, 0);
      }
    }
  }

  float* pb = partials + ((size_t)(r * B_ + b) * CHUNKS + chunk) * STATS;
#pragma unroll
  for (int ct = 0; ct < 4; ++ct)
#pragma unroll
    for (int rg = 0; rg < 4; ++rg)
      pb[(w * 16 + g * 4 + rg) * 64 + ct * 16 + li] = accM[ct][rg];
  if (li == 0) {
#pragma unroll
    for (int rg = 0; rg < 4; ++rg) {
      pb[4096 + w * 16 + g * 4 + rg] = accSk[rg];
      pb[4160 + w * 16 + g * 4 + rg] = accSv[rg];
    }
  }
}

// ================================================================
// Finalize: reduce partials, fold r_w in. (unchanged)
// ================================================================
__global__ void finalize_kernel(const float* __restrict__ partials,
                                const float* __restrict__ r1w,
                                const float* __restrict__ r2w,
                                float* __restrict__ derived)
{
  const int bb = blockIdx.x;
  const int r = bb >> 3;
  const float* rw = r ? r2w : r1w;
  __shared__ float mat[4096];
  __shared__ float ks[64], vs[64];
  const int t = threadIdx.x;
  const float* pb = partials + (size_t)bb * CHUNKS * STATS;
  for (int e = t; e < STATS; e += 256) {
    float s = 0.f;
    for (int j = 0; j < CHUNKS; ++j) s += pb[(size_t)j * STATS + e];
    if (e < 4096) mat[e] = s;
    else if (e < 4160) ks[e - 4096] = s;
    else vs[e - 4160] = s;
  }
  __syncthreads();
  float* der = derived + (size_t)bb * STATS;
  for (int e = t; e < 4096; e += 256) {
    const int o = e >> 6, m = e & 63;
    float s = 0.f;
    for (int c = 0; c < 64; ++c) s += rw[o * 64 + c] * mat[m * 64 + c];
    der[e] = s;
  }
  if (t < 64) {
    float s = 0.f;
    for (int c = 0; c < 64; ++c) s += rw[t * 64 + c] * vs[c];
    der[4096 + t] = s;
    der[4160 + t] = ks[t] + EPSF;
  }
}

// ================================================================
// Pass 2 (MFMA attn, unchanged from round 8)
// ================================================================
__global__ __launch_bounds__(256, 2) void attn_mfma_kernel(
    const float* __restrict__ t1, const float* __restrict__ t2,
    const float* __restrict__ q1b, const float* __restrict__ q2b,
    const float* __restrict__ r1b, const float* __restrict__ r2b,
    const float* __restrict__ derived,
    const unsigned short* __restrict__ QWA,
    const unsigned short* __restrict__ RMA,
    __hip_bfloat16* __restrict__ catH, __hip_bfloat16* __restrict__ catL)
{
  const int chunk = blockIdx.x;
  const int b = blockIdx.y;
  const int rbr = blockIdx.z;
  const float* x  = (rbr ? t2 : t1) + (size_t)b * C_ * N_;
  const float* qb = rbr ? q2b : q1b;
  const float* rb = rbr ? r2b : r1b;
  const int bb = rbr * B_ + b;
  const float* der = derived + (size_t)bb * STATS;
  const unsigned short* qwa = QWA + rbr * 8192;
  const unsigned short* rma = RMA + (size_t)bb * 8192;

  __shared__ unsigned short XsH[64 * 72];
  __shared__ unsigned short XsL[64 * 72];
  __shared__ unsigned short QsH[64 * 72];
  __shared__ unsigned short QsL[64 * 72];

  const int t  = threadIdx.x;
  const int w  = t >> 6;
  const int l  = t & 63;
  const int li = l & 15;
  const int g  = l >> 4;

  float qbv[16], ksev[16], rvsv[16], rbv[16];
#pragma unroll
  for (int ot = 0; ot < 4; ++ot)
#pragma unroll
    for (int rg = 0; rg < 4; ++rg) {
      const int row = ot * 16 + g * 4 + rg;
      qbv[ot * 4 + rg]  = qb[row];
      ksev[ot * 4 + rg] = der[4160 + row];
      rvsv[ot * 4 + rg] = der[4096 + row];
      rbv[ot * 4 + rg]  = rb[row];
    }

#pragma clang loop unroll(disable)
  for (int it = 0; it < 16; ++it) {
    const int px0 = chunk * 1024 + it * 64;
    __syncthreads();
    {
      const int ch = t >> 2;
      const int ps = t & 3;
      const float* src = x + (size_t)ch * N_ + px0 + ps * 16;
      const float4 f0 = ((const float4*)src)[0];
      const float4 f1v = ((const float4*)src)[1];
      const float4 f2v = ((const float4*)src)[2];
      const float4 f3v = ((const float4*)src)[3];
      float v[16] = {f0.x, f0.y, f0.z, f0.w, f1v.x, f1v.y, f1v.z, f1v.w,
                     f2v.x, f2v.y, f2v.z, f2v.w, f3v.x, f3v.y, f3v.z, f3v.w};
      const int col = ch ^ (ps << 4);
      unsigned short* dH = &XsH[(ps * 16) * 72 + col];
      unsigned short* dL = &XsL[(ps * 16) * 72 + col];
#pragma unroll
      for (int i = 0; i < 16; ++i) {
        const unsigned short h = f2bf(v[i]);
        dH[i * 72] = h;
        dL[i * 72] = f2bf(v[i] - __uint_as_float((unsigned)h << 16));
      }
    }
    __syncthreads();

    const int rowb = (w * 16 + li) * 72;
    const bf16x8 bxh0 = *(const bf16x8*)&XsH[rowb + ((g * 8) ^ (w << 4))];
    const bf16x8 bxh1 = *(const bf16x8*)&XsH[rowb + ((32 + g * 8) ^ (w << 4))];
    const bf16x8 bxl0 = *(const bf16x8*)&XsL[rowb + ((g * 8) ^ (w << 4))];
    const bf16x8 bxl1 = *(const bf16x8*)&XsL[rowb + ((32 + g * 8) ^ (w << 4))];

    float q[16];
#pragma unroll
    for (int ot = 0; ot < 4; ++ot) {
      f32x4 a = (f32x4){0.f, 0.f, 0.f, 0.f};
      const bf16x8 wh0 = *(const bf16x8*)(qwa + ((0 * 4 + ot) * 2 + 0) * 512 + l * 8);
      const bf16x8 wh1 = *(const bf16x8*)(qwa + ((0 * 4 + ot) * 2 + 1) * 512 + l * 8);
      const bf16x8 wl0 = *(const bf16x8*)(qwa + ((1 * 4 + ot) * 2 + 0) * 512 + l * 8);
      const bf16x8 wl1 = *(const bf16x8*)(qwa + ((1 * 4 + ot) * 2 + 1) * 512 + l * 8);
      a = __builtin_amdgcn_mfma_f32_16x16x32_bf16(wh0, bxh0, a, 0, 0, 0);
      a = __builtin_amdgcn_mfma_f32_16x16x32_bf16(wh1, bxh1, a, 0, 0, 0);
      a = __builtin_amdgcn_mfma_f32_16x16x32_bf16(wh0, bxl0, a, 0, 0, 0);
      a = __builtin_amdgcn_mfma_f32_16x16x32_bf16(wh1, bxl1, a, 0, 0, 0);
      a = __builtin_amdgcn_mfma_f32_16x16x32_bf16(wl0, bxh0, a, 0, 0, 0);
      a = __builtin_amdgcn_mfma_f32_16x16x32_bf16(wl1, bxh1, a, 0, 0, 0);
#pragma unroll
      for (int rg = 0; rg < 4; ++rg) q[ot * 4 + rg] = a[rg] + qbv[ot * 4 + rg];
    }

    float ss = 0.f, d = 0.f;
#pragma unroll
    for (int i = 0; i < 16; ++i) { ss += q[i] * q[i]; d += q[i] * ksev[i]; }
    ss += __shfl_xor(ss, 16);  ss += __shfl_xor(ss, 32);
    d  += __shfl_xor(d, 16);   d  += __shfl_xor(d, 32);
    const float inv = rsqrtf(ss);
    const float rden = 1.0f / (65536.0f + inv * d);
    const float f1 = rden * inv;

#pragma unroll
    for (int ot = 0; ot < 4; ++ot) {
      unsigned h0, h1, h2, h3, l0, l1, l2, l3;
      {
        const float v0 = q[ot * 4 + 0], v1 = q[ot * 4 + 1];
        const float v2 = q[ot * 4 + 2], v3 = q[ot * 4 + 3];
        h0 = f2bf(v0); l0 = f2bf(v0 - __uint_as_float(h0 << 16));
        h1 = f2bf(v1); l1 = f2bf(v1 - __uint_as_float(h1 << 16));
        h2 = f2bf(v2); l2 = f2bf(v2 - __uint_as_float(h2 << 16));
        h3 = f2bf(v3); l3 = f2bf(v3 - __uint_as_float(h3 << 16));
      }
      const int off = (w * 16 + li) * 72 + ot * 16 + g * 4;
      *(uint2*)&QsH[off] = make_uint2(h0 | (h1 << 16), h2 | (h3 << 16));
      *(uint2*)&QsL[off] = make_uint2(l0 | (l1 << 16), l2 | (l3 << 16));
    }

    const bf16x8 bqh0 = *(const bf16x8*)&QsH[rowb + g * 8];
    const bf16x8 bqh1 = *(const bf16x8*)&QsH[rowb + 32 + g * 8];
    const bf16x8 bql0 = *(const bf16x8*)&QsL[rowb + g * 8];
    const bf16x8 bql1 = *(const bf16x8*)&QsL[rowb + 32 + g * 8];

#pragma unroll
    for (int ot = 0; ot < 4; ++ot) {
      f32x4 a = (f32x4){0.f, 0.f, 0.f, 0.f};
      const bf16x8 rh0 = *(const bf16x8*)(rma + ((0 * 4 + ot) * 2 + 0) * 512 + l * 8);
      const bf16x8 rh1 = *(const bf16x8*)(rma + ((0 * 4 + ot) * 2 + 1) * 512 + l * 8);
      const bf16x8 rl0 = *(const bf16x8*)(rma + ((1 * 4 + ot) * 2 + 0) * 512 + l * 8);
      const bf16x8 rl1 = *(const bf16x8*)(rma + ((1 * 4 + ot) * 2 + 1) * 512 + l * 8);
      a = __builtin_amdgcn_mfma_f32_16x16x32_bf16(rh0, bqh0, a, 0, 0, 0);
      a = __builtin_amdgcn_mfma_f32_16x16x32_bf16(rh1, bqh1, a, 0, 0, 0);
      a = __builtin_amdgcn_mfma_f32_16x16x32_bf16(rh0, bql0, a, 0, 0, 0);
      a = __builtin_amdgcn_mfma_f32_16x16x32_bf16(rh1, bql1, a, 0, 0, 0);
      a = __builtin_amdgcn_mfma_f32_16x16x32_bf16(rl0, bqh0, a, 0, 0, 0);
      a = __builtin_amdgcn_mfma_f32_16x16x32_bf16(rl1, bqh1, a, 0, 0, 0);

      unsigned h0, h1, h2, h3, l0, l1, l2, l3;
      {
        const float a0 = f1 * a[0] + rden * rvsv[ot * 4 + 0] + rbv[ot * 4 + 0];
        const float a1 = f1 * a[1] + rden * rvsv[ot * 4 + 1] + rbv[ot * 4 + 1];
        const float a2 = f1 * a[2] + rden * rvsv[ot * 4 + 2] + rbv[ot * 4 + 2];
        const float a3 = f1 * a[3] + rden * rvsv[ot * 4 + 3] + rbv[ot * 4 + 3];
        h0 = f2bf(a0); l0 = f2bf(a0 - __uint_as_float(h0 << 16));
        h1 = f2bf(a1); l1 = f2bf(a1 - __uint_as_float(h1 << 16));
        h2 = f2bf(a2); l2 = f2bf(a2 - __uint_as_float(h2 << 16));
        h3 = f2bf(a3); l3 = f2bf(a3 - __uint_as_float(h3 << 16));
      }
      const size_t base =
          (((size_t)(b * 8 + rbr * 4 + ot)) * N_ + (px0 + w * 16 + li)) * 16 + g * 4;
      *(uint2*)(catH + base) = make_uint2(h0 | (h1 << 16), h2 | (h3 << 16));
      *(uint2*)(catL + base) = make_uint2(l0 | (l1 << 16), l2 | (l3 << 16));
    }
  }
}

// ================================================================
// prep_wa: conv weights -> A-frag order, split bf16 hi/lo. (unchanged)
// ================================================================
__global__ void prep_wa_kernel(const float* __restrict__ cw,
                               __hip_bfloat16* __restrict__ WA) {
  const int e = blockIdx.x * 256 + threadIdx.x;
  if (e >= 8 * 5 * 2 * 4 * 512) return;
  const int j    = e & 7;
  const int lane = (e >> 3) & 63;
  const int f    = e >> 9;
  const int ot   = f & 3;
  const int v    = (f >> 2) & 1;
  const int s    = (f >> 3) % 5;
  const int c    = (f >> 3) / 5;
  const int o    = ot * 16 + (lane & 15);
  const int g    = lane >> 4;
  const int tap  = 2 * s + (g >> 1);
  float val = 0.f;
  if (tap <= 8) {
    const int ci = c * 16 + (g & 1) * 8 + j;
    val = cw[(size_t)(o * 128 + ci) * 9 + tap];
  }
  __hip_bfloat16 h = __float2bfloat16(val);
  if (v) h = __float2bfloat16(val - __bfloat162float(h));
  WA[e] = h;
}

// ================================================================
// Pass 3: 3x3 conv via MFMA implicit GEMM, split-bf16.
// ROUND-9 CHANGE (T14 async-STAGE): round 8 serialized
// barrier -> global staging (all waves stall ~500cyc) -> barrier ->
// compute. Now reg-staged issue-early/write-late pipeline:
//   LOAD(0)->regs; for c: { barrier; WRITE regs->LDS; barrier;
//   if(c<7) LOAD(c+1)->regs; COMPUTE(c); }
// Next chunk's loads fly across the whole ~1500cyc compute phase.
// Staged regs are 8 named uint4 (static indexing, no scratch).
// ================================================================
__global__ __launch_bounds__(256, 3) void conv_mfma_kernel(
    const __hip_bfloat16* __restrict__ catH,
    const __hip_bfloat16* __restrict__ catL,
    const __hip_bfloat16* __restrict__ WA,
    const float* __restrict__ cb,
    float* __restrict__ out)
{
  __shared__ __hip_bfloat16 XsH[6 * 68 * 24];
  __shared__ __hip_bfloat16 XsL[6 * 68 * 24];

  const int t  = threadIdx.x;
  const int w  = t >> 6;
  const int l  = t & 63;
  const int li = l & 15;
  const int g  = l >> 4;
  const int x0 = blockIdx.x * 64;
  const int y0 = blockIdx.y * 4;
  const int b  = blockIdx.z;

  // staging geometry: items 0..395 = row(6) x col(66); thread owns
  // item A = t and item B = t+256 (B valid for t < 140).
  const int iA = t;
  const int iB = t + 256;
  const bool hasB = (iB < 396);
  const int rA = iA / 66, cA = iA - rA * 66;
  const int rB = iB / 66, cB = iB - rB * 66;
  const int gyA = y0 + rA - 1, gxA = x0 + cA - 1;
  const int gyB = y0 + rB - 1, gxB = x0 + cB - 1;
  const bool okA = ((unsigned)gyA < 256u) && ((unsigned)gxA < 256u);
  const bool okB = hasB && ((unsigned)gyB < 256u) && ((unsigned)gxB < 256u);
  const size_t offA = ((size_t)(gyA * HW_ + gxA)) * 16;
  const size_t offB = ((size_t)(gyB * HW_ + gxB)) * 16;
  const int leA = (rA * 68 + cA) * 24;
  const int leB = (rB * 68 + cB) * 24;
  const uint4 Z = make_uint4(0u, 0u, 0u, 0u);

  uint4 Ah0, Ah1, Al0, Al1, Bh0, Bh1, Bl0, Bl1;

  f32x4 acc[4][4];
#pragma unroll
  for (int i = 0; i < 4; ++i)
#pragma unroll
    for (int k = 0; k < 4; ++k) acc[i][k] = (f32x4){0.f, 0.f, 0.f, 0.f};

  // ---- prologue: issue chunk-0 loads
  {
    const size_t chb = ((size_t)(b * 8 + 0)) * N_ * 16;
    Ah0 = Ah1 = Al0 = Al1 = Z;
    Bh0 = Bh1 = Bl0 = Bl1 = Z;
    if (okA) {
      const uint4* ph = (const uint4*)(catH + chb + offA);
      Ah0 = ph[0]; Ah1 = ph[1];
      const uint4* pl = (const uint4*)(catL + chb + offA);
      Al0 = pl[0]; Al1 = pl[1];
    }
    if (okB) {
      const uint4* ph = (const uint4*)(catH + chb + offB);
      Bh0 = ph[0]; Bh1 = ph[1];
      const uint4* pl = (const uint4*)(catL + chb + offB);
      Bl0 = pl[0]; Bl1 = pl[1];
    }
  }

  for (int c = 0; c < 8; ++c) {
    __syncthreads();             // previous chunk's compute reads done
    // ---- write-late: staged regs -> LDS
    *(uint4*)(&XsH[leA]) = Ah0; *(uint4*)(&XsH[leA + 8]) = Ah1;
    *(uint4*)(&XsL[leA]) = Al0; *(uint4*)(&XsL[leA + 8]) = Al1;
    if (hasB) {
      *(uint4*)(&XsH[leB]) = Bh0; *(uint4*)(&XsH[leB + 8]) = Bh1;
      *(uint4*)(&XsL[leB]) = Bl0; *(uint4*)(&XsL[leB + 8]) = Bl1;
    }
    __syncthreads();
    // ---- issue-early: chunk c+1 loads fly across COMPUTE(c)
    if (c < 7) {
      const size_t chb = ((size_t)(b * 8 + c + 1)) * N_ * 16;
      Ah0 = Ah1 = Al0 = Al1 = Z;
      Bh0 = Bh1 = Bl0 = Bl1 = Z;
      if (okA) {
        const uint4* ph = (const uint4*)(catH + chb + offA);
        Ah0 = ph[0]; Ah1 = ph[1];
        const uint4* pl = (const uint4*)(catL + chb + offA);
        Al0 = pl[0]; Al1 = pl[1];
      }
      if (okB) {
        const uint4* ph = (const uint4*)(catH + chb + offB);
        Bh0 = ph[0]; Bh1 = ph[1];
        const uint4* pl = (const uint4*)(catL + chb + offB);
        Bl0 = pl[0]; Bl1 = pl[1];
      }
    }

    // ---- COMPUTE(c)
    const __hip_bfloat16* wa_c = WA + (size_t)c * 20480;
#pragma unroll
    for (int s = 0; s < 5; ++s) {
      const __hip_bfloat16* wa_s = wa_c + s * 4096 + l * 8;
      bf16x8 aH[4], aL[4];
#pragma unroll
      for (int ot = 0; ot < 4; ++ot) aH[ot] = *(const bf16x8*)(wa_s + ot * 512);
#pragma unroll
      for (int ot = 0; ot < 4; ++ot) aL[ot] = *(const bf16x8*)(wa_s + 2048 + ot * 512);

      int tap = 2 * s + (g >> 1);
      if (tap > 8) tap = 0;
      const int ky = tap / 3;
      const int kx = tap - ky * 3;
      const int e0 = ((w + ky) * 68 + li + kx) * 24 + (g & 1) * 8;
      bf16x8 bH[4], bL[4];
#pragma unroll
      for (int pt = 0; pt < 4; ++pt) bH[pt] = *(const bf16x8*)(&XsH[e0 + pt * 384]);
#pragma unroll
      for (int pt = 0; pt < 4; ++pt) bL[pt] = *(const bf16x8*)(&XsL[e0 + pt * 384]);

#pragma unroll
      for (int ot = 0; ot < 4; ++ot)
#pragma unroll
        for (int pt = 0; pt < 4; ++pt) {
          acc[ot][pt] = __builtin_amdgcn_mfma_f32_16x16x32_bf16(
              aH[ot], bH[pt], acc[ot][pt], 0, 0, 0);
          acc[ot][pt] = __builtin_amdgcn_mfma_f32_16x16x32_bf16(
              aH[ot], bL[pt], acc[ot][pt], 0, 0, 0);
          acc[ot][pt] = __builtin_amdgcn_mfma_f32_16x16x32_bf16(
              aL[ot], bH[pt], acc[ot][pt], 0, 0, 0);
        }
    }
  }

#pragma unroll
  for (int ot = 0; ot < 4; ++ot)
#pragma unroll
    for (int r = 0; r < 4; ++r) {
      const int o = ot * 16 + g * 4 + r;
      const float bv = cb[o];
      float* orow = out + ((size_t)b * 64 + o) * N_ + (size_t)(y0 + w) * HW_ + x0 + li;
#pragma unroll
      for (int pt = 0; pt < 4; ++pt)
        orow[pt * 16] = acc[ot][pt][r] + bv;
    }
}

// ================================================================
extern "C" void kernel_launch(void* const* d_in, const int* in_sizes, int n_in,
                              void* d_out, int out_size, void* d_ws, size_t ws_size,
                              hipStream_t stream) {
  const float* t1  = (const float*)d_in[0];
  const float* t2  = (const float*)d_in[1];
  const float* q1w = (const float*)d_in[2];
  const float* q1b = (const float*)d_in[3];
  const float* k1w = (const float*)d_in[4];
  const float* k1b = (const float*)d_in[5];
  const float* v1w = (const float*)d_in[6];
  const float* v1b = (const float*)d_in[7];
  const float* r1w = (const float*)d_in[8];
  const float* r1b = (const float*)d_in[9];
  const float* q2w = (const float*)d_in[10];
  const float* q2b = (const float*)d_in[11];
  const float* k2w = (const float*)d_in[12];
  const float* k2b = (const float*)d_in[13];
  const float* v2w = (const float*)d_in[14];
  const float* v2b = (const float*)d_in[15];
  const float* r2w = (const float*)d_in[16];
  const float* r2b = (const float*)d_in[17];
  const float* cw  = (const float*)d_in[18];
  const float* cbp = (const float*)d_in[19];
  float* out = (float*)d_out;

  // ws: [catH 128MB][catL 128MB][partials 16.5MB][derived 264KB]
  // Aliases inside the dead-after-finalize partials region:
  //   WA at +0 (320KB), RMA at +1MB (256KB), QWA at +2MB (32KB).
  // WK (stats weights) aliases catH (dead until attn runs).
  char* ws = (char*)d_ws;
  const size_t catB  = (size_t)B_ * 8 * N_ * 16 * 2;     // 128 MB each
  const size_t partB = (size_t)16 * CHUNKS * STATS * sizeof(float);
  __hip_bfloat16* catHp = (__hip_bfloat16*)ws;
  __hip_bfloat16* catLp = (__hip_bfloat16*)(ws + catB);
  float* part = (float*)(ws + 2 * catB);
  float* der  = (float*)(ws + 2 * catB + partB);
  __hip_bfloat16* WA   = (__hip_bfloat16*)part;                         // alias
  unsigned short* RMAp = (unsigned short*)(ws + 2 * catB + (1u << 20)); // alias
  unsigned short* QWAp = (unsigned short*)(ws + 2 * catB + (2u << 20)); // alias
  unsigned short* WKp  = (unsigned short*)ws;                           // alias (catH)

  prep_proj_kernel<<<dim3(64), 256, 0, stream>>>(k1w, v1w, k2w, v2w, WKp);
  stats_mfma_kernel<<<dim3(CHUNKS, B_, 2), 256, 0, stream>>>(
      t1, t2, k1b, v1b, k2b, v2b, WKp, part);
  finalize_kernel<<<dim3(16), 256, 0, stream>>>(part, r1w, r2w, der);
  qw_prep_kernel<<<dim3(64), 256, 0, stream>>>(q1w, q2w, QWAp);
  rm_prep_kernel<<<dim3(512), 256, 0, stream>>>(der, RMAp);
  prep_wa_kernel<<<dim3(640), 256, 0, stream>>>(cw, WA);
  attn_mfma_kernel<<<dim3(CHUNKS, B_, 2), 256, 0, stream>>>(
      t1, t2, q1b, q2b, r1b, r2b, der, QWAp, RMAp, catHp, catLp);
  conv_mfma_kernel<<<dim3(4, 64, B_), 256, 0, stream>>>(
      catHp, catLp, WA, cbp, out);
}

// Round 10
// 577.483 us; speedup vs baseline: 8.0104x; 1.1136x over previous
//
#include <hip/hip_runtime.h>
#include <hip/hip_bf16.h>

// Problem constants (fixed by setup_inputs)
constexpr int B_ = 8;
constexpr int C_ = 64;      // input channels = KC = VC = 64
constexpr int N_ = 65536;   // H*W = 256*256
constexpr int HW_ = 256;
constexpr float EPSF = 1e-6f;
constexpr int STATS = 4224; // 4096 matrix + 64 ksum + 64 vsum
constexpr int CHUNKS = 64;  // stats blocks per (branch,batch)

typedef __attribute__((ext_vector_type(8))) short bf16x8;
typedef __attribute__((ext_vector_type(4))) float f32x4;

// RNE fp32 -> bf16 bits, pure bit arithmetic (no address-taken locals)
__device__ __forceinline__ unsigned short f2bf(float f) {
  const unsigned u = __float_as_uint(f);
  return (unsigned short)((u + 0x7fffu + ((u >> 16) & 1u)) >> 16);
}

// ================================================================
// prep_proj: K/V projection weights -> MFMA A-fragment order, bf16.
// WK[r(2)][kv(2)][ot(4)][ks(2)][lane(64)][j(8)]  (unchanged)
// ================================================================
__global__ void prep_proj_kernel(const float* __restrict__ k1w,
                                 const float* __restrict__ v1w,
                                 const float* __restrict__ k2w,
                                 const float* __restrict__ v2w,
                                 unsigned short* __restrict__ WK) {
  const int e = blockIdx.x * 256 + threadIdx.x;   // 16384 total
  if (e >= 16384) return;
  const int j    = e & 7;
  const int lane = (e >> 3) & 63;
  const int ks   = (e >> 9) & 1;
  const int ot   = (e >> 10) & 3;
  const int kv   = (e >> 12) & 1;
  const int r    = (e >> 13) & 1;
  const int m    = ot * 16 + (lane & 15);
  const int ch   = ks * 32 + ((lane >> 4) & 3) * 8 + j;
  const float* w = r ? (kv ? v2w : k2w) : (kv ? v1w : k1w);
  WK[e] = f2bf(w[m * 64 + ch]);
}

// ================================================================
// qw_prep: Q projection weights -> A-frag order, bf16 HI/LO planes.
// ================================================================
__global__ void qw_prep_kernel(const float* __restrict__ q1w,
                               const float* __restrict__ q2w,
                               unsigned short* __restrict__ QWA) {
  const int e = blockIdx.x * 256 + threadIdx.x;
  if (e >= 16384) return;
  const int j    = e & 7;
  const int lane = (e >> 3) & 63;
  const int ks   = (e >> 9) & 1;
  const int ot   = (e >> 10) & 3;
  const int v    = (e >> 12) & 1;
  const int r    = (e >> 13) & 1;
  const int m    = ot * 16 + (lane & 15);
  const int ch   = ks * 32 + ((lane >> 4) & 3) * 8 + j;
  const float val = (r ? q2w : q1w)[m * 64 + ch];
  unsigned short h = f2bf(val);
  if (v) h = f2bf(val - __uint_as_float((unsigned)h << 16));
  QWA[e] = h;
}

// ================================================================
// rm_prep: rm (= derived[bb][o*64+m]) -> A-frag order bf16 HI/LO.
// ================================================================
__global__ void rm_prep_kernel(const float* __restrict__ derived,
                               unsigned short* __restrict__ RMA) {
  const int e = blockIdx.x * 256 + threadIdx.x;   // 131072 total
  if (e >= 131072) return;
  const int j    = e & 7;
  const int lane = (e >> 3) & 63;
  const int ks   = (e >> 9) & 1;
  const int ot   = (e >> 10) & 3;
  const int v    = (e >> 12) & 1;
  const int bb   = e >> 13;
  const int o    = ot * 16 + (lane & 15);
  const int m    = ks * 32 + ((lane >> 4) & 3) * 8 + j;
  const float val = derived[(size_t)bb * STATS + o * 64 + m];
  unsigned short h = f2bf(val);
  if (v) h = f2bf(val - __uint_as_float((unsigned)h << 16));
  RMA[e] = h;
}

// ================================================================
// Pass 1 (MFMA stats, unchanged)
// ================================================================
__global__ __launch_bounds__(256, 2) void stats_mfma_kernel(
    const float* __restrict__ t1, const float* __restrict__ t2,
    const float* __restrict__ k1b, const float* __restrict__ v1b,
    const float* __restrict__ k2b, const float* __restrict__ v2b,
    const unsigned short* __restrict__ WK,
    float* __restrict__ partials)
{
  const int chunk = blockIdx.x;
  const int b = blockIdx.y;
  const int r = blockIdx.z;
  const float* x  = (r ? t2 : t1) + (size_t)b * C_ * N_;
  const float* kb = r ? k2b : k1b;
  const float* vb = r ? v2b : v1b;
  const unsigned short* WKr = WK + r * 8192;

  __shared__ unsigned short Xs[64 * 72];
  __shared__ unsigned short Ks[64 * 72];
  __shared__ unsigned short Vs[64 * 72];

  const int t  = threadIdx.x;
  const int w  = t >> 6;
  const int l  = t & 63;
  const int li = l & 15;
  const int g  = l >> 4;

  float kbv[4][4], vbv[4][4];
#pragma unroll
  for (int ot = 0; ot < 4; ++ot)
#pragma unroll
    for (int rg = 0; rg < 4; ++rg) {
      kbv[ot][rg] = kb[ot * 16 + g * 4 + rg];
      vbv[ot][rg] = vb[ot * 16 + g * 4 + rg];
    }

  bf16x8 ones;
#pragma unroll
  for (int j = 0; j < 8; ++j) ones[j] = (short)0x3F80;

  f32x4 accM[4];
#pragma unroll
  for (int ct = 0; ct < 4; ++ct) accM[ct] = (f32x4){0.f, 0.f, 0.f, 0.f};
  f32x4 accSk = (f32x4){0.f, 0.f, 0.f, 0.f};
  f32x4 accSv = (f32x4){0.f, 0.f, 0.f, 0.f};

  for (int it = 0; it < 16; ++it) {
    const int px0 = chunk * 1024 + it * 64;
    __syncthreads();
    {
      const int ch = t >> 2;
      const int ps = t & 3;
      const float* src = x + (size_t)ch * N_ + px0 + ps * 16;
      const float4 f0 = ((const float4*)src)[0];
      const float4 f1 = ((const float4*)src)[1];
      const float4 f2 = ((const float4*)src)[2];
      const float4 f3 = ((const float4*)src)[3];
      float v[16] = {f0.x, f0.y, f0.z, f0.w, f1.x, f1.y, f1.z, f1.w,
                     f2.x, f2.y, f2.z, f2.w, f3.x, f3.y, f3.z, f3.w};
      unsigned short* dst = &Xs[(ps * 16) * 72 + (ch ^ (ps << 4))];
#pragma unroll
      for (int i = 0; i < 16; ++i) dst[i * 72] = f2bf(v[i]);
    }
    __syncthreads();

    bf16x8 bx0 = *(const bf16x8*)&Xs[(w * 16 + li) * 72 + ((g * 8) ^ (w << 4))];
    bf16x8 bx1 = *(const bf16x8*)&Xs[(w * 16 + li) * 72 + ((32 + g * 8) ^ (w << 4))];

    f32x4 ka[4];
#pragma unroll
    for (int ot = 0; ot < 4; ++ot) {
      f32x4 a = (f32x4){0.f, 0.f, 0.f, 0.f};
      const bf16x8 w0 = *(const bf16x8*)(WKr + ((ot * 2 + 0) * 64 + l) * 8);
      const bf16x8 w1 = *(const bf16x8*)(WKr + ((ot * 2 + 1) * 64 + l) * 8);
      a = __builtin_amdgcn_mfma_f32_16x16x32_bf16(w0, bx0, a, 0, 0, 0);
      a = __builtin_amdgcn_mfma_f32_16x16x32_bf16(w1, bx1, a, 0, 0, 0);
      ka[ot] = a;
    }
    float ss = 0.f;
#pragma unroll
    for (int ot = 0; ot < 4; ++ot)
#pragma unroll
      for (int rg = 0; rg < 4; ++rg) {
        const float v2 = ka[ot][rg] + kbv[ot][rg];
        ka[ot][rg] = v2;
        ss += v2 * v2;
      }
    ss += __shfl_xor(ss, 16);
    ss += __shfl_xor(ss, 32);
    const float inv = rsqrtf(ss);
#pragma unroll
    for (int ot = 0; ot < 4; ++ot)
#pragma unroll
      for (int rg = 0; rg < 4; ++rg)
        Ks[(ot * 16 + g * 4 + rg) * 72 + w * 16 + li] = f2bf(ka[ot][rg] * inv);

#pragma unroll
    for (int ot = 0; ot < 4; ++ot) {
      f32x4 a = (f32x4){0.f, 0.f, 0.f, 0.f};
      const bf16x8 w0 = *(const bf16x8*)(WKr + 4096 + ((ot * 2 + 0) * 64 + l) * 8);
      const bf16x8 w1 = *(const bf16x8*)(WKr + 4096 + ((ot * 2 + 1) * 64 + l) * 8);
      a = __builtin_amdgcn_mfma_f32_16x16x32_bf16(w0, bx0, a, 0, 0, 0);
      a = __builtin_amdgcn_mfma_f32_16x16x32_bf16(w1, bx1, a, 0, 0, 0);
#pragma unroll
      for (int rg = 0; rg < 4; ++rg)
        Vs[(ot * 16 + g * 4 + rg) * 72 + w * 16 + li] = f2bf(a[rg] + vbv[ot][rg]);
    }
    __syncthreads();

#pragma unroll
    for (int ks = 0; ks < 2; ++ks) {
      const int ko = ks * 32 + g * 8;
      const bf16x8 aK = *(const bf16x8*)&Ks[(w * 16 + li) * 72 + ko];
      const bf16x8 aV = *(const bf16x8*)&Vs[(w * 16 + li) * 72 + ko];
      accSk = __builtin_amdgcn_mfma_f32_16x16x32_bf16(aK, ones, accSk, 0, 0, 0);
      accSv = __builtin_amdgcn_mfma_f32_16x16x32_bf16(aV, ones, accSv, 0, 0, 0);
#pragma unroll
      for (int ct = 0; ct < 4; ++ct) {
        const bf16x8 bV = *(const bf16x8*)&Vs[(ct * 16 + li) * 72 + ko];
        accM[ct] = __builtin_amdgcn_mfma_f32_16x16x32_bf16(aK, bV, accM[ct], 0, 0, 0);
      }
    }
  }

  float* pb = partials + ((size_t)(r * B_ + b) * CHUNKS + chunk) * STATS;
#pragma unroll
  for (int ct = 0; ct < 4; ++ct)
#pragma unroll
    for (int rg = 0; rg < 4; ++rg)
      pb[(w * 16 + g * 4 + rg) * 64 + ct * 16 + li] = accM[ct][rg];
  if (li == 0) {
#pragma unroll
    for (int rg = 0; rg < 4; ++rg) {
      pb[4096 + w * 16 + g * 4 + rg] = accSk[rg];
      pb[4160 + w * 16 + g * 4 + rg] = accSv[rg];
    }
  }
}

// ================================================================
// Finalize: reduce partials, fold r_w in. (unchanged)
// ================================================================
__global__ void finalize_kernel(const float* __restrict__ partials,
                                const float* __restrict__ r1w,
                                const float* __restrict__ r2w,
                                float* __restrict__ derived)
{
  const int bb = blockIdx.x;
  const int r = bb >> 3;
  const float* rw = r ? r2w : r1w;
  __shared__ float mat[4096];
  __shared__ float ks[64], vs[64];
  const int t = threadIdx.x;
  const float* pb = partials + (size_t)bb * CHUNKS * STATS;
  for (int e = t; e < STATS; e += 256) {
    float s = 0.f;
    for (int j = 0; j < CHUNKS; ++j) s += pb[(size_t)j * STATS + e];
    if (e < 4096) mat[e] = s;
    else if (e < 4160) ks[e - 4096] = s;
    else vs[e - 4160] = s;
  }
  __syncthreads();
  float* der = derived + (size_t)bb * STATS;
  for (int e = t; e < 4096; e += 256) {
    const int o = e >> 6, m = e & 63;
    float s = 0.f;
    for (int c = 0; c < 64; ++c) s += rw[o * 64 + c] * mat[m * 64 + c];
    der[e] = s;
  }
  if (t < 64) {
    float s = 0.f;
    for (int c = 0; c < 64; ++c) s += rw[t * 64 + c] * vs[c];
    der[4096 + t] = s;
    der[4160 + t] = ks[t] + EPSF;
  }
}

// ================================================================
// Pass 2 (MFMA attn, unchanged from round 8)
// ================================================================
__global__ __launch_bounds__(256, 2) void attn_mfma_kernel(
    const float* __restrict__ t1, const float* __restrict__ t2,
    const float* __restrict__ q1b, const float* __restrict__ q2b,
    const float* __restrict__ r1b, const float* __restrict__ r2b,
    const float* __restrict__ derived,
    const unsigned short* __restrict__ QWA,
    const unsigned short* __restrict__ RMA,
    __hip_bfloat16* __restrict__ catH, __hip_bfloat16* __restrict__ catL)
{
  const int chunk = blockIdx.x;
  const int b = blockIdx.y;
  const int rbr = blockIdx.z;
  const float* x  = (rbr ? t2 : t1) + (size_t)b * C_ * N_;
  const float* qb = rbr ? q2b : q1b;
  const float* rb = rbr ? r2b : r1b;
  const int bb = rbr * B_ + b;
  const float* der = derived + (size_t)bb * STATS;
  const unsigned short* qwa = QWA + rbr * 8192;
  const unsigned short* rma = RMA + (size_t)bb * 8192;

  __shared__ unsigned short XsH[64 * 72];
  __shared__ unsigned short XsL[64 * 72];
  __shared__ unsigned short QsH[64 * 72];
  __shared__ unsigned short QsL[64 * 72];

  const int t  = threadIdx.x;
  const int w  = t >> 6;
  const int l  = t & 63;
  const int li = l & 15;
  const int g  = l >> 4;

  float qbv[16], ksev[16], rvsv[16], rbv[16];
#pragma unroll
  for (int ot = 0; ot < 4; ++ot)
#pragma unroll
    for (int rg = 0; rg < 4; ++rg) {
      const int row = ot * 16 + g * 4 + rg;
      qbv[ot * 4 + rg]  = qb[row];
      ksev[ot * 4 + rg] = der[4160 + row];
      rvsv[ot * 4 + rg] = der[4096 + row];
      rbv[ot * 4 + rg]  = rb[row];
    }

#pragma clang loop unroll(disable)
  for (int it = 0; it < 16; ++it) {
    const int px0 = chunk * 1024 + it * 64;
    __syncthreads();
    {
      const int ch = t >> 2;
      const int ps = t & 3;
      const float* src = x + (size_t)ch * N_ + px0 + ps * 16;
      const float4 f0 = ((const float4*)src)[0];
      const float4 f1v = ((const float4*)src)[1];
      const float4 f2v = ((const float4*)src)[2];
      const float4 f3v = ((const float4*)src)[3];
      float v[16] = {f0.x, f0.y, f0.z, f0.w, f1v.x, f1v.y, f1v.z, f1v.w,
                     f2v.x, f2v.y, f2v.z, f2v.w, f3v.x, f3v.y, f3v.z, f3v.w};
      const int col = ch ^ (ps << 4);
      unsigned short* dH = &XsH[(ps * 16) * 72 + col];
      unsigned short* dL = &XsL[(ps * 16) * 72 + col];
#pragma unroll
      for (int i = 0; i < 16; ++i) {
        const unsigned short h = f2bf(v[i]);
        dH[i * 72] = h;
        dL[i * 72] = f2bf(v[i] - __uint_as_float((unsigned)h << 16));
      }
    }
    __syncthreads();

    const int rowb = (w * 16 + li) * 72;
    const bf16x8 bxh0 = *(const bf16x8*)&XsH[rowb + ((g * 8) ^ (w << 4))];
    const bf16x8 bxh1 = *(const bf16x8*)&XsH[rowb + ((32 + g * 8) ^ (w << 4))];
    const bf16x8 bxl0 = *(const bf16x8*)&XsL[rowb + ((g * 8) ^ (w << 4))];
    const bf16x8 bxl1 = *(const bf16x8*)&XsL[rowb + ((32 + g * 8) ^ (w << 4))];

    float q[16];
#pragma unroll
    for (int ot = 0; ot < 4; ++ot) {
      f32x4 a = (f32x4){0.f, 0.f, 0.f, 0.f};
      const bf16x8 wh0 = *(const bf16x8*)(qwa + ((0 * 4 + ot) * 2 + 0) * 512 + l * 8);
      const bf16x8 wh1 = *(const bf16x8*)(qwa + ((0 * 4 + ot) * 2 + 1) * 512 + l * 8);
      const bf16x8 wl0 = *(const bf16x8*)(qwa + ((1 * 4 + ot) * 2 + 0) * 512 + l * 8);
      const bf16x8 wl1 = *(const bf16x8*)(qwa + ((1 * 4 + ot) * 2 + 1) * 512 + l * 8);
      a = __builtin_amdgcn_mfma_f32_16x16x32_bf16(wh0, bxh0, a, 0, 0, 0);
      a = __builtin_amdgcn_mfma_f32_16x16x32_bf16(wh1, bxh1, a, 0, 0, 0);
      a = __builtin_amdgcn_mfma_f32_16x16x32_bf16(wh0, bxl0, a, 0, 0, 0);
      a = __builtin_amdgcn_mfma_f32_16x16x32_bf16(wh1, bxl1, a, 0, 0, 0);
      a = __builtin_amdgcn_mfma_f32_16x16x32_bf16(wl0, bxh0, a, 0, 0, 0);
      a = __builtin_amdgcn_mfma_f32_16x16x32_bf16(wl1, bxh1, a, 0, 0, 0);
#pragma unroll
      for (int rg = 0; rg < 4; ++rg) q[ot * 4 + rg] = a[rg] + qbv[ot * 4 + rg];
    }

    float ss = 0.f, d = 0.f;
#pragma unroll
    for (int i = 0; i < 16; ++i) { ss += q[i] * q[i]; d += q[i] * ksev[i]; }
    ss += __shfl_xor(ss, 16);  ss += __shfl_xor(ss, 32);
    d  += __shfl_xor(d, 16);   d  += __shfl_xor(d, 32);
    const float inv = rsqrtf(ss);
    const float rden = 1.0f / (65536.0f + inv * d);
    const float f1 = rden * inv;

#pragma unroll
    for (int ot = 0; ot < 4; ++ot) {
      unsigned h0, h1, h2, h3, l0, l1, l2, l3;
      {
        const float v0 = q[ot * 4 + 0], v1 = q[ot * 4 + 1];
        const float v2 = q[ot * 4 + 2], v3 = q[ot * 4 + 3];
        h0 = f2bf(v0); l0 = f2bf(v0 - __uint_as_float(h0 << 16));
        h1 = f2bf(v1); l1 = f2bf(v1 - __uint_as_float(h1 << 16));
        h2 = f2bf(v2); l2 = f2bf(v2 - __uint_as_float(h2 << 16));
        h3 = f2bf(v3); l3 = f2bf(v3 - __uint_as_float(h3 << 16));
      }
      const int off = (w * 16 + li) * 72 + ot * 16 + g * 4;
      *(uint2*)&QsH[off] = make_uint2(h0 | (h1 << 16), h2 | (h3 << 16));
      *(uint2*)&QsL[off] = make_uint2(l0 | (l1 << 16), l2 | (l3 << 16));
    }

    const bf16x8 bqh0 = *(const bf16x8*)&QsH[rowb + g * 8];
    const bf16x8 bqh1 = *(const bf16x8*)&QsH[rowb + 32 + g * 8];
    const bf16x8 bql0 = *(const bf16x8*)&QsL[rowb + g * 8];
    const bf16x8 bql1 = *(const bf16x8*)&QsL[rowb + 32 + g * 8];

#pragma unroll
    for (int ot = 0; ot < 4; ++ot) {
      f32x4 a = (f32x4){0.f, 0.f, 0.f, 0.f};
      const bf16x8 rh0 = *(const bf16x8*)(rma + ((0 * 4 + ot) * 2 + 0) * 512 + l * 8);
      const bf16x8 rh1 = *(const bf16x8*)(rma + ((0 * 4 + ot) * 2 + 1) * 512 + l * 8);
      const bf16x8 rl0 = *(const bf16x8*)(rma + ((1 * 4 + ot) * 2 + 0) * 512 + l * 8);
      const bf16x8 rl1 = *(const bf16x8*)(rma + ((1 * 4 + ot) * 2 + 1) * 512 + l * 8);
      a = __builtin_amdgcn_mfma_f32_16x16x32_bf16(rh0, bqh0, a, 0, 0, 0);
      a = __builtin_amdgcn_mfma_f32_16x16x32_bf16(rh1, bqh1, a, 0, 0, 0);
      a = __builtin_amdgcn_mfma_f32_16x16x32_bf16(rh0, bql0, a, 0, 0, 0);
      a = __builtin_amdgcn_mfma_f32_16x16x32_bf16(rh1, bql1, a, 0, 0, 0);
      a = __builtin_amdgcn_mfma_f32_16x16x32_bf16(rl0, bqh0, a, 0, 0, 0);
      a = __builtin_amdgcn_mfma_f32_16x16x32_bf16(rl1, bqh1, a, 0, 0, 0);

      unsigned h0, h1, h2, h3, l0, l1, l2, l3;
      {
        const float a0 = f1 * a[0] + rden * rvsv[ot * 4 + 0] + rbv[ot * 4 + 0];
        const float a1 = f1 * a[1] + rden * rvsv[ot * 4 + 1] + rbv[ot * 4 + 1];
        const float a2 = f1 * a[2] + rden * rvsv[ot * 4 + 2] + rbv[ot * 4 + 2];
        const float a3 = f1 * a[3] + rden * rvsv[ot * 4 + 3] + rbv[ot * 4 + 3];
        h0 = f2bf(a0); l0 = f2bf(a0 - __uint_as_float(h0 << 16));
        h1 = f2bf(a1); l1 = f2bf(a1 - __uint_as_float(h1 << 16));
        h2 = f2bf(a2); l2 = f2bf(a2 - __uint_as_float(h2 << 16));
        h3 = f2bf(a3); l3 = f2bf(a3 - __uint_as_float(h3 << 16));
      }
      const size_t base =
          (((size_t)(b * 8 + rbr * 4 + ot)) * N_ + (px0 + w * 16 + li)) * 16 + g * 4;
      *(uint2*)(catH + base) = make_uint2(h0 | (h1 << 16), h2 | (h3 << 16));
      *(uint2*)(catL + base) = make_uint2(l0 | (l1 << 16), l2 | (l3 << 16));
    }
  }
}

// ================================================================
// prep_wa: conv weights -> A-frag order, split bf16 hi/lo. (unchanged)
// ================================================================
__global__ void prep_wa_kernel(const float* __restrict__ cw,
                               __hip_bfloat16* __restrict__ WA) {
  const int e = blockIdx.x * 256 + threadIdx.x;
  if (e >= 8 * 5 * 2 * 4 * 512) return;
  const int j    = e & 7;
  const int lane = (e >> 3) & 63;
  const int f    = e >> 9;
  const int ot   = f & 3;
  const int v    = (f >> 2) & 1;
  const int s    = (f >> 3) % 5;
  const int c    = (f >> 3) / 5;
  const int o    = ot * 16 + (lane & 15);
  const int g    = lane >> 4;
  const int tap  = 2 * s + (g >> 1);
  float val = 0.f;
  if (tap <= 8) {
    const int ci = c * 16 + (g & 1) * 8 + j;
    val = cw[(size_t)(o * 128 + ci) * 9 + tap];
  }
  __hip_bfloat16 h = __float2bfloat16(val);
  if (v) h = __float2bfloat16(val - __bfloat162float(h));
  WA[e] = h;
}

// ================================================================
// Pass 3: 3x3 conv via MFMA implicit GEMM, split-bf16, T14 pipeline.
// ROUND-10 FIX: round 9's live set (staged 32 + A-frags 32 + B-frags
// 32 + acc 64 + geom ~25 = ~185) blew the (256,3) ~168 unified cap ->
// compiler spilled the staged uint4s (WRITE 132->366 MB), nullifying
// the pipeline. Now B-frags load inside the pt loop (2 live instead
// of 8, -24 regs -> ~160): no spill, pipeline intact.
// ================================================================
__global__ __launch_bounds__(256, 3) void conv_mfma_kernel(
    const __hip_bfloat16* __restrict__ catH,
    const __hip_bfloat16* __restrict__ catL,
    const __hip_bfloat16* __restrict__ WA,
    const float* __restrict__ cb,
    float* __restrict__ out)
{
  __shared__ __hip_bfloat16 XsH[6 * 68 * 24];
  __shared__ __hip_bfloat16 XsL[6 * 68 * 24];

  const int t  = threadIdx.x;
  const int w  = t >> 6;
  const int l  = t & 63;
  const int li = l & 15;
  const int g  = l >> 4;
  const int x0 = blockIdx.x * 64;
  const int y0 = blockIdx.y * 4;
  const int b  = blockIdx.z;

  // staging geometry: items 0..395 = row(6) x col(66); thread owns
  // item A = t and item B = t+256 (B valid for t < 140).
  const int iA = t;
  const int iB = t + 256;
  const bool hasB = (iB < 396);
  const int rA = iA / 66, cA = iA - rA * 66;
  const int rB = iB / 66, cB = iB - rB * 66;
  const int gyA = y0 + rA - 1, gxA = x0 + cA - 1;
  const int gyB = y0 + rB - 1, gxB = x0 + cB - 1;
  const bool okA = ((unsigned)gyA < 256u) && ((unsigned)gxA < 256u);
  const bool okB = hasB && ((unsigned)gyB < 256u) && ((unsigned)gxB < 256u);
  const size_t offA = ((size_t)(gyA * HW_ + gxA)) * 16;
  const size_t offB = ((size_t)(gyB * HW_ + gxB)) * 16;
  const int leA = (rA * 68 + cA) * 24;
  const int leB = (rB * 68 + cB) * 24;
  const uint4 Z = make_uint4(0u, 0u, 0u, 0u);

  uint4 Ah0, Ah1, Al0, Al1, Bh0, Bh1, Bl0, Bl1;

  f32x4 acc[4][4];
#pragma unroll
  for (int i = 0; i < 4; ++i)
#pragma unroll
    for (int k = 0; k < 4; ++k) acc[i][k] = (f32x4){0.f, 0.f, 0.f, 0.f};

  // ---- prologue: issue chunk-0 loads
  {
    const size_t chb = ((size_t)(b * 8 + 0)) * N_ * 16;
    Ah0 = Ah1 = Al0 = Al1 = Z;
    Bh0 = Bh1 = Bl0 = Bl1 = Z;
    if (okA) {
      const uint4* ph = (const uint4*)(catH + chb + offA);
      Ah0 = ph[0]; Ah1 = ph[1];
      const uint4* pl = (const uint4*)(catL + chb + offA);
      Al0 = pl[0]; Al1 = pl[1];
    }
    if (okB) {
      const uint4* ph = (const uint4*)(catH + chb + offB);
      Bh0 = ph[0]; Bh1 = ph[1];
      const uint4* pl = (const uint4*)(catL + chb + offB);
      Bl0 = pl[0]; Bl1 = pl[1];
    }
  }

  for (int c = 0; c < 8; ++c) {
    __syncthreads();             // previous chunk's compute reads done
    // ---- write-late: staged regs -> LDS
    *(uint4*)(&XsH[leA]) = Ah0; *(uint4*)(&XsH[leA + 8]) = Ah1;
    *(uint4*)(&XsL[leA]) = Al0; *(uint4*)(&XsL[leA + 8]) = Al1;
    if (hasB) {
      *(uint4*)(&XsH[leB]) = Bh0; *(uint4*)(&XsH[leB + 8]) = Bh1;
      *(uint4*)(&XsL[leB]) = Bl0; *(uint4*)(&XsL[leB + 8]) = Bl1;
    }
    __syncthreads();
    // ---- issue-early: chunk c+1 loads fly across COMPUTE(c)
    if (c < 7) {
      const size_t chb = ((size_t)(b * 8 + c + 1)) * N_ * 16;
      Ah0 = Ah1 = Al0 = Al1 = Z;
      Bh0 = Bh1 = Bl0 = Bl1 = Z;
      if (okA) {
        const uint4* ph = (const uint4*)(catH + chb + offA);
        Ah0 = ph[0]; Ah1 = ph[1];
        const uint4* pl = (const uint4*)(catL + chb + offA);
        Al0 = pl[0]; Al1 = pl[1];
      }
      if (okB) {
        const uint4* ph = (const uint4*)(catH + chb + offB);
        Bh0 = ph[0]; Bh1 = ph[1];
        const uint4* pl = (const uint4*)(catL + chb + offB);
        Bl0 = pl[0]; Bl1 = pl[1];
      }
    }

    // ---- COMPUTE(c): B-frags loaded per-pt (2 live, not 8)
    const __hip_bfloat16* wa_c = WA + (size_t)c * 20480;
#pragma unroll
    for (int s = 0; s < 5; ++s) {
      const __hip_bfloat16* wa_s = wa_c + s * 4096 + l * 8;
      bf16x8 aH[4], aL[4];
#pragma unroll
      for (int ot = 0; ot < 4; ++ot) aH[ot] = *(const bf16x8*)(wa_s + ot * 512);
#pragma unroll
      for (int ot = 0; ot < 4; ++ot) aL[ot] = *(const bf16x8*)(wa_s + 2048 + ot * 512);

      int tap = 2 * s + (g >> 1);
      if (tap > 8) tap = 0;
      const int ky = tap / 3;
      const int kx = tap - ky * 3;
      const int e0 = ((w + ky) * 68 + li + kx) * 24 + (g & 1) * 8;

#pragma unroll
      for (int pt = 0; pt < 4; ++pt) {
        const bf16x8 bH = *(const bf16x8*)(&XsH[e0 + pt * 384]);
        const bf16x8 bL = *(const bf16x8*)(&XsL[e0 + pt * 384]);
#pragma unroll
        for (int ot = 0; ot < 4; ++ot) {
          acc[ot][pt] = __builtin_amdgcn_mfma_f32_16x16x32_bf16(
              aH[ot], bH, acc[ot][pt], 0, 0, 0);
          acc[ot][pt] = __builtin_amdgcn_mfma_f32_16x16x32_bf16(
              aH[ot], bL, acc[ot][pt], 0, 0, 0);
          acc[ot][pt] = __builtin_amdgcn_mfma_f32_16x16x32_bf16(
              aL[ot], bH, acc[ot][pt], 0, 0, 0);
        }
      }
    }
  }

#pragma unroll
  for (int ot = 0; ot < 4; ++ot)
#pragma unroll
    for (int r = 0; r < 4; ++r) {
      const int o = ot * 16 + g * 4 + r;
      const float bv = cb[o];
      float* orow = out + ((size_t)b * 64 + o) * N_ + (size_t)(y0 + w) * HW_ + x0 + li;
#pragma unroll
      for (int pt = 0; pt < 4; ++pt)
        orow[pt * 16] = acc[ot][pt][r] + bv;
    }
}

// ================================================================
extern "C" void kernel_launch(void* const* d_in, const int* in_sizes, int n_in,
                              void* d_out, int out_size, void* d_ws, size_t ws_size,
                              hipStream_t stream) {
  const float* t1  = (const float*)d_in[0];
  const float* t2  = (const float*)d_in[1];
  const float* q1w = (const float*)d_in[2];
  const float* q1b = (const float*)d_in[3];
  const float* k1w = (const float*)d_in[4];
  const float* k1b = (const float*)d_in[5];
  const float* v1w = (const float*)d_in[6];
  const float* v1b = (const float*)d_in[7];
  const float* r1w = (const float*)d_in[8];
  const float* r1b = (const float*)d_in[9];
  const float* q2w = (const float*)d_in[10];
  const float* q2b = (const float*)d_in[11];
  const float* k2w = (const float*)d_in[12];
  const float* k2b = (const float*)d_in[13];
  const float* v2w = (const float*)d_in[14];
  const float* v2b = (const float*)d_in[15];
  const float* r2w = (const float*)d_in[16];
  const float* r2b = (const float*)d_in[17];
  const float* cw  = (const float*)d_in[18];
  const float* cbp = (const float*)d_in[19];
  float* out = (float*)d_out;

  // ws: [catH 128MB][catL 128MB][partials 16.5MB][derived 264KB]
  // Aliases inside the dead-after-finalize partials region:
  //   WA at +0 (320KB), RMA at +1MB (256KB), QWA at +2MB (32KB).
  // WK (stats weights) aliases catH (dead until attn runs).
  char* ws = (char*)d_ws;
  const size_t catB  = (size_t)B_ * 8 * N_ * 16 * 2;     // 128 MB each
  const size_t partB = (size_t)16 * CHUNKS * STATS * sizeof(float);
  __hip_bfloat16* catHp = (__hip_bfloat16*)ws;
  __hip_bfloat16* catLp = (__hip_bfloat16*)(ws + catB);
  float* part = (float*)(ws + 2 * catB);
  float* der  = (float*)(ws + 2 * catB + partB);
  __hip_bfloat16* WA   = (__hip_bfloat16*)part;                         // alias
  unsigned short* RMAp = (unsigned short*)(ws + 2 * catB + (1u << 20)); // alias
  unsigned short* QWAp = (unsigned short*)(ws + 2 * catB + (2u << 20)); // alias
  unsigned short* WKp  = (unsigned short*)ws;                           // alias (catH)

  prep_proj_kernel<<<dim3(64), 256, 0, stream>>>(k1w, v1w, k2w, v2w, WKp);
  stats_mfma_kernel<<<dim3(CHUNKS, B_, 2), 256, 0, stream>>>(
      t1, t2, k1b, v1b, k2b, v2b, WKp, part);
  finalize_kernel<<<dim3(16), 256, 0, stream>>>(part, r1w, r2w, der);
  qw_prep_kernel<<<dim3(64), 256, 0, stream>>>(q1w, q2w, QWAp);
  rm_prep_kernel<<<dim3(512), 256, 0, stream>>>(der, RMAp);
  prep_wa_kernel<<<dim3(640), 256, 0, stream>>>(cw, WA);
  attn_mfma_kernel<<<dim3(CHUNKS, B_, 2), 256, 0, stream>>>(
      t1, t2, q1b, q2b, r1b, r2b, der, QWAp, RMAp, catHp, catLp);
  conv_mfma_kernel<<<dim3(4, 64, B_), 256, 0, stream>>>(
      catHp, catLp, WA, cbp, out);
}

// Round 11
// 525.302 us; speedup vs baseline: 8.8062x; 1.0993x over previous
//
#include <hip/hip_runtime.h>
#include <hip/hip_bf16.h>

// Problem constants (fixed by setup_inputs)
constexpr int B_ = 8;
constexpr int C_ = 64;      // input channels = KC = VC = 64
constexpr int N_ = 65536;   // H*W = 256*256
constexpr int HW_ = 256;
constexpr float EPSF = 1e-6f;
constexpr int STATS = 4224; // 4096 matrix + 64 ksum + 64 vsum
constexpr int CHUNKS = 64;  // stats blocks per (branch,batch)

typedef __attribute__((ext_vector_type(8))) short bf16x8;
typedef __attribute__((ext_vector_type(4))) float f32x4;

// RNE fp32 -> bf16 bits, pure bit arithmetic (no address-taken locals)
__device__ __forceinline__ unsigned short f2bf(float f) {
  const unsigned u = __float_as_uint(f);
  return (unsigned short)((u + 0x7fffu + ((u >> 16) & 1u)) >> 16);
}

// ================================================================
// prep_proj: K/V projection weights -> MFMA A-fragment order, bf16.
// WK[r(2)][kv(2)][ot(4)][ks(2)][lane(64)][j(8)]  (unchanged)
// ================================================================
__global__ void prep_proj_kernel(const float* __restrict__ k1w,
                                 const float* __restrict__ v1w,
                                 const float* __restrict__ k2w,
                                 const float* __restrict__ v2w,
                                 unsigned short* __restrict__ WK) {
  const int e = blockIdx.x * 256 + threadIdx.x;   // 16384 total
  if (e >= 16384) return;
  const int j    = e & 7;
  const int lane = (e >> 3) & 63;
  const int ks   = (e >> 9) & 1;
  const int ot   = (e >> 10) & 3;
  const int kv   = (e >> 12) & 1;
  const int r    = (e >> 13) & 1;
  const int m    = ot * 16 + (lane & 15);
  const int ch   = ks * 32 + ((lane >> 4) & 3) * 8 + j;
  const float* w = r ? (kv ? v2w : k2w) : (kv ? v1w : k1w);
  WK[e] = f2bf(w[m * 64 + ch]);
}

// ================================================================
// qw_prep: Q projection weights -> A-frag order, bf16 HI/LO planes.
// ================================================================
__global__ void qw_prep_kernel(const float* __restrict__ q1w,
                               const float* __restrict__ q2w,
                               unsigned short* __restrict__ QWA) {
  const int e = blockIdx.x * 256 + threadIdx.x;
  if (e >= 16384) return;
  const int j    = e & 7;
  const int lane = (e >> 3) & 63;
  const int ks   = (e >> 9) & 1;
  const int ot   = (e >> 10) & 3;
  const int v    = (e >> 12) & 1;
  const int r    = (e >> 13) & 1;
  const int m    = ot * 16 + (lane & 15);
  const int ch   = ks * 32 + ((lane >> 4) & 3) * 8 + j;
  const float val = (r ? q2w : q1w)[m * 64 + ch];
  unsigned short h = f2bf(val);
  if (v) h = f2bf(val - __uint_as_float((unsigned)h << 16));
  QWA[e] = h;
}

// ================================================================
// rm_prep: rm (= derived[bb][o*64+m]) -> A-frag order bf16 HI/LO.
// ================================================================
__global__ void rm_prep_kernel(const float* __restrict__ derived,
                               unsigned short* __restrict__ RMA) {
  const int e = blockIdx.x * 256 + threadIdx.x;   // 131072 total
  if (e >= 131072) return;
  const int j    = e & 7;
  const int lane = (e >> 3) & 63;
  const int ks   = (e >> 9) & 1;
  const int ot   = (e >> 10) & 3;
  const int v    = (e >> 12) & 1;
  const int bb   = e >> 13;
  const int o    = ot * 16 + (lane & 15);
  const int m    = ks * 32 + ((lane >> 4) & 3) * 8 + j;
  const float val = derived[(size_t)bb * STATS + o * 64 + m];
  unsigned short h = f2bf(val);
  if (v) h = f2bf(val - __uint_as_float((unsigned)h << 16));
  RMA[e] = h;
}

// ================================================================
// Pass 1 (MFMA stats, unchanged)
// ================================================================
__global__ __launch_bounds__(256, 2) void stats_mfma_kernel(
    const float* __restrict__ t1, const float* __restrict__ t2,
    const float* __restrict__ k1b, const float* __restrict__ v1b,
    const float* __restrict__ k2b, const float* __restrict__ v2b,
    const unsigned short* __restrict__ WK,
    float* __restrict__ partials)
{
  const int chunk = blockIdx.x;
  const int b = blockIdx.y;
  const int r = blockIdx.z;
  const float* x  = (r ? t2 : t1) + (size_t)b * C_ * N_;
  const float* kb = r ? k2b : k1b;
  const float* vb = r ? v2b : v1b;
  const unsigned short* WKr = WK + r * 8192;

  __shared__ unsigned short Xs[64 * 72];
  __shared__ unsigned short Ks[64 * 72];
  __shared__ unsigned short Vs[64 * 72];

  const int t  = threadIdx.x;
  const int w  = t >> 6;
  const int l  = t & 63;
  const int li = l & 15;
  const int g  = l >> 4;

  float kbv[4][4], vbv[4][4];
#pragma unroll
  for (int ot = 0; ot < 4; ++ot)
#pragma unroll
    for (int rg = 0; rg < 4; ++rg) {
      kbv[ot][rg] = kb[ot * 16 + g * 4 + rg];
      vbv[ot][rg] = vb[ot * 16 + g * 4 + rg];
    }

  bf16x8 ones;
#pragma unroll
  for (int j = 0; j < 8; ++j) ones[j] = (short)0x3F80;

  f32x4 accM[4];
#pragma unroll
  for (int ct = 0; ct < 4; ++ct) accM[ct] = (f32x4){0.f, 0.f, 0.f, 0.f};
  f32x4 accSk = (f32x4){0.f, 0.f, 0.f, 0.f};
  f32x4 accSv = (f32x4){0.f, 0.f, 0.f, 0.f};

  for (int it = 0; it < 16; ++it) {
    const int px0 = chunk * 1024 + it * 64;
    __syncthreads();
    {
      const int ch = t >> 2;
      const int ps = t & 3;
      const float* src = x + (size_t)ch * N_ + px0 + ps * 16;
      const float4 f0 = ((const float4*)src)[0];
      const float4 f1 = ((const float4*)src)[1];
      const float4 f2 = ((const float4*)src)[2];
      const float4 f3 = ((const float4*)src)[3];
      float v[16] = {f0.x, f0.y, f0.z, f0.w, f1.x, f1.y, f1.z, f1.w,
                     f2.x, f2.y, f2.z, f2.w, f3.x, f3.y, f3.z, f3.w};
      unsigned short* dst = &Xs[(ps * 16) * 72 + (ch ^ (ps << 4))];
#pragma unroll
      for (int i = 0; i < 16; ++i) dst[i * 72] = f2bf(v[i]);
    }
    __syncthreads();

    bf16x8 bx0 = *(const bf16x8*)&Xs[(w * 16 + li) * 72 + ((g * 8) ^ (w << 4))];
    bf16x8 bx1 = *(const bf16x8*)&Xs[(w * 16 + li) * 72 + ((32 + g * 8) ^ (w << 4))];

    f32x4 ka[4];
#pragma unroll
    for (int ot = 0; ot < 4; ++ot) {
      f32x4 a = (f32x4){0.f, 0.f, 0.f, 0.f};
      const bf16x8 w0 = *(const bf16x8*)(WKr + ((ot * 2 + 0) * 64 + l) * 8);
      const bf16x8 w1 = *(const bf16x8*)(WKr + ((ot * 2 + 1) * 64 + l) * 8);
      a = __builtin_amdgcn_mfma_f32_16x16x32_bf16(w0, bx0, a, 0, 0, 0);
      a = __builtin_amdgcn_mfma_f32_16x16x32_bf16(w1, bx1, a, 0, 0, 0);
      ka[ot] = a;
    }
    float ss = 0.f;
#pragma unroll
    for (int ot = 0; ot < 4; ++ot)
#pragma unroll
      for (int rg = 0; rg < 4; ++rg) {
        const float v2 = ka[ot][rg] + kbv[ot][rg];
        ka[ot][rg] = v2;
        ss += v2 * v2;
      }
    ss += __shfl_xor(ss, 16);
    ss += __shfl_xor(ss, 32);
    const float inv = rsqrtf(ss);
#pragma unroll
    for (int ot = 0; ot < 4; ++ot)
#pragma unroll
      for (int rg = 0; rg < 4; ++rg)
        Ks[(ot * 16 + g * 4 + rg) * 72 + w * 16 + li] = f2bf(ka[ot][rg] * inv);

#pragma unroll
    for (int ot = 0; ot < 4; ++ot) {
      f32x4 a = (f32x4){0.f, 0.f, 0.f, 0.f};
      const bf16x8 w0 = *(const bf16x8*)(WKr + 4096 + ((ot * 2 + 0) * 64 + l) * 8);
      const bf16x8 w1 = *(const bf16x8*)(WKr + 4096 + ((ot * 2 + 1) * 64 + l) * 8);
      a = __builtin_amdgcn_mfma_f32_16x16x32_bf16(w0, bx0, a, 0, 0, 0);
      a = __builtin_amdgcn_mfma_f32_16x16x32_bf16(w1, bx1, a, 0, 0, 0);
#pragma unroll
      for (int rg = 0; rg < 4; ++rg)
        Vs[(ot * 16 + g * 4 + rg) * 72 + w * 16 + li] = f2bf(a[rg] + vbv[ot][rg]);
    }
    __syncthreads();

#pragma unroll
    for (int ks = 0; ks < 2; ++ks) {
      const int ko = ks * 32 + g * 8;
      const bf16x8 aK = *(const bf16x8*)&Ks[(w * 16 + li) * 72 + ko];
      const bf16x8 aV = *(const bf16x8*)&Vs[(w * 16 + li) * 72 + ko];
      accSk = __builtin_amdgcn_mfma_f32_16x16x32_bf16(aK, ones, accSk, 0, 0, 0);
      accSv = __builtin_amdgcn_mfma_f32_16x16x32_bf16(aV, ones, accSv, 0, 0, 0);
#pragma unroll
      for (int ct = 0; ct < 4; ++ct) {
        const bf16x8 bV = *(const bf16x8*)&Vs[(ct * 16 + li) * 72 + ko];
        accM[ct] = __builtin_amdgcn_mfma_f32_16x16x32_bf16(aK, bV, accM[ct], 0, 0, 0);
      }
    }
  }

  float* pb = partials + ((size_t)(r * B_ + b) * CHUNKS + chunk) * STATS;
#pragma unroll
  for (int ct = 0; ct < 4; ++ct)
#pragma unroll
    for (int rg = 0; rg < 4; ++rg)
      pb[(w * 16 + g * 4 + rg) * 64 + ct * 16 + li] = accM[ct][rg];
  if (li == 0) {
#pragma unroll
    for (int rg = 0; rg < 4; ++rg) {
      pb[4096 + w * 16 + g * 4 + rg] = accSk[rg];
      pb[4160 + w * 16 + g * 4 + rg] = accSv[rg];
    }
  }
}

// ================================================================
// Finalize: reduce partials, fold r_w in. (unchanged)
// ================================================================
__global__ void finalize_kernel(const float* __restrict__ partials,
                                const float* __restrict__ r1w,
                                const float* __restrict__ r2w,
                                float* __restrict__ derived)
{
  const int bb = blockIdx.x;
  const int r = bb >> 3;
  const float* rw = r ? r2w : r1w;
  __shared__ float mat[4096];
  __shared__ float ks[64], vs[64];
  const int t = threadIdx.x;
  const float* pb = partials + (size_t)bb * CHUNKS * STATS;
  for (int e = t; e < STATS; e += 256) {
    float s = 0.f;
    for (int j = 0; j < CHUNKS; ++j) s += pb[(size_t)j * STATS + e];
    if (e < 4096) mat[e] = s;
    else if (e < 4160) ks[e - 4096] = s;
    else vs[e - 4160] = s;
  }
  __syncthreads();
  float* der = derived + (size_t)bb * STATS;
  for (int e = t; e < 4096; e += 256) {
    const int o = e >> 6, m = e & 63;
    float s = 0.f;
    for (int c = 0; c < 64; ++c) s += rw[o * 64 + c] * mat[m * 64 + c];
    der[e] = s;
  }
  if (t < 64) {
    float s = 0.f;
    for (int c = 0; c < 64; ++c) s += rw[t * 64 + c] * vs[c];
    der[4096 + t] = s;
    der[4160 + t] = ks[t] + EPSF;
  }
}

// ================================================================
// Pass 2 (MFMA attn, unchanged from round 8)
// ================================================================
__global__ __launch_bounds__(256, 2) void attn_mfma_kernel(
    const float* __restrict__ t1, const float* __restrict__ t2,
    const float* __restrict__ q1b, const float* __restrict__ q2b,
    const float* __restrict__ r1b, const float* __restrict__ r2b,
    const float* __restrict__ derived,
    const unsigned short* __restrict__ QWA,
    const unsigned short* __restrict__ RMA,
    __hip_bfloat16* __restrict__ catH, __hip_bfloat16* __restrict__ catL)
{
  const int chunk = blockIdx.x;
  const int b = blockIdx.y;
  const int rbr = blockIdx.z;
  const float* x  = (rbr ? t2 : t1) + (size_t)b * C_ * N_;
  const float* qb = rbr ? q2b : q1b;
  const float* rb = rbr ? r2b : r1b;
  const int bb = rbr * B_ + b;
  const float* der = derived + (size_t)bb * STATS;
  const unsigned short* qwa = QWA + rbr * 8192;
  const unsigned short* rma = RMA + (size_t)bb * 8192;

  __shared__ unsigned short XsH[64 * 72];
  __shared__ unsigned short XsL[64 * 72];
  __shared__ unsigned short QsH[64 * 72];
  __shared__ unsigned short QsL[64 * 72];

  const int t  = threadIdx.x;
  const int w  = t >> 6;
  const int l  = t & 63;
  const int li = l & 15;
  const int g  = l >> 4;

  float qbv[16], ksev[16], rvsv[16], rbv[16];
#pragma unroll
  for (int ot = 0; ot < 4; ++ot)
#pragma unroll
    for (int rg = 0; rg < 4; ++rg) {
      const int row = ot * 16 + g * 4 + rg;
      qbv[ot * 4 + rg]  = qb[row];
      ksev[ot * 4 + rg] = der[4160 + row];
      rvsv[ot * 4 + rg] = der[4096 + row];
      rbv[ot * 4 + rg]  = rb[row];
    }

#pragma clang loop unroll(disable)
  for (int it = 0; it < 16; ++it) {
    const int px0 = chunk * 1024 + it * 64;
    __syncthreads();
    {
      const int ch = t >> 2;
      const int ps = t & 3;
      const float* src = x + (size_t)ch * N_ + px0 + ps * 16;
      const float4 f0 = ((const float4*)src)[0];
      const float4 f1v = ((const float4*)src)[1];
      const float4 f2v = ((const float4*)src)[2];
      const float4 f3v = ((const float4*)src)[3];
      float v[16] = {f0.x, f0.y, f0.z, f0.w, f1v.x, f1v.y, f1v.z, f1v.w,
                     f2v.x, f2v.y, f2v.z, f2v.w, f3v.x, f3v.y, f3v.z, f3v.w};
      const int col = ch ^ (ps << 4);
      unsigned short* dH = &XsH[(ps * 16) * 72 + col];
      unsigned short* dL = &XsL[(ps * 16) * 72 + col];
#pragma unroll
      for (int i = 0; i < 16; ++i) {
        const unsigned short h = f2bf(v[i]);
        dH[i * 72] = h;
        dL[i * 72] = f2bf(v[i] - __uint_as_float((unsigned)h << 16));
      }
    }
    __syncthreads();

    const int rowb = (w * 16 + li) * 72;
    const bf16x8 bxh0 = *(const bf16x8*)&XsH[rowb + ((g * 8) ^ (w << 4))];
    const bf16x8 bxh1 = *(const bf16x8*)&XsH[rowb + ((32 + g * 8) ^ (w << 4))];
    const bf16x8 bxl0 = *(const bf16x8*)&XsL[rowb + ((g * 8) ^ (w << 4))];
    const bf16x8 bxl1 = *(const bf16x8*)&XsL[rowb + ((32 + g * 8) ^ (w << 4))];

    float q[16];
#pragma unroll
    for (int ot = 0; ot < 4; ++ot) {
      f32x4 a = (f32x4){0.f, 0.f, 0.f, 0.f};
      const bf16x8 wh0 = *(const bf16x8*)(qwa + ((0 * 4 + ot) * 2 + 0) * 512 + l * 8);
      const bf16x8 wh1 = *(const bf16x8*)(qwa + ((0 * 4 + ot) * 2 + 1) * 512 + l * 8);
      const bf16x8 wl0 = *(const bf16x8*)(qwa + ((1 * 4 + ot) * 2 + 0) * 512 + l * 8);
      const bf16x8 wl1 = *(const bf16x8*)(qwa + ((1 * 4 + ot) * 2 + 1) * 512 + l * 8);
      a = __builtin_amdgcn_mfma_f32_16x16x32_bf16(wh0, bxh0, a, 0, 0, 0);
      a = __builtin_amdgcn_mfma_f32_16x16x32_bf16(wh1, bxh1, a, 0, 0, 0);
      a = __builtin_amdgcn_mfma_f32_16x16x32_bf16(wh0, bxl0, a, 0, 0, 0);
      a = __builtin_amdgcn_mfma_f32_16x16x32_bf16(wh1, bxl1, a, 0, 0, 0);
      a = __builtin_amdgcn_mfma_f32_16x16x32_bf16(wl0, bxh0, a, 0, 0, 0);
      a = __builtin_amdgcn_mfma_f32_16x16x32_bf16(wl1, bxh1, a, 0, 0, 0);
#pragma unroll
      for (int rg = 0; rg < 4; ++rg) q[ot * 4 + rg] = a[rg] + qbv[ot * 4 + rg];
    }

    float ss = 0.f, d = 0.f;
#pragma unroll
    for (int i = 0; i < 16; ++i) { ss += q[i] * q[i]; d += q[i] * ksev[i]; }
    ss += __shfl_xor(ss, 16);  ss += __shfl_xor(ss, 32);
    d  += __shfl_xor(d, 16);   d  += __shfl_xor(d, 32);
    const float inv = rsqrtf(ss);
    const float rden = 1.0f / (65536.0f + inv * d);
    const float f1 = rden * inv;

#pragma unroll
    for (int ot = 0; ot < 4; ++ot) {
      unsigned h0, h1, h2, h3, l0, l1, l2, l3;
      {
        const float v0 = q[ot * 4 + 0], v1 = q[ot * 4 + 1];
        const float v2 = q[ot * 4 + 2], v3 = q[ot * 4 + 3];
        h0 = f2bf(v0); l0 = f2bf(v0 - __uint_as_float(h0 << 16));
        h1 = f2bf(v1); l1 = f2bf(v1 - __uint_as_float(h1 << 16));
        h2 = f2bf(v2); l2 = f2bf(v2 - __uint_as_float(h2 << 16));
        h3 = f2bf(v3); l3 = f2bf(v3 - __uint_as_float(h3 << 16));
      }
      const int off = (w * 16 + li) * 72 + ot * 16 + g * 4;
      *(uint2*)&QsH[off] = make_uint2(h0 | (h1 << 16), h2 | (h3 << 16));
      *(uint2*)&QsL[off] = make_uint2(l0 | (l1 << 16), l2 | (l3 << 16));
    }

    const bf16x8 bqh0 = *(const bf16x8*)&QsH[rowb + g * 8];
    const bf16x8 bqh1 = *(const bf16x8*)&QsH[rowb + 32 + g * 8];
    const bf16x8 bql0 = *(const bf16x8*)&QsL[rowb + g * 8];
    const bf16x8 bql1 = *(const bf16x8*)&QsL[rowb + 32 + g * 8];

#pragma unroll
    for (int ot = 0; ot < 4; ++ot) {
      f32x4 a = (f32x4){0.f, 0.f, 0.f, 0.f};
      const bf16x8 rh0 = *(const bf16x8*)(rma + ((0 * 4 + ot) * 2 + 0) * 512 + l * 8);
      const bf16x8 rh1 = *(const bf16x8*)(rma + ((0 * 4 + ot) * 2 + 1) * 512 + l * 8);
      const bf16x8 rl0 = *(const bf16x8*)(rma + ((1 * 4 + ot) * 2 + 0) * 512 + l * 8);
      const bf16x8 rl1 = *(const bf16x8*)(rma + ((1 * 4 + ot) * 2 + 1) * 512 + l * 8);
      a = __builtin_amdgcn_mfma_f32_16x16x32_bf16(rh0, bqh0, a, 0, 0, 0);
      a = __builtin_amdgcn_mfma_f32_16x16x32_bf16(rh1, bqh1, a, 0, 0, 0);
      a = __builtin_amdgcn_mfma_f32_16x16x32_bf16(rh0, bql0, a, 0, 0, 0);
      a = __builtin_amdgcn_mfma_f32_16x16x32_bf16(rh1, bql1, a, 0, 0, 0);
      a = __builtin_amdgcn_mfma_f32_16x16x32_bf16(rl0, bqh0, a, 0, 0, 0);
      a = __builtin_amdgcn_mfma_f32_16x16x32_bf16(rl1, bqh1, a, 0, 0, 0);

      unsigned h0, h1, h2, h3, l0, l1, l2, l3;
      {
        const float a0 = f1 * a[0] + rden * rvsv[ot * 4 + 0] + rbv[ot * 4 + 0];
        const float a1 = f1 * a[1] + rden * rvsv[ot * 4 + 1] + rbv[ot * 4 + 1];
        const float a2 = f1 * a[2] + rden * rvsv[ot * 4 + 2] + rbv[ot * 4 + 2];
        const float a3 = f1 * a[3] + rden * rvsv[ot * 4 + 3] + rbv[ot * 4 + 3];
        h0 = f2bf(a0); l0 = f2bf(a0 - __uint_as_float(h0 << 16));
        h1 = f2bf(a1); l1 = f2bf(a1 - __uint_as_float(h1 << 16));
        h2 = f2bf(a2); l2 = f2bf(a2 - __uint_as_float(h2 << 16));
        h3 = f2bf(a3); l3 = f2bf(a3 - __uint_as_float(h3 << 16));
      }
      const size_t base =
          (((size_t)(b * 8 + rbr * 4 + ot)) * N_ + (px0 + w * 16 + li)) * 16 + g * 4;
      *(uint2*)(catH + base) = make_uint2(h0 | (h1 << 16), h2 | (h3 << 16));
      *(uint2*)(catL + base) = make_uint2(l0 | (l1 << 16), l2 | (l3 << 16));
    }
  }
}

// ================================================================
// prep_wa: conv weights -> A-frag order, split bf16 hi/lo. (unchanged)
// ================================================================
__global__ void prep_wa_kernel(const float* __restrict__ cw,
                               __hip_bfloat16* __restrict__ WA) {
  const int e = blockIdx.x * 256 + threadIdx.x;
  if (e >= 8 * 5 * 2 * 4 * 512) return;
  const int j    = e & 7;
  const int lane = (e >> 3) & 63;
  const int f    = e >> 9;
  const int ot   = f & 3;
  const int v    = (f >> 2) & 1;
  const int s    = (f >> 3) % 5;
  const int c    = (f >> 3) / 5;
  const int o    = ot * 16 + (lane & 15);
  const int g    = lane >> 4;
  const int tap  = 2 * s + (g >> 1);
  float val = 0.f;
  if (tap <= 8) {
    const int ci = c * 16 + (g & 1) * 8 + j;
    val = cw[(size_t)(o * 128 + ci) * 9 + tap];
  }
  __hip_bfloat16 h = __float2bfloat16(val);
  if (v) h = __float2bfloat16(val - __bfloat162float(h));
  WA[e] = h;
}

// ================================================================
// Pass 3: 3x3 conv via MFMA implicit GEMM, split-bf16, T14 pipeline.
// ROUND-11 FIX: round 10 still spilled (WRITE 351 MB, VGPR=84 — the
// (256,3) cap of ~170 unified minus 64 AGPR left only ~106 VGPR vs
// ~130 live). Relax to __launch_bounds__(256,2): 256 unified budget,
// live set (~161) fits with headroom. Occupancy cap 3->2 blocks/CU;
// measured was only 31% anyway, and 16 indep acc chains keep the
// MFMA pipe fed at 8 waves/CU with the pipeline intact.
// ================================================================
__global__ __launch_bounds__(256, 2) void conv_mfma_kernel(
    const __hip_bfloat16* __restrict__ catH,
    const __hip_bfloat16* __restrict__ catL,
    const __hip_bfloat16* __restrict__ WA,
    const float* __restrict__ cb,
    float* __restrict__ out)
{
  __shared__ __hip_bfloat16 XsH[6 * 68 * 24];
  __shared__ __hip_bfloat16 XsL[6 * 68 * 24];

  const int t  = threadIdx.x;
  const int w  = t >> 6;
  const int l  = t & 63;
  const int li = l & 15;
  const int g  = l >> 4;
  const int x0 = blockIdx.x * 64;
  const int y0 = blockIdx.y * 4;
  const int b  = blockIdx.z;

  // staging geometry: items 0..395 = row(6) x col(66); thread owns
  // item A = t and item B = t+256 (B valid for t < 140).
  const int iA = t;
  const int iB = t + 256;
  const bool hasB = (iB < 396);
  const int rA = iA / 66, cA = iA - rA * 66;
  const int rB = iB / 66, cB = iB - rB * 66;
  const int gyA = y0 + rA - 1, gxA = x0 + cA - 1;
  const int gyB = y0 + rB - 1, gxB = x0 + cB - 1;
  const bool okA = ((unsigned)gyA < 256u) && ((unsigned)gxA < 256u);
  const bool okB = hasB && ((unsigned)gyB < 256u) && ((unsigned)gxB < 256u);
  const size_t offA = ((size_t)(gyA * HW_ + gxA)) * 16;
  const size_t offB = ((size_t)(gyB * HW_ + gxB)) * 16;
  const int leA = (rA * 68 + cA) * 24;
  const int leB = (rB * 68 + cB) * 24;
  const uint4 Z = make_uint4(0u, 0u, 0u, 0u);

  uint4 Ah0, Ah1, Al0, Al1, Bh0, Bh1, Bl0, Bl1;

  f32x4 acc[4][4];
#pragma unroll
  for (int i = 0; i < 4; ++i)
#pragma unroll
    for (int k = 0; k < 4; ++k) acc[i][k] = (f32x4){0.f, 0.f, 0.f, 0.f};

  // ---- prologue: issue chunk-0 loads
  {
    const size_t chb = ((size_t)(b * 8 + 0)) * N_ * 16;
    Ah0 = Ah1 = Al0 = Al1 = Z;
    Bh0 = Bh1 = Bl0 = Bl1 = Z;
    if (okA) {
      const uint4* ph = (const uint4*)(catH + chb + offA);
      Ah0 = ph[0]; Ah1 = ph[1];
      const uint4* pl = (const uint4*)(catL + chb + offA);
      Al0 = pl[0]; Al1 = pl[1];
    }
    if (okB) {
      const uint4* ph = (const uint4*)(catH + chb + offB);
      Bh0 = ph[0]; Bh1 = ph[1];
      const uint4* pl = (const uint4*)(catL + chb + offB);
      Bl0 = pl[0]; Bl1 = pl[1];
    }
  }

  for (int c = 0; c < 8; ++c) {
    __syncthreads();             // previous chunk's compute reads done
    // ---- write-late: staged regs -> LDS
    *(uint4*)(&XsH[leA]) = Ah0; *(uint4*)(&XsH[leA + 8]) = Ah1;
    *(uint4*)(&XsL[leA]) = Al0; *(uint4*)(&XsL[leA + 8]) = Al1;
    if (hasB) {
      *(uint4*)(&XsH[leB]) = Bh0; *(uint4*)(&XsH[leB + 8]) = Bh1;
      *(uint4*)(&XsL[leB]) = Bl0; *(uint4*)(&XsL[leB + 8]) = Bl1;
    }
    __syncthreads();
    // ---- issue-early: chunk c+1 loads fly across COMPUTE(c)
    if (c < 7) {
      const size_t chb = ((size_t)(b * 8 + c + 1)) * N_ * 16;
      Ah0 = Ah1 = Al0 = Al1 = Z;
      Bh0 = Bh1 = Bl0 = Bl1 = Z;
      if (okA) {
        const uint4* ph = (const uint4*)(catH + chb + offA);
        Ah0 = ph[0]; Ah1 = ph[1];
        const uint4* pl = (const uint4*)(catL + chb + offA);
        Al0 = pl[0]; Al1 = pl[1];
      }
      if (okB) {
        const uint4* ph = (const uint4*)(catH + chb + offB);
        Bh0 = ph[0]; Bh1 = ph[1];
        const uint4* pl = (const uint4*)(catL + chb + offB);
        Bl0 = pl[0]; Bl1 = pl[1];
      }
    }

    // ---- COMPUTE(c): B-frags loaded per-pt (2 live, not 8)
    const __hip_bfloat16* wa_c = WA + (size_t)c * 20480;
#pragma unroll
    for (int s = 0; s < 5; ++s) {
      const __hip_bfloat16* wa_s = wa_c + s * 4096 + l * 8;
      bf16x8 aH[4], aL[4];
#pragma unroll
      for (int ot = 0; ot < 4; ++ot) aH[ot] = *(const bf16x8*)(wa_s + ot * 512);
#pragma unroll
      for (int ot = 0; ot < 4; ++ot) aL[ot] = *(const bf16x8*)(wa_s + 2048 + ot * 512);

      int tap = 2 * s + (g >> 1);
      if (tap > 8) tap = 0;
      const int ky = tap / 3;
      const int kx = tap - ky * 3;
      const int e0 = ((w + ky) * 68 + li + kx) * 24 + (g & 1) * 8;

#pragma unroll
      for (int pt = 0; pt < 4; ++pt) {
        const bf16x8 bH = *(const bf16x8*)(&XsH[e0 + pt * 384]);
        const bf16x8 bL = *(const bf16x8*)(&XsL[e0 + pt * 384]);
#pragma unroll
        for (int ot = 0; ot < 4; ++ot) {
          acc[ot][pt] = __builtin_amdgcn_mfma_f32_16x16x32_bf16(
              aH[ot], bH, acc[ot][pt], 0, 0, 0);
          acc[ot][pt] = __builtin_amdgcn_mfma_f32_16x16x32_bf16(
              aH[ot], bL, acc[ot][pt], 0, 0, 0);
          acc[ot][pt] = __builtin_amdgcn_mfma_f32_16x16x32_bf16(
              aL[ot], bH, acc[ot][pt], 0, 0, 0);
        }
      }
    }
  }

#pragma unroll
  for (int ot = 0; ot < 4; ++ot)
#pragma unroll
    for (int r = 0; r < 4; ++r) {
      const int o = ot * 16 + g * 4 + r;
      const float bv = cb[o];
      float* orow = out + ((size_t)b * 64 + o) * N_ + (size_t)(y0 + w) * HW_ + x0 + li;
#pragma unroll
      for (int pt = 0; pt < 4; ++pt)
        orow[pt * 16] = acc[ot][pt][r] + bv;
    }
}

// ================================================================
extern "C" void kernel_launch(void* const* d_in, const int* in_sizes, int n_in,
                              void* d_out, int out_size, void* d_ws, size_t ws_size,
                              hipStream_t stream) {
  const float* t1  = (const float*)d_in[0];
  const float* t2  = (const float*)d_in[1];
  const float* q1w = (const float*)d_in[2];
  const float* q1b = (const float*)d_in[3];
  const float* k1w = (const float*)d_in[4];
  const float* k1b = (const float*)d_in[5];
  const float* v1w = (const float*)d_in[6];
  const float* v1b = (const float*)d_in[7];
  const float* r1w = (const float*)d_in[8];
  const float* r1b = (const float*)d_in[9];
  const float* q2w = (const float*)d_in[10];
  const float* q2b = (const float*)d_in[11];
  const float* k2w = (const float*)d_in[12];
  const float* k2b = (const float*)d_in[13];
  const float* v2w = (const float*)d_in[14];
  const float* v2b = (const float*)d_in[15];
  const float* r2w = (const float*)d_in[16];
  const float* r2b = (const float*)d_in[17];
  const float* cw  = (const float*)d_in[18];
  const float* cbp = (const float*)d_in[19];
  float* out = (float*)d_out;

  // ws: [catH 128MB][catL 128MB][partials 16.5MB][derived 264KB]
  // Aliases inside the dead-after-finalize partials region:
  //   WA at +0 (320KB), RMA at +1MB (256KB), QWA at +2MB (32KB).
  // WK (stats weights) aliases catH (dead until attn runs).
  char* ws = (char*)d_ws;
  const size_t catB  = (size_t)B_ * 8 * N_ * 16 * 2;     // 128 MB each
  const size_t partB = (size_t)16 * CHUNKS * STATS * sizeof(float);
  __hip_bfloat16* catHp = (__hip_bfloat16*)ws;
  __hip_bfloat16* catLp = (__hip_bfloat16*)(ws + catB);
  float* part = (float*)(ws + 2 * catB);
  float* der  = (float*)(ws + 2 * catB + partB);
  __hip_bfloat16* WA   = (__hip_bfloat16*)part;                         // alias
  unsigned short* RMAp = (unsigned short*)(ws + 2 * catB + (1u << 20)); // alias
  unsigned short* QWAp = (unsigned short*)(ws + 2 * catB + (2u << 20)); // alias
  unsigned short* WKp  = (unsigned short*)ws;                           // alias (catH)

  prep_proj_kernel<<<dim3(64), 256, 0, stream>>>(k1w, v1w, k2w, v2w, WKp);
  stats_mfma_kernel<<<dim3(CHUNKS, B_, 2), 256, 0, stream>>>(
      t1, t2, k1b, v1b, k2b, v2b, WKp, part);
  finalize_kernel<<<dim3(16), 256, 0, stream>>>(part, r1w, r2w, der);
  qw_prep_kernel<<<dim3(64), 256, 0, stream>>>(q1w, q2w, QWAp);
  rm_prep_kernel<<<dim3(512), 256, 0, stream>>>(der, RMAp);
  prep_wa_kernel<<<dim3(640), 256, 0, stream>>>(cw, WA);
  attn_mfma_kernel<<<dim3(CHUNKS, B_, 2), 256, 0, stream>>>(
      t1, t2, q1b, q2b, r1b, r2b, der, QWAp, RMAp, catHp, catLp);
  conv_mfma_kernel<<<dim3(4, 64, B_), 256, 0, stream>>>(
      catHp, catLp, WA, cbp, out);
}